// Round 1
// baseline (2813.941 us; speedup 1.0000x reference)
//
#include <hip/hip_runtime.h>
#include <math.h>

// ---------------------------------------------------------------------------
// LSTNet on MI355X — full fp32 pipeline, round 0 (correctness-first).
// Workspace requirement: ~90.8 MB (22,695,936 floats).
// ---------------------------------------------------------------------------

#define B_ 32
#define N_ 2048
#define NPOINT 512
#define NSAMPLE 16
#define NKNN 16
#define NPTS (B_ * NPOINT)   // 16384

// ---- workspace layout (float offsets) ----
// pre-transposed weights Wt[k][n] = W[n][k]
#define WS_WT_START 0         // 128x64   (8192)
#define WS_WT_Q     8192      // 64x64    (4096)
#define WS_WT_K     12288
#define WS_WT_V     16384
#define WS_WT_E1    20480     // 128x256  (32768)
#define WS_WT_E2    53248     // 256x512  (131072)
#define WS_WT_M1    184320    // 1024x512 (524288)
#define WS_WT_M2    708608    // 512x256  (131072)
#define WS_WT_M3    839680    // 256x128  (32768)
#define WS_XYZT     872448    // (B,2048,3) 196608
#define WS_RR       1069056   // (B,2048)   65536
#define WS_NEWXYZ   1134592   // (B,512,3)  49152
#define WS_IDX1     1183744   // int (B,512,16) 262144
#define WS_IDXK     1445888   // int (B,512,16) 262144
#define WS_KF       1708032   // (NPTS,128) 2097152
#define WS_Q        3805184   // (NPTS,64)  1048576
#define WS_K        4853760
#define WS_V        5902336
#define WS_AGG      6950912
#define WS_KFF      7999488   // (NPTS,128) 2097152
#define WS_E1       10096640  // (NPTS,256) 4194304
#define WS_FEAT     14290944  // (NPTS,512) 8388608
#define WS_GF       22679552  // (B,512)    16384
#define WS_TOTAL    22695936
// reuse (dead by the time they're written):
#define WS_M1       WS_KF     // (NPTS,512) overlays kf..kff exactly (8388608)
#define WS_M2       WS_E1     // (NPTS,256) overlays e1 exactly
#define WS_M3       WS_FEAT   // (NPTS,128) overlays feat head

// ---------------------------------------------------------------------------
// prep: xyz transpose + |r|^2 + 9 weight transposes. 937984 threads exact.
// ---------------------------------------------------------------------------
__global__ __launch_bounds__(256) void prep_kernel(
    const float* __restrict__ pc,
    const float* __restrict__ w_start, const float* __restrict__ w_q,
    const float* __restrict__ w_k, const float* __restrict__ w_v,
    const float* __restrict__ w_e1, const float* __restrict__ w_e2,
    const float* __restrict__ w_m1, const float* __restrict__ w_m2,
    const float* __restrict__ w_m3, float* __restrict__ ws) {
  int f = blockIdx.x * 256 + threadIdx.x;
  if (f < 65536) {  // xyz_t + rr
    int b = f >> 11, j = f & 2047;
    const float* base = pc + (size_t)b * 3 * 2048;
    float x = base[j], y = base[2048 + j], z = base[4096 + j];
    float* xt = ws + WS_XYZT + (size_t)f * 3;
    xt[0] = x; xt[1] = y; xt[2] = z;
    ws[WS_RR + f] = x * x + y * y + z * z;
    return;
  }
  int u = f - 65536;
  if (u < 8192)  { int k = u >> 6, n = u & 63;  ws[WS_WT_START + u] = w_start[n * 128 + k]; return; }
  u -= 8192;
  if (u < 4096)  { int k = u >> 6, n = u & 63;  ws[WS_WT_Q + u] = w_q[n * 64 + k]; return; }
  u -= 4096;
  if (u < 4096)  { int k = u >> 6, n = u & 63;  ws[WS_WT_K + u] = w_k[n * 64 + k]; return; }
  u -= 4096;
  if (u < 4096)  { int k = u >> 6, n = u & 63;  ws[WS_WT_V + u] = w_v[n * 64 + k]; return; }
  u -= 4096;
  if (u < 32768) { int k = u >> 8, n = u & 255; ws[WS_WT_E1 + u] = w_e1[n * 128 + k]; return; }
  u -= 32768;
  if (u < 131072){ int k = u >> 9, n = u & 511; ws[WS_WT_E2 + u] = w_e2[n * 256 + k]; return; }
  u -= 131072;
  if (u < 524288){ int k = u >> 9, n = u & 511; ws[WS_WT_M1 + u] = w_m1[n * 1024 + k]; return; }
  u -= 524288;
  if (u < 131072){ int k = u >> 8, n = u & 255; ws[WS_WT_M2 + u] = w_m2[n * 512 + k]; return; }
  u -= 131072;
  if (u < 32768) { int k = u >> 7, n = u & 127; ws[WS_WT_M3 + u] = w_m3[n * 256 + k]; return; }
}

// ---------------------------------------------------------------------------
// FPS: 1 block per batch, 256 threads * 8 points. Writes new_xyz only.
// argmax tie-break = first (smallest) index, matching jnp.argmax.
// ---------------------------------------------------------------------------
__global__ __launch_bounds__(256) void fps_kernel(const float* __restrict__ xyz_t,
                                                  float* __restrict__ new_xyz) {
  int b = blockIdx.x;
  int tid = threadIdx.x;
  const float* xb = xyz_t + (size_t)b * 2048 * 3;
  float px[8], py[8], pz[8], md[8];
#pragma unroll
  for (int r = 0; r < 8; ++r) {
    int j = tid + r * 256;
    px[r] = xb[j * 3 + 0]; py[r] = xb[j * 3 + 1]; pz[r] = xb[j * 3 + 2];
    md[r] = 1e10f;
  }
  __shared__ float wv_[4];
  __shared__ int wi_[4];
  __shared__ int sfar;
  int far = 0;
  for (int i = 0; i < 512; ++i) {
    float cx = xb[far * 3 + 0], cy = xb[far * 3 + 1], cz = xb[far * 3 + 2];
    if (tid == 0) {
      float* o = new_xyz + (size_t)(b * 512 + i) * 3;
      o[0] = cx; o[1] = cy; o[2] = cz;
    }
    float bv = -1.0f; int bj = 0;
#pragma unroll
    for (int r = 0; r < 8; ++r) {
      float dx = px[r] - cx, dy = py[r] - cy, dz = pz[r] - cz;
      float d = dx * dx + dy * dy + dz * dz;
      md[r] = fminf(md[r], d);
      if (md[r] > bv) { bv = md[r]; bj = tid + r * 256; }
    }
#pragma unroll
    for (int off = 32; off > 0; off >>= 1) {
      float ov = __shfl_down(bv, off);
      int oj = __shfl_down(bj, off);
      if (ov > bv || (ov == bv && oj < bj)) { bv = ov; bj = oj; }
    }
    int w = tid >> 6;
    if ((tid & 63) == 0) { wv_[w] = bv; wi_[w] = bj; }
    __syncthreads();
    if (tid == 0) {
      float fv = wv_[0]; int fj = wi_[0];
      for (int ww = 1; ww < 4; ++ww)
        if (wv_[ww] > fv || (wv_[ww] == fv && wi_[ww] < fj)) { fv = wv_[ww]; fj = wi_[ww]; }
      sfar = fj;
    }
    __syncthreads();
    far = sfar;
  }
}

// ---------------------------------------------------------------------------
// KNN of 512 queries (new_xyz) vs 2048 refs (xyz_t) per batch, k=16.
// ---------------------------------------------------------------------------
__global__ __launch_bounds__(256) void knn1_kernel(const float* __restrict__ xyz_t,
                                                   const float* __restrict__ rr,
                                                   const float* __restrict__ new_xyz,
                                                   int* __restrict__ idx1) {
  int gid = blockIdx.x * 256 + threadIdx.x;
  int b = gid >> 9;
  const float* refs = xyz_t + (size_t)b * 2048 * 3;
  const float* rrb = rr + (size_t)b * 2048;
  float qx = new_xyz[gid * 3 + 0], qy = new_xyz[gid * 3 + 1], qz = new_xyz[gid * 3 + 2];
  float qq = qx * qx + qy * qy + qz * qz;
  float bd[16]; int bi[16];
#pragma unroll
  for (int s = 0; s < 16; ++s) { bd[s] = 3.0e38f; bi[s] = 0; }
  for (int j = 0; j < 2048; ++j) {
    float rx = refs[j * 3 + 0], ry = refs[j * 3 + 1], rz = refs[j * 3 + 2];
    float dot = qx * rx + qy * ry + qz * rz;
    float d = (qq - 2.0f * dot) + rrb[j];
    if (d < bd[15]) {
      float nd = d; int ni = j;
#pragma unroll
      for (int s = 0; s < 16; ++s) {
        bool sw = nd < bd[s];
        float ob = bd[s]; int oi = bi[s];
        bd[s] = sw ? nd : ob; bi[s] = sw ? ni : oi;
        nd = sw ? ob : nd; ni = sw ? oi : ni;
      }
    }
  }
#pragma unroll
  for (int s = 0; s < 16; ++s) idx1[(size_t)gid * 16 + s] = bi[s];
}

// KNN among the 512 keypoints themselves, k=16.
__global__ __launch_bounds__(256) void knn2_kernel(const float* __restrict__ new_xyz,
                                                   int* __restrict__ idxk) {
  int gid = blockIdx.x * 256 + threadIdx.x;
  int b = gid >> 9;
  const float* refs = new_xyz + (size_t)b * 512 * 3;
  float qx = new_xyz[gid * 3 + 0], qy = new_xyz[gid * 3 + 1], qz = new_xyz[gid * 3 + 2];
  float qq = qx * qx + qy * qy + qz * qz;
  float bd[16]; int bi[16];
#pragma unroll
  for (int s = 0; s < 16; ++s) { bd[s] = 3.0e38f; bi[s] = 0; }
  for (int j = 0; j < 512; ++j) {
    float rx = refs[j * 3 + 0], ry = refs[j * 3 + 1], rz = refs[j * 3 + 2];
    float rrv = rx * rx + ry * ry + rz * rz;
    float dot = qx * rx + qy * ry + qz * rz;
    float d = (qq - 2.0f * dot) + rrv;
    if (d < bd[15]) {
      float nd = d; int ni = j;
#pragma unroll
      for (int s = 0; s < 16; ++s) {
        bool sw = nd < bd[s];
        float ob = bd[s]; int oi = bi[s];
        bd[s] = sw ? nd : ob; bi[s] = sw ? ni : oi;
        nd = sw ? ob : nd; ni = sw ? oi : ni;
      }
    }
  }
#pragma unroll
  for (int s = 0; s < 16; ++s) idxk[(size_t)gid * 16 + s] = bi[s];
}

// ---------------------------------------------------------------------------
// SA: group + conv2d(6->64,relu) + conv2d(64->128) + max over 16 samples.
// One block (128 threads) per point. Output point-major (NPTS,128).
// ---------------------------------------------------------------------------
__global__ __launch_bounds__(128) void sa_kernel(const float* __restrict__ xyz_t,
                                                 const float* __restrict__ new_xyz,
                                                 const int* __restrict__ idx1,
                                                 const float* __restrict__ w1g,
                                                 const float* __restrict__ b1g,
                                                 const float* __restrict__ w2g,
                                                 const float* __restrict__ b2g,
                                                 float* __restrict__ kf_pm) {
  int pt = blockIdx.x;
  int tid = threadIdx.x;
  int b = pt >> 9;
  __shared__ float x6[16][6];
  __shared__ __align__(16) float h1[16][64];
  __shared__ float w1s[384], b1s[64], cs[3];
  for (int i = tid; i < 384; i += 128) w1s[i] = w1g[i];
  if (tid < 64) b1s[tid] = b1g[tid];
  if (tid < 3) cs[tid] = new_xyz[(size_t)pt * 3 + tid];
  __syncthreads();
  if (tid < 16) {
    int j = idx1[(size_t)pt * 16 + tid];
    const float* npn = xyz_t + (size_t)(b * 2048 + j) * 3;
    float nx = npn[0], ny = npn[1], nz = npn[2];
    x6[tid][0] = nx - cs[0]; x6[tid][1] = ny - cs[1]; x6[tid][2] = nz - cs[2];
    x6[tid][3] = nx; x6[tid][4] = ny; x6[tid][5] = nz;
  }
  __syncthreads();
  for (int e = tid; e < 1024; e += 128) {
    int s = e >> 6, cc = e & 63;
    float v = b1s[cc];
#pragma unroll
    for (int i = 0; i < 6; ++i) v += w1s[cc * 6 + i] * x6[s][i];
    h1[s][cc] = fmaxf(v, 0.0f);
  }
  __syncthreads();
  float wrow[64];
#pragma unroll
  for (int i = 0; i < 16; ++i) {
    float4 w4 = *(const float4*)(w2g + (size_t)tid * 64 + i * 4);
    wrow[i * 4 + 0] = w4.x; wrow[i * 4 + 1] = w4.y;
    wrow[i * 4 + 2] = w4.z; wrow[i * 4 + 3] = w4.w;
  }
  float bb = b2g[tid];
  float mx = -3.0e38f;
  for (int s = 0; s < 16; s += 2) {
    float a0 = 0.f, a1 = 0.f, c0 = 0.f, c1 = 0.f;
    const float4* hA = (const float4*)&h1[s][0];
    const float4* hB = (const float4*)&h1[s + 1][0];
#pragma unroll
    for (int i = 0; i < 16; ++i) {
      float4 ha = hA[i], hb = hB[i];
      a0 += wrow[i * 4 + 0] * ha.x + wrow[i * 4 + 1] * ha.y;
      a1 += wrow[i * 4 + 2] * ha.z + wrow[i * 4 + 3] * ha.w;
      c0 += wrow[i * 4 + 0] * hb.x + wrow[i * 4 + 1] * hb.y;
      c1 += wrow[i * 4 + 2] * hb.z + wrow[i * 4 + 3] * hb.w;
    }
    mx = fmaxf(mx, fmaxf(bb + (a0 + a1), bb + (c0 + c1)));
  }
  kf_pm[(size_t)pt * 128 + tid] = mx;
}

// ---------------------------------------------------------------------------
// qkv: x = start(kf) then q,k,v = Wq/Wk/Wv x. Weights (pre-transposed) in LDS.
// Block 256 = 4 waves, each wave handles 4 of the block's 16 points.
// ---------------------------------------------------------------------------
__global__ __launch_bounds__(256) void qkv_kernel(const float* __restrict__ kf_pm,
                                                  const float* __restrict__ wstT,
                                                  const float* __restrict__ wqT,
                                                  const float* __restrict__ wkT,
                                                  const float* __restrict__ wvT,
                                                  const float* __restrict__ bst,
                                                  const float* __restrict__ bq,
                                                  const float* __restrict__ bk,
                                                  const float* __restrict__ bv,
                                                  float* __restrict__ q_pm,
                                                  float* __restrict__ k_pm,
                                                  float* __restrict__ v_pm) {
  int t = threadIdx.x;
  int c = t & 63, g = t >> 6;
  __shared__ float wst[8192];
  __shared__ float wq[4096], wk[4096], wv[4096];
  __shared__ float bsts[64], bqs[64], bks[64], bvs[64];
  __shared__ __align__(16) float kfsh[4][128];
  __shared__ __align__(16) float xsh[4][64];
  for (int i = t; i < 8192; i += 256) wst[i] = wstT[i];
  for (int i = t; i < 4096; i += 256) { wq[i] = wqT[i]; wk[i] = wkT[i]; wv[i] = wvT[i]; }
  if (t < 64) { bsts[t] = bst[t]; bqs[t] = bq[t]; bks[t] = bk[t]; bvs[t] = bv[t]; }
  __syncthreads();
  for (int pi = g; pi < 16; pi += 4) {
    int pt = blockIdx.x * 16 + pi;
    kfsh[g][c] = kf_pm[(size_t)pt * 128 + c];
    kfsh[g][64 + c] = kf_pm[(size_t)pt * 128 + 64 + c];
    float a0 = bsts[c], a1 = 0.f, a2 = 0.f, a3 = 0.f;
    const float4* kf4 = (const float4*)&kfsh[g][0];
#pragma unroll
    for (int i = 0; i < 32; ++i) {
      float4 kv = kf4[i];
      a0 += kv.x * wst[(i * 4 + 0) * 64 + c];
      a1 += kv.y * wst[(i * 4 + 1) * 64 + c];
      a2 += kv.z * wst[(i * 4 + 2) * 64 + c];
      a3 += kv.w * wst[(i * 4 + 3) * 64 + c];
    }
    xsh[g][c] = (a0 + a1) + (a2 + a3);
    float q0 = bqs[c], q1 = 0.f, k0 = bks[c], k1 = 0.f, v0 = bvs[c], v1 = 0.f;
    const float4* x4 = (const float4*)&xsh[g][0];
#pragma unroll
    for (int i = 0; i < 16; ++i) {
      float4 xv = x4[i];
      q0 += xv.x * wq[(i * 4 + 0) * 64 + c] + xv.y * wq[(i * 4 + 1) * 64 + c];
      q1 += xv.z * wq[(i * 4 + 2) * 64 + c] + xv.w * wq[(i * 4 + 3) * 64 + c];
      k0 += xv.x * wk[(i * 4 + 0) * 64 + c] + xv.y * wk[(i * 4 + 1) * 64 + c];
      k1 += xv.z * wk[(i * 4 + 2) * 64 + c] + xv.w * wk[(i * 4 + 3) * 64 + c];
      v0 += xv.x * wv[(i * 4 + 0) * 64 + c] + xv.y * wv[(i * 4 + 1) * 64 + c];
      v1 += xv.z * wv[(i * 4 + 2) * 64 + c] + xv.w * wv[(i * 4 + 3) * 64 + c];
    }
    q_pm[(size_t)pt * 64 + c] = q0 + q1;
    k_pm[(size_t)pt * 64 + c] = k0 + k1;
    v_pm[(size_t)pt * 64 + c] = v0 + v1;
  }
}

// ---------------------------------------------------------------------------
// Fused point-transformer attention. 1 block = 16 points, 2 samples/iter.
// Hot weights live in registers (Wa1 row per thread o=t, Wa2 quarter-row,
// Wp2 half-row); activations broadcast via LDS (conflict-free).
// ---------------------------------------------------------------------------
__global__ __launch_bounds__(256, 2) void attn_kernel(
    const float* __restrict__ q_pm, const float* __restrict__ k_pm,
    const float* __restrict__ v_pm, const int* __restrict__ idx_knn,
    const float* __restrict__ new_xyz,
    const float* __restrict__ wa1, const float* __restrict__ ba1,
    const float* __restrict__ wa2, const float* __restrict__ ba2,
    const float* __restrict__ wp1, const float* __restrict__ bp1,
    const float* __restrict__ wp2, const float* __restrict__ bp2,
    float* __restrict__ agg_pm) {
  const int t = threadIdx.x;
  const int c = t & 63;
  const int g = t >> 6;
  const int si_b = g >> 1;  // sample served in pe-partial phase
  const int jq = g & 1;     // j-half served in pe-partial phase

  float w1r[64];
#pragma unroll
  for (int i = 0; i < 16; ++i) {
    float4 w4 = *(const float4*)(wa1 + (size_t)t * 64 + i * 4);
    w1r[i * 4 + 0] = w4.x; w1r[i * 4 + 1] = w4.y; w1r[i * 4 + 2] = w4.z; w1r[i * 4 + 3] = w4.w;
  }
  float w2r[64];
#pragma unroll
  for (int i = 0; i < 16; ++i) {
    float4 w4 = *(const float4*)(wa2 + (size_t)c * 256 + g * 64 + i * 4);
    w2r[i * 4 + 0] = w4.x; w2r[i * 4 + 1] = w4.y; w2r[i * 4 + 2] = w4.z; w2r[i * 4 + 3] = w4.w;
  }
  float wp2r[32];
#pragma unroll
  for (int i = 0; i < 8; ++i) {
    float4 w4 = *(const float4*)(wp2 + (size_t)c * 64 + jq * 32 + i * 4);
    wp2r[i * 4 + 0] = w4.x; wp2r[i * 4 + 1] = w4.y; wp2r[i * 4 + 2] = w4.z; wp2r[i * 4 + 3] = w4.w;
  }
  float wp1r0 = wp1[c * 3 + 0], wp1r1 = wp1[c * 3 + 1], wp1r2 = wp1[c * 3 + 2];
  float bp1r = bp1[c], bp2r = bp2[c], ba1r = ba1[t], ba2r = ba2[c];

  __shared__ __align__(16) float hs[2][64];
  __shared__ float kgs[2][64];
  __shared__ float pp[4][64];
  __shared__ __align__(16) float pl[2][4][64];
  __shared__ __align__(16) float tins[2][64];
  __shared__ __align__(16) float a1s[2][256];
  __shared__ float pes[16][64];
  __shared__ float lgs[16][64];
  __shared__ float qs[64], vs[64];
  __shared__ int idxs[16];
  __shared__ float p0s[4];

  for (int pi = 0; pi < 16; ++pi) {
    int pt = blockIdx.x * 16 + pi;
    int b = pt >> 9;
    __syncthreads();  // previous point's softmax readers done
    if (g == 0) qs[c] = q_pm[(size_t)pt * 64 + c];
    else if (g == 1) vs[c] = v_pm[(size_t)pt * 64 + c];
    else if (g == 2) { if (c < 16) idxs[c] = idx_knn[(size_t)pt * 16 + c]; }
    else { if (c < 3) p0s[c] = new_xyz[(size_t)pt * 3 + c]; }
    __syncthreads();

    for (int it = 0; it < 8; ++it) {
      // A: h (waves 0/1) + kg prefetch (waves 2/3)
      if (g < 2) {
        int s = it * 2 + g;
        int jn = idxs[s];
        const float* nb = new_xyz + (size_t)(b * 512 + jn) * 3;
        float prx = p0s[0] - nb[0];
        float pry = p0s[1] - nb[1];
        float prz = p0s[2] - nb[2];
        float h = bp1r + wp1r0 * prx + wp1r1 * pry + wp1r2 * prz;
        hs[g][c] = fmaxf(h, 0.0f);
      } else {
        int s = it * 2 + (g - 2);
        int jn = idxs[s];
        kgs[g - 2][c] = k_pm[(size_t)(b * 512 + jn) * 64 + c];
      }
      __syncthreads();
      // B: pe partial (all threads)
      {
        float s0 = 0.f, s1 = 0.f, s2 = 0.f, s3 = 0.f;
        const float4* h4 = (const float4*)&hs[si_b][jq * 32];
#pragma unroll
        for (int i = 0; i < 8; ++i) {
          float4 hv = h4[i];
          s0 += wp2r[i * 4 + 0] * hv.x;
          s1 += wp2r[i * 4 + 1] * hv.y;
          s2 += wp2r[i * 4 + 2] * hv.z;
          s3 += wp2r[i * 4 + 3] * hv.w;
        }
        pp[g][c] = (s0 + s1) + (s2 + s3);
      }
      __syncthreads();
      // C: finalize pe/tin (waves 0/1)
      if (g < 2) {
        int s = it * 2 + g;
        float pe = bp2r + pp[g * 2 + 0][c] + pp[g * 2 + 1][c];
        pes[s][c] = pe;
        tins[g][c] = qs[c] - kgs[g][c] + pe;
      }
      __syncthreads();
      // D: a1 = relu(Wa1 tin + b), o = t, both samples
#pragma unroll
      for (int si = 0; si < 2; ++si) {
        float s0 = 0.f, s1 = 0.f, s2 = 0.f, s3 = 0.f;
        const float4* t4 = (const float4*)&tins[si][0];
#pragma unroll
        for (int i = 0; i < 16; ++i) {
          float4 tv = t4[i];
          s0 += w1r[i * 4 + 0] * tv.x;
          s1 += w1r[i * 4 + 1] * tv.y;
          s2 += w1r[i * 4 + 2] * tv.z;
          s3 += w1r[i * 4 + 3] * tv.w;
        }
        a1s[si][t] = fmaxf(ba1r + (s0 + s1) + (s2 + s3), 0.0f);
      }
      __syncthreads();
      // E: logit partials (Wa2 quarter-row per thread)
#pragma unroll
      for (int si = 0; si < 2; ++si) {
        float s0 = 0.f, s1 = 0.f, s2 = 0.f, s3 = 0.f;
        const float4* a4 = (const float4*)&a1s[si][g * 64];
#pragma unroll
        for (int i = 0; i < 16; ++i) {
          float4 av = a4[i];
          s0 += w2r[i * 4 + 0] * av.x;
          s1 += w2r[i * 4 + 1] * av.y;
          s2 += w2r[i * 4 + 2] * av.z;
          s3 += w2r[i * 4 + 3] * av.w;
        }
        pl[si][g][c] = (s0 + s1) + (s2 + s3);
      }
      __syncthreads();
      // F: finalize logits (waves 0/1)
      if (g < 2) {
        int s = it * 2 + g;
        lgs[s][c] = ba2r + ((pl[g][0][c] + pl[g][1][c]) + (pl[g][2][c] + pl[g][3][c]));
      }
      __syncthreads();
    }
    // softmax over 16 samples + aggregation (wave 0)
    if (g == 0) {
      float m = lgs[0][c];
#pragma unroll
      for (int s = 1; s < 16; ++s) m = fmaxf(m, lgs[s][c]);
      float den = 0.f, acc = 0.f;
      float vv = vs[c];
#pragma unroll
      for (int s = 0; s < 16; ++s) {
        float e = expf(lgs[s][c] - m);
        den += e;
        acc += e * (vv + pes[s][c]);
      }
      agg_pm[(size_t)pt * 64 + c] = acc / den;
    }
  }
}

// ---------------------------------------------------------------------------
// kf_final = t_end(agg) + identity; also writes output2 (B,128,512).
// ---------------------------------------------------------------------------
__global__ __launch_bounds__(128) void kfend_kernel(const float* __restrict__ agg_pm,
                                                    const float* __restrict__ kf_pm,
                                                    const float* __restrict__ wend,
                                                    const float* __restrict__ bend,
                                                    float* __restrict__ kff,
                                                    float* __restrict__ out2) {
  int pt = blockIdx.x;
  int tid = threadIdx.x;
  __shared__ __align__(16) float aggs[64];
  if (tid < 64) aggs[tid] = agg_pm[(size_t)pt * 64 + tid];
  __syncthreads();
  float a0 = bend[tid], a1 = 0.f;
  const float4* ag4 = (const float4*)aggs;
#pragma unroll
  for (int i = 0; i < 16; ++i) {
    float4 w4 = *(const float4*)(wend + (size_t)tid * 64 + i * 4);
    float4 av = ag4[i];
    a0 += w4.x * av.x + w4.y * av.y;
    a1 += w4.z * av.z + w4.w * av.w;
  }
  float val = a0 + a1 + kf_pm[(size_t)pt * 128 + tid];
  kff[(size_t)pt * 128 + tid] = val;
  int b = pt >> 9, n = pt & 511;
  out2[(size_t)b * 65536 + (size_t)tid * 512 + n] = val;
}

// ---------------------------------------------------------------------------
// Generic fp32 GEMM: C[M,N] = act(A[M,K] * Bt[K,N] + bias[N]).
// 128x128 tile, BK=16, 8x8 register microtile, 256 threads.
// CONCAT: A = feat rows (stride 512) for k<512, gf rows for k>=512, K=1024.
// ---------------------------------------------------------------------------
template <int ACT, bool CONCAT>
__global__ __launch_bounds__(256) void gemm_kernel(const float* __restrict__ A,
                                                   const float* __restrict__ Bt,
                                                   const float* __restrict__ bias,
                                                   float* __restrict__ C,
                                                   int M, int N, int K,
                                                   const float* __restrict__ gf) {
  __shared__ __align__(16) float As[16][128];
  __shared__ __align__(16) float Bs[16][128];
  int t = threadIdx.x;
  int m0 = blockIdx.x * 128, n0 = blockIdx.y * 128;
  int tm = t >> 4, tn = t & 15;
  float acc[8][8];
#pragma unroll
  for (int i = 0; i < 8; ++i) {
#pragma unroll
    for (int j = 0; j < 8; ++j) acc[i][j] = 0.0f;
  }
  for (int k0 = 0; k0 < K; k0 += 16) {
#pragma unroll
    for (int i = 0; i < 2; ++i) {
      int lin = t * 2 + i;
      int mm = lin >> 2, kq = lin & 3;
      int kg = k0 + kq * 4;
      int m = m0 + mm;
      float4 av;
      if (CONCAT) {
        if (kg < 512) av = *(const float4*)(A + (size_t)m * 512 + kg);
        else av = *(const float4*)(gf + (size_t)(m >> 9) * 512 + (kg - 512));
      } else {
        av = *(const float4*)(A + (size_t)m * K + kg);
      }
      As[kq * 4 + 0][mm] = av.x;
      As[kq * 4 + 1][mm] = av.y;
      As[kq * 4 + 2][mm] = av.z;
      As[kq * 4 + 3][mm] = av.w;
      int kk = lin >> 5, nq = lin & 31;
      float4 bv = *(const float4*)(Bt + (size_t)(k0 + kk) * N + n0 + nq * 4);
      *(float4*)&Bs[kk][nq * 4] = bv;
    }
    __syncthreads();
#pragma unroll
    for (int kk = 0; kk < 16; ++kk) {
      float4 A0 = *(const float4*)&As[kk][tm * 8];
      float4 A1 = *(const float4*)&As[kk][tm * 8 + 4];
      float4 B0 = *(const float4*)&Bs[kk][tn * 8];
      float4 B1 = *(const float4*)&Bs[kk][tn * 8 + 4];
      float aa[8] = {A0.x, A0.y, A0.z, A0.w, A1.x, A1.y, A1.z, A1.w};
      float bb[8] = {B0.x, B0.y, B0.z, B0.w, B1.x, B1.y, B1.z, B1.w};
#pragma unroll
      for (int ii = 0; ii < 8; ++ii) {
#pragma unroll
        for (int jj = 0; jj < 8; ++jj) acc[ii][jj] += aa[ii] * bb[jj];
      }
    }
    __syncthreads();
  }
#pragma unroll
  for (int ii = 0; ii < 8; ++ii) {
    int m = m0 + tm * 8 + ii;
#pragma unroll
    for (int jj = 0; jj < 8; ++jj) {
      int n = n0 + tn * 8 + jj;
      float v = acc[ii][jj] + bias[n];
      if (ACT == 1) v = fmaxf(v, 0.0f);
      if (ACT == 2) v = (v >= 0.0f) ? v : 0.2f * v;
      C[(size_t)m * N + n] = v;
    }
  }
}

// global max over points per (batch, channel)
__global__ __launch_bounds__(256) void gf_kernel(const float* __restrict__ feat,
                                                 float* __restrict__ gf) {
  int gid = blockIdx.x * 256 + threadIdx.x;  // b*512 + cc
  int b = gid >> 9, cc = gid & 511;
  const float* fb = feat + (size_t)b * 512 * 512 + cc;
  float m = -3.0e38f;
  for (int n = 0; n < 512; ++n) m = fmaxf(m, fb[(size_t)n * 512]);
  gf[gid] = m;
}

// ---------------------------------------------------------------------------
// mlp4 (128->12) + R/T split + sym + output assembly (coarse, sym).
// ---------------------------------------------------------------------------
__global__ __launch_bounds__(256) void final_kernel(const float* __restrict__ m3,
                                                    const float* __restrict__ w4,
                                                    const float* __restrict__ b4,
                                                    const float* __restrict__ new_xyz,
                                                    float* __restrict__ out0,
                                                    float* __restrict__ out1) {
  int gid = blockIdx.x * 256 + threadIdx.x;
  __shared__ float w4s[1536];
  __shared__ float b4s[12];
  for (int i = threadIdx.x; i < 1536; i += 256) w4s[i] = w4[i];
  if (threadIdx.x < 12) b4s[threadIdx.x] = b4[threadIdx.x];
  __syncthreads();
  float acc[12];
#pragma unroll
  for (int o = 0; o < 12; ++o) acc[o] = b4s[o];
  const float4* row = (const float4*)(m3 + (size_t)gid * 128);
#pragma unroll 8
  for (int iq = 0; iq < 32; ++iq) {
    float4 xv = row[iq];
#pragma unroll
    for (int o = 0; o < 12; ++o) {
      acc[o] += xv.x * w4s[o * 128 + iq * 4 + 0] + xv.y * w4s[o * 128 + iq * 4 + 1] +
                xv.z * w4s[o * 128 + iq * 4 + 2] + xv.w * w4s[o * 128 + iq * 4 + 3];
    }
  }
  float kx = new_xyz[(size_t)gid * 3 + 0];
  float ky = new_xyz[(size_t)gid * 3 + 1];
  float kz = new_xyz[(size_t)gid * 3 + 2];
  int b = gid >> 9, n = gid & 511;
#pragma unroll
  for (int d = 0; d < 3; ++d) {
    float s = kx * acc[d] + ky * acc[3 + d] + kz * acc[6 + d] + acc[9 + d];
    float kp = (d == 0) ? kx : ((d == 1) ? ky : kz);
    out0[(size_t)b * 3072 + (size_t)d * 1024 + n] = s;
    out0[(size_t)b * 3072 + (size_t)d * 1024 + 512 + n] = kp;
    out1[(size_t)b * 1536 + (size_t)d * 512 + n] = s;
  }
}

// ---------------------------------------------------------------------------
extern "C" void kernel_launch(void* const* d_in, const int* in_sizes, int n_in,
                              void* d_out, int out_size, void* d_ws, size_t ws_size,
                              hipStream_t stream) {
  (void)in_sizes; (void)n_in; (void)out_size; (void)ws_size;
  const float* pc        = (const float*)d_in[0];
  const float* sa_w1     = (const float*)d_in[1];
  const float* sa_b1     = (const float*)d_in[2];
  const float* sa_w2     = (const float*)d_in[3];
  const float* sa_b2     = (const float*)d_in[4];
  const float* t_start_w = (const float*)d_in[5];
  const float* t_start_b = (const float*)d_in[6];
  const float* t_q_w     = (const float*)d_in[7];
  const float* t_q_b     = (const float*)d_in[8];
  const float* t_k_w     = (const float*)d_in[9];
  const float* t_k_b     = (const float*)d_in[10];
  const float* t_v_w     = (const float*)d_in[11];
  const float* t_v_b     = (const float*)d_in[12];
  const float* t_pos_w1  = (const float*)d_in[13];
  const float* t_pos_b1  = (const float*)d_in[14];
  const float* t_pos_w2  = (const float*)d_in[15];
  const float* t_pos_b2  = (const float*)d_in[16];
  const float* t_attn_w1 = (const float*)d_in[17];
  const float* t_attn_b1 = (const float*)d_in[18];
  const float* t_attn_w2 = (const float*)d_in[19];
  const float* t_attn_b2 = (const float*)d_in[20];
  const float* t_end_w   = (const float*)d_in[21];
  const float* t_end_b   = (const float*)d_in[22];
  const float* exp_w1    = (const float*)d_in[23];
  const float* exp_b1    = (const float*)d_in[24];
  const float* exp_w2    = (const float*)d_in[25];
  const float* exp_b2    = (const float*)d_in[26];
  const float* mlp_w1    = (const float*)d_in[27];
  const float* mlp_b1    = (const float*)d_in[28];
  const float* mlp_w2    = (const float*)d_in[29];
  const float* mlp_b2    = (const float*)d_in[30];
  const float* mlp_w3    = (const float*)d_in[31];
  const float* mlp_b3    = (const float*)d_in[32];
  const float* mlp_w4    = (const float*)d_in[33];
  const float* mlp_b4    = (const float*)d_in[34];

  float* ws = (float*)d_ws;
  float* out = (float*)d_out;
  float* out0 = out;            // coarse (32,3,1024)
  float* out1 = out + 98304;    // sym    (32,3,512)
  float* out2 = out + 147456;   // keyfeatures (32,128,512)

  prep_kernel<<<3664, 256, 0, stream>>>(pc, t_start_w, t_q_w, t_k_w, t_v_w,
                                        exp_w1, exp_w2, mlp_w1, mlp_w2, mlp_w3, ws);
  fps_kernel<<<32, 256, 0, stream>>>(ws + WS_XYZT, ws + WS_NEWXYZ);
  knn1_kernel<<<64, 256, 0, stream>>>(ws + WS_XYZT, ws + WS_RR, ws + WS_NEWXYZ,
                                      (int*)(ws + WS_IDX1));
  sa_kernel<<<16384, 128, 0, stream>>>(ws + WS_XYZT, ws + WS_NEWXYZ,
                                       (const int*)(ws + WS_IDX1),
                                       sa_w1, sa_b1, sa_w2, sa_b2, ws + WS_KF);
  knn2_kernel<<<64, 256, 0, stream>>>(ws + WS_NEWXYZ, (int*)(ws + WS_IDXK));
  qkv_kernel<<<1024, 256, 0, stream>>>(ws + WS_KF, ws + WS_WT_START, ws + WS_WT_Q,
                                       ws + WS_WT_K, ws + WS_WT_V,
                                       t_start_b, t_q_b, t_k_b, t_v_b,
                                       ws + WS_Q, ws + WS_K, ws + WS_V);
  attn_kernel<<<1024, 256, 0, stream>>>(ws + WS_Q, ws + WS_K, ws + WS_V,
                                        (const int*)(ws + WS_IDXK), ws + WS_NEWXYZ,
                                        t_attn_w1, t_attn_b1, t_attn_w2, t_attn_b2,
                                        t_pos_w1, t_pos_b1, t_pos_w2, t_pos_b2,
                                        ws + WS_AGG);
  kfend_kernel<<<16384, 128, 0, stream>>>(ws + WS_AGG, ws + WS_KF, t_end_w, t_end_b,
                                          ws + WS_KFF, out2);
  gemm_kernel<1, false><<<dim3(128, 2), 256, 0, stream>>>(ws + WS_KFF, ws + WS_WT_E1,
                                                          exp_b1, ws + WS_E1,
                                                          NPTS, 256, 128, nullptr);
  gemm_kernel<0, false><<<dim3(128, 4), 256, 0, stream>>>(ws + WS_E1, ws + WS_WT_E2,
                                                          exp_b2, ws + WS_FEAT,
                                                          NPTS, 512, 256, nullptr);
  gf_kernel<<<64, 256, 0, stream>>>(ws + WS_FEAT, ws + WS_GF);
  gemm_kernel<2, true><<<dim3(128, 4), 256, 0, stream>>>(ws + WS_FEAT, ws + WS_WT_M1,
                                                         mlp_b1, ws + WS_M1,
                                                         NPTS, 512, 1024, ws + WS_GF);
  gemm_kernel<2, false><<<dim3(128, 2), 256, 0, stream>>>(ws + WS_M1, ws + WS_WT_M2,
                                                          mlp_b2, ws + WS_M2,
                                                          NPTS, 256, 512, nullptr);
  gemm_kernel<2, false><<<dim3(128, 1), 256, 0, stream>>>(ws + WS_M2, ws + WS_WT_M3,
                                                          mlp_b3, ws + WS_M3,
                                                          NPTS, 128, 256, nullptr);
  final_kernel<<<64, 256, 0, stream>>>(ws + WS_M3, mlp_w4, mlp_b4, ws + WS_NEWXYZ,
                                       out0, out1);
}

// Round 2
// 2371.456 us; speedup vs baseline: 1.1866x; 1.1866x over previous
//
#include <hip/hip_runtime.h>
#include <math.h>

// ---------------------------------------------------------------------------
// LSTNet on MI355X — round 1: MFMA-based fused point-transformer attention.
// Everything else unchanged from round 0. Workspace: 90.8 MB.
// ---------------------------------------------------------------------------

#define B_ 32
#define N_ 2048
#define NPOINT 512
#define NSAMPLE 16
#define NKNN 16
#define NPTS (B_ * NPOINT)   // 16384

// ---- workspace layout (float offsets) ----
#define WS_WT_START 0         // 128x64   (8192)
#define WS_WT_Q     8192      // 64x64    (4096)
#define WS_WT_K     12288
#define WS_WT_V     16384
#define WS_WT_E1    20480     // 128x256  (32768)
#define WS_WT_E2    53248     // 256x512  (131072)
#define WS_WT_M1    184320    // 1024x512 (524288)
#define WS_WT_M2    708608    // 512x256  (131072)
#define WS_WT_M3    839680    // 256x128  (32768)
#define WS_XYZT     872448    // (B,2048,3) 196608
#define WS_RR       1069056   // (B,2048)   65536
#define WS_NEWXYZ   1134592   // (B,512,3)  49152
#define WS_IDX1     1183744   // int (B,512,16) 262144
#define WS_IDXK     1445888   // int (B,512,16) 262144
#define WS_KF       1708032   // (NPTS,128) 2097152
#define WS_Q        3805184   // (NPTS,64)  1048576
#define WS_K        4853760
#define WS_V        5902336
#define WS_AGG      6950912
#define WS_KFF      7999488   // (NPTS,128) 2097152
#define WS_E1       10096640  // (NPTS,256) 4194304
#define WS_FEAT     14290944  // (NPTS,512) 8388608
#define WS_GF       22679552  // (B,512)    16384
#define WS_TOTAL    22695936
// reuse (dead by the time they're written):
#define WS_M1       WS_KF     // (NPTS,512) overlays kf..kff exactly
#define WS_M2       WS_E1
#define WS_M3       WS_FEAT
// attention weight fragments (bf16) live in the KFF region: dead until kfend,
// attn (the only reader) runs before kfend writes KFF.
#define WS_WFRAG    WS_KFF    // 36864 bf16 = 73728 B (w1f 16384 | w2f 16384 | wpf 4096)

typedef __attribute__((ext_vector_type(8))) short bf16x8;
typedef __attribute__((ext_vector_type(4))) float f32x4;

__device__ __forceinline__ unsigned short f2bf(float f) {
  unsigned u = __float_as_uint(f);
  u += 0x7fff + ((u >> 16) & 1);  // RNE
  return (unsigned short)(u >> 16);
}

#define MFMA16(a, b, c) __builtin_amdgcn_mfma_f32_16x16x32_bf16((a), (b), (c), 0, 0, 0)
#define LDS_FENCE() __asm__ volatile("" ::: "memory")

// ---------------------------------------------------------------------------
// prep: xyz transpose + |r|^2 + 9 weight transposes.
// ---------------------------------------------------------------------------
__global__ __launch_bounds__(256) void prep_kernel(
    const float* __restrict__ pc,
    const float* __restrict__ w_start, const float* __restrict__ w_q,
    const float* __restrict__ w_k, const float* __restrict__ w_v,
    const float* __restrict__ w_e1, const float* __restrict__ w_e2,
    const float* __restrict__ w_m1, const float* __restrict__ w_m2,
    const float* __restrict__ w_m3, float* __restrict__ ws) {
  int f = blockIdx.x * 256 + threadIdx.x;
  if (f < 65536) {  // xyz_t + rr
    int b = f >> 11, j = f & 2047;
    const float* base = pc + (size_t)b * 3 * 2048;
    float x = base[j], y = base[2048 + j], z = base[4096 + j];
    float* xt = ws + WS_XYZT + (size_t)f * 3;
    xt[0] = x; xt[1] = y; xt[2] = z;
    ws[WS_RR + f] = x * x + y * y + z * z;
    return;
  }
  int u = f - 65536;
  if (u < 8192)  { int k = u >> 6, n = u & 63;  ws[WS_WT_START + u] = w_start[n * 128 + k]; return; }
  u -= 8192;
  if (u < 4096)  { int k = u >> 6, n = u & 63;  ws[WS_WT_Q + u] = w_q[n * 64 + k]; return; }
  u -= 4096;
  if (u < 4096)  { int k = u >> 6, n = u & 63;  ws[WS_WT_K + u] = w_k[n * 64 + k]; return; }
  u -= 4096;
  if (u < 4096)  { int k = u >> 6, n = u & 63;  ws[WS_WT_V + u] = w_v[n * 64 + k]; return; }
  u -= 4096;
  if (u < 32768) { int k = u >> 8, n = u & 255; ws[WS_WT_E1 + u] = w_e1[n * 128 + k]; return; }
  u -= 32768;
  if (u < 131072){ int k = u >> 9, n = u & 511; ws[WS_WT_E2 + u] = w_e2[n * 256 + k]; return; }
  u -= 131072;
  if (u < 524288){ int k = u >> 9, n = u & 511; ws[WS_WT_M1 + u] = w_m1[n * 1024 + k]; return; }
  u -= 524288;
  if (u < 131072){ int k = u >> 8, n = u & 255; ws[WS_WT_M2 + u] = w_m2[n * 512 + k]; return; }
  u -= 131072;
  if (u < 32768) { int k = u >> 7, n = u & 127; ws[WS_WT_M3 + u] = w_m3[n * 256 + k]; return; }
}

// ---------------------------------------------------------------------------
// wfrag: pack attention weights into MFMA B-fragment order (bf16).
// B-frag for 16x16x32: lane l holds B[k = kt*32 + (l>>4)*8 + j][n = nt*16 + (l&15)].
// For Wt[k][n] = w[n][k] the 8 j-elements are contiguous in w's row n.
// w1f: (kt<2, nt<16) of W1t(64x256)   w2f: (kt<8, nt<4) of W2t(256x64)
// wpf: (kt<2, nt<4)  of Wp2t(64x64)
// ---------------------------------------------------------------------------
__global__ __launch_bounds__(256) void wfrag_kernel(const float* __restrict__ w1,
                                                    const float* __restrict__ w2,
                                                    const float* __restrict__ wp2,
                                                    unsigned short* __restrict__ wf) {
  int t = blockIdx.x * 256 + threadIdx.x;
  const float* src;
  unsigned short* dst;
  if (t < 2048) {            // w1f: t = (kt*16+nt)*64 + l
    int l = t & 63, nt = (t >> 6) & 15, kt = t >> 10;
    int n = nt * 16 + (l & 15);
    int kb = kt * 32 + ((l >> 4) & 3) * 8;
    src = w1 + n * 64 + kb;
    dst = wf + t * 8;
  } else if (t < 4096) {     // w2f: u = (kt*4+nt)*64 + l
    int u = t - 2048;
    int l = u & 63, nt = (u >> 6) & 3, kt = u >> 8;
    int n = nt * 16 + (l & 15);
    int kb = kt * 32 + ((l >> 4) & 3) * 8;
    src = w2 + n * 256 + kb;
    dst = wf + 16384 + u * 8;
  } else if (t < 4608) {     // wpf
    int u = t - 4096;
    int l = u & 63, nt = (u >> 6) & 3, kt = u >> 8;
    int n = nt * 16 + (l & 15);
    int kb = kt * 32 + ((l >> 4) & 3) * 8;
    src = wp2 + n * 64 + kb;
    dst = wf + 32768 + u * 8;
  } else {
    return;
  }
#pragma unroll
  for (int j = 0; j < 8; ++j) dst[j] = f2bf(src[j]);
}

// ---------------------------------------------------------------------------
// FPS: 1 block per batch.
// ---------------------------------------------------------------------------
__global__ __launch_bounds__(256) void fps_kernel(const float* __restrict__ xyz_t,
                                                  float* __restrict__ new_xyz) {
  int b = blockIdx.x;
  int tid = threadIdx.x;
  const float* xb = xyz_t + (size_t)b * 2048 * 3;
  float px[8], py[8], pz[8], md[8];
#pragma unroll
  for (int r = 0; r < 8; ++r) {
    int j = tid + r * 256;
    px[r] = xb[j * 3 + 0]; py[r] = xb[j * 3 + 1]; pz[r] = xb[j * 3 + 2];
    md[r] = 1e10f;
  }
  __shared__ float wv_[4];
  __shared__ int wi_[4];
  __shared__ int sfar;
  int far = 0;
  for (int i = 0; i < 512; ++i) {
    float cx = xb[far * 3 + 0], cy = xb[far * 3 + 1], cz = xb[far * 3 + 2];
    if (tid == 0) {
      float* o = new_xyz + (size_t)(b * 512 + i) * 3;
      o[0] = cx; o[1] = cy; o[2] = cz;
    }
    float bv = -1.0f; int bj = 0;
#pragma unroll
    for (int r = 0; r < 8; ++r) {
      float dx = px[r] - cx, dy = py[r] - cy, dz = pz[r] - cz;
      float d = dx * dx + dy * dy + dz * dz;
      md[r] = fminf(md[r], d);
      if (md[r] > bv) { bv = md[r]; bj = tid + r * 256; }
    }
#pragma unroll
    for (int off = 32; off > 0; off >>= 1) {
      float ov = __shfl_down(bv, off);
      int oj = __shfl_down(bj, off);
      if (ov > bv || (ov == bv && oj < bj)) { bv = ov; bj = oj; }
    }
    int w = tid >> 6;
    if ((tid & 63) == 0) { wv_[w] = bv; wi_[w] = bj; }
    __syncthreads();
    if (tid == 0) {
      float fv = wv_[0]; int fj = wi_[0];
      for (int ww = 1; ww < 4; ++ww)
        if (wv_[ww] > fv || (wv_[ww] == fv && wi_[ww] < fj)) { fv = wv_[ww]; fj = wi_[ww]; }
      sfar = fj;
    }
    __syncthreads();
    far = sfar;
  }
}

// ---------------------------------------------------------------------------
// KNN 512 queries vs 2048 refs, k=16.
// ---------------------------------------------------------------------------
__global__ __launch_bounds__(256) void knn1_kernel(const float* __restrict__ xyz_t,
                                                   const float* __restrict__ rr,
                                                   const float* __restrict__ new_xyz,
                                                   int* __restrict__ idx1) {
  int gid = blockIdx.x * 256 + threadIdx.x;
  int b = gid >> 9;
  const float* refs = xyz_t + (size_t)b * 2048 * 3;
  const float* rrb = rr + (size_t)b * 2048;
  float qx = new_xyz[gid * 3 + 0], qy = new_xyz[gid * 3 + 1], qz = new_xyz[gid * 3 + 2];
  float qq = qx * qx + qy * qy + qz * qz;
  float bd[16]; int bi[16];
#pragma unroll
  for (int s = 0; s < 16; ++s) { bd[s] = 3.0e38f; bi[s] = 0; }
  for (int j = 0; j < 2048; ++j) {
    float rx = refs[j * 3 + 0], ry = refs[j * 3 + 1], rz = refs[j * 3 + 2];
    float dot = qx * rx + qy * ry + qz * rz;
    float d = (qq - 2.0f * dot) + rrb[j];
    if (d < bd[15]) {
      float nd = d; int ni = j;
#pragma unroll
      for (int s = 0; s < 16; ++s) {
        bool sw = nd < bd[s];
        float ob = bd[s]; int oi = bi[s];
        bd[s] = sw ? nd : ob; bi[s] = sw ? ni : oi;
        nd = sw ? ob : nd; ni = sw ? oi : ni;
      }
    }
  }
#pragma unroll
  for (int s = 0; s < 16; ++s) idx1[(size_t)gid * 16 + s] = bi[s];
}

__global__ __launch_bounds__(256) void knn2_kernel(const float* __restrict__ new_xyz,
                                                   int* __restrict__ idxk) {
  int gid = blockIdx.x * 256 + threadIdx.x;
  int b = gid >> 9;
  const float* refs = new_xyz + (size_t)b * 512 * 3;
  float qx = new_xyz[gid * 3 + 0], qy = new_xyz[gid * 3 + 1], qz = new_xyz[gid * 3 + 2];
  float qq = qx * qx + qy * qy + qz * qz;
  float bd[16]; int bi[16];
#pragma unroll
  for (int s = 0; s < 16; ++s) { bd[s] = 3.0e38f; bi[s] = 0; }
  for (int j = 0; j < 512; ++j) {
    float rx = refs[j * 3 + 0], ry = refs[j * 3 + 1], rz = refs[j * 3 + 2];
    float rrv = rx * rx + ry * ry + rz * rz;
    float dot = qx * rx + qy * ry + qz * rz;
    float d = (qq - 2.0f * dot) + rrv;
    if (d < bd[15]) {
      float nd = d; int ni = j;
#pragma unroll
      for (int s = 0; s < 16; ++s) {
        bool sw = nd < bd[s];
        float ob = bd[s]; int oi = bi[s];
        bd[s] = sw ? nd : ob; bi[s] = sw ? ni : oi;
        nd = sw ? ob : nd; ni = sw ? oi : ni;
      }
    }
  }
#pragma unroll
  for (int s = 0; s < 16; ++s) idxk[(size_t)gid * 16 + s] = bi[s];
}

// ---------------------------------------------------------------------------
// SA: group + conv2d(6->64,relu) + conv2d(64->128) + max over 16 samples.
// ---------------------------------------------------------------------------
__global__ __launch_bounds__(128) void sa_kernel(const float* __restrict__ xyz_t,
                                                 const float* __restrict__ new_xyz,
                                                 const int* __restrict__ idx1,
                                                 const float* __restrict__ w1g,
                                                 const float* __restrict__ b1g,
                                                 const float* __restrict__ w2g,
                                                 const float* __restrict__ b2g,
                                                 float* __restrict__ kf_pm) {
  int pt = blockIdx.x;
  int tid = threadIdx.x;
  int b = pt >> 9;
  __shared__ float x6[16][6];
  __shared__ __align__(16) float h1[16][64];
  __shared__ float w1s[384], b1s[64], cs[3];
  for (int i = tid; i < 384; i += 128) w1s[i] = w1g[i];
  if (tid < 64) b1s[tid] = b1g[tid];
  if (tid < 3) cs[tid] = new_xyz[(size_t)pt * 3 + tid];
  __syncthreads();
  if (tid < 16) {
    int j = idx1[(size_t)pt * 16 + tid];
    const float* npn = xyz_t + (size_t)(b * 2048 + j) * 3;
    float nx = npn[0], ny = npn[1], nz = npn[2];
    x6[tid][0] = nx - cs[0]; x6[tid][1] = ny - cs[1]; x6[tid][2] = nz - cs[2];
    x6[tid][3] = nx; x6[tid][4] = ny; x6[tid][5] = nz;
  }
  __syncthreads();
  for (int e = tid; e < 1024; e += 128) {
    int s = e >> 6, cc = e & 63;
    float v = b1s[cc];
#pragma unroll
    for (int i = 0; i < 6; ++i) v += w1s[cc * 6 + i] * x6[s][i];
    h1[s][cc] = fmaxf(v, 0.0f);
  }
  __syncthreads();
  float wrow[64];
#pragma unroll
  for (int i = 0; i < 16; ++i) {
    float4 w4 = *(const float4*)(w2g + (size_t)tid * 64 + i * 4);
    wrow[i * 4 + 0] = w4.x; wrow[i * 4 + 1] = w4.y;
    wrow[i * 4 + 2] = w4.z; wrow[i * 4 + 3] = w4.w;
  }
  float bb = b2g[tid];
  float mx = -3.0e38f;
  for (int s = 0; s < 16; s += 2) {
    float a0 = 0.f, a1 = 0.f, c0 = 0.f, c1 = 0.f;
    const float4* hA = (const float4*)&h1[s][0];
    const float4* hB = (const float4*)&h1[s + 1][0];
#pragma unroll
    for (int i = 0; i < 16; ++i) {
      float4 ha = hA[i], hb = hB[i];
      a0 += wrow[i * 4 + 0] * ha.x + wrow[i * 4 + 1] * ha.y;
      a1 += wrow[i * 4 + 2] * ha.z + wrow[i * 4 + 3] * ha.w;
      c0 += wrow[i * 4 + 0] * hb.x + wrow[i * 4 + 1] * hb.y;
      c1 += wrow[i * 4 + 2] * hb.z + wrow[i * 4 + 3] * hb.w;
    }
    mx = fmaxf(mx, fmaxf(bb + (a0 + a1), bb + (c0 + c1)));
  }
  kf_pm[(size_t)pt * 128 + tid] = mx;
}

// ---------------------------------------------------------------------------
// qkv
// ---------------------------------------------------------------------------
__global__ __launch_bounds__(256) void qkv_kernel(const float* __restrict__ kf_pm,
                                                  const float* __restrict__ wstT,
                                                  const float* __restrict__ wqT,
                                                  const float* __restrict__ wkT,
                                                  const float* __restrict__ wvT,
                                                  const float* __restrict__ bst,
                                                  const float* __restrict__ bq,
                                                  const float* __restrict__ bk,
                                                  const float* __restrict__ bv,
                                                  float* __restrict__ q_pm,
                                                  float* __restrict__ k_pm,
                                                  float* __restrict__ v_pm) {
  int t = threadIdx.x;
  int c = t & 63, g = t >> 6;
  __shared__ float wst[8192];
  __shared__ float wq[4096], wk[4096], wv[4096];
  __shared__ float bsts[64], bqs[64], bks[64], bvs[64];
  __shared__ __align__(16) float kfsh[4][128];
  __shared__ __align__(16) float xsh[4][64];
  for (int i = t; i < 8192; i += 256) wst[i] = wstT[i];
  for (int i = t; i < 4096; i += 256) { wq[i] = wqT[i]; wk[i] = wkT[i]; wv[i] = wvT[i]; }
  if (t < 64) { bsts[t] = bst[t]; bqs[t] = bq[t]; bks[t] = bk[t]; bvs[t] = bv[t]; }
  __syncthreads();
  for (int pi = g; pi < 16; pi += 4) {
    int pt = blockIdx.x * 16 + pi;
    kfsh[g][c] = kf_pm[(size_t)pt * 128 + c];
    kfsh[g][64 + c] = kf_pm[(size_t)pt * 128 + 64 + c];
    float a0 = bsts[c], a1 = 0.f, a2 = 0.f, a3 = 0.f;
    const float4* kf4 = (const float4*)&kfsh[g][0];
#pragma unroll
    for (int i = 0; i < 32; ++i) {
      float4 kv = kf4[i];
      a0 += kv.x * wst[(i * 4 + 0) * 64 + c];
      a1 += kv.y * wst[(i * 4 + 1) * 64 + c];
      a2 += kv.z * wst[(i * 4 + 2) * 64 + c];
      a3 += kv.w * wst[(i * 4 + 3) * 64 + c];
    }
    xsh[g][c] = (a0 + a1) + (a2 + a3);
    float q0 = bqs[c], q1 = 0.f, k0 = bks[c], k1 = 0.f, v0 = bvs[c], v1 = 0.f;
    const float4* x4 = (const float4*)&xsh[g][0];
#pragma unroll
    for (int i = 0; i < 16; ++i) {
      float4 xv = x4[i];
      q0 += xv.x * wq[(i * 4 + 0) * 64 + c] + xv.y * wq[(i * 4 + 1) * 64 + c];
      q1 += xv.z * wq[(i * 4 + 2) * 64 + c] + xv.w * wq[(i * 4 + 3) * 64 + c];
      k0 += xv.x * wk[(i * 4 + 0) * 64 + c] + xv.y * wk[(i * 4 + 1) * 64 + c];
      k1 += xv.z * wk[(i * 4 + 2) * 64 + c] + xv.w * wk[(i * 4 + 3) * 64 + c];
      v0 += xv.x * wv[(i * 4 + 0) * 64 + c] + xv.y * wv[(i * 4 + 1) * 64 + c];
      v1 += xv.z * wv[(i * 4 + 2) * 64 + c] + xv.w * wv[(i * 4 + 3) * 64 + c];
    }
    q_pm[(size_t)pt * 64 + c] = q0 + q1;
    k_pm[(size_t)pt * 64 + c] = k0 + k1;
    v_pm[(size_t)pt * 64 + c] = v0 + v1;
  }
}

// ---------------------------------------------------------------------------
// MFMA attention: one wave per point (4 points sequentially per wave).
// Per point: pe = relu-MLP -> MFMA(16x64x64); tin = q-kg+pe;
// a1 = relu(MFMA(16x256x64)); logits = MFMA(16x64x256); softmax over quads
// (s = quad*4+reg in C-layout); agg = sum attn*(v+pe).
// No __syncthreads in the point loop — all LDS traffic is wave-private
// (intra-wave DS ops complete in order).
// A-layout: A[m=lane&15][k=(lane>>4)*8+j]; C-layout: col=lane&15, row=(lane>>4)*4+reg.
// ---------------------------------------------------------------------------
__global__ __launch_bounds__(256) void attn_mfma_kernel(
    const float* __restrict__ q_pm, const float* __restrict__ k_pm,
    const float* __restrict__ v_pm, const int* __restrict__ idx_knn,
    const float* __restrict__ new_xyz,
    const unsigned short* __restrict__ wfrag,
    const float* __restrict__ ba1, const float* __restrict__ ba2,
    const float* __restrict__ wp1, const float* __restrict__ bp1,
    const float* __restrict__ bp2,
    float* __restrict__ agg_pm) {
  const int t = threadIdx.x;
  const int w = t >> 6, l = t & 63;
  const int x = l & 15, quad = l >> 4;
  const unsigned short* w1f = wfrag;
  const unsigned short* w2f = wfrag + 16384;
  const unsigned short* wpf = wfrag + 32768;

  __shared__ float4 wp14[64];                       // (w0,w1,w2,bias) per hidden ch
  __shared__ float bp2s[64], ba2s[64], ba1s[256];
  __shared__ __align__(16) float pebuf[4][16 * 68];          // per-wave pe (f32, padded)
  __shared__ __align__(16) unsigned short a1buf[4][16 * 264];// per-wave a1 (bf16, padded)

  if (t < 64) wp14[t] = make_float4(wp1[t * 3], wp1[t * 3 + 1], wp1[t * 3 + 2], bp1[t]);
  else if (t < 128) bp2s[t - 64] = bp2[t - 64];
  else if (t < 192) ba2s[t - 128] = ba2[t - 128];
  if (t < 256) ba1s[t] = ba1[t];
  __syncthreads();

  float* pew = pebuf[w];
  unsigned short* a1w = a1buf[w];
  const f32x4 zero = {0.f, 0.f, 0.f, 0.f};

  for (int pi = 0; pi < 4; ++pi) {
    int pt = blockIdx.x * 16 + w * 4 + pi;
    int b = pt >> 9;
    int jn = idx_knn[(size_t)pt * 16 + x];   // neighbor for sample s = x
    const float* nb = new_xyz + (size_t)(b * 512 + jn) * 3;
    const float* p0 = new_xyz + (size_t)pt * 3;
    float prx = p0[0] - nb[0], pry = p0[1] - nb[1], prz = p0[2] - nb[2];

    // h fragments (A-layout, computed directly per lane)
    bf16x8 hA0, hA1;
#pragma unroll
    for (int j = 0; j < 8; ++j) {
      float4 cf = wp14[quad * 8 + j];
      hA0[j] = (short)f2bf(fmaxf(cf.w + cf.x * prx + cf.y * pry + cf.z * prz, 0.0f));
      float4 cg = wp14[32 + quad * 8 + j];
      hA1[j] = (short)f2bf(fmaxf(cg.w + cg.x * prx + cg.y * pry + cg.z * prz, 0.0f));
    }
    // pe = h @ Wp2t + bp2   (16x64, K=64)
    f32x4 pacc[4];
#pragma unroll
    for (int nt = 0; nt < 4; ++nt) {
      bf16x8 b0 = *(const bf16x8*)(wpf + nt * 512 + l * 8);
      bf16x8 b1 = *(const bf16x8*)(wpf + (4 + nt) * 512 + l * 8);
      f32x4 z = MFMA16(hA0, b0, zero);
      pacc[nt] = MFMA16(hA1, b1, z);
    }
    float pev[4][4];  // C-layout pe (+bias), kept for aggregation
#pragma unroll
    for (int nt = 0; nt < 4; ++nt) {
      float bb = bp2s[nt * 16 + x];
#pragma unroll
      for (int r = 0; r < 4; ++r) {
        float pe = pacc[nt][r] + bb;
        pev[nt][r] = pe;
        pew[(quad * 4 + r) * 68 + nt * 16 + x] = pe;  // row s, col c
      }
    }
    LDS_FENCE();

    // tin = q - kg + pe, assembled in A-layout (row s=x, k = channel)
    const float* qp = q_pm + (size_t)pt * 64;
    const float* kgp = k_pm + (size_t)(b * 512 + jn) * 64;
    const float* per = pew + x * 68;
    float4 q0a = *(const float4*)(qp + quad * 8);
    float4 q0b = *(const float4*)(qp + quad * 8 + 4);
    float4 q1a = *(const float4*)(qp + 32 + quad * 8);
    float4 q1b = *(const float4*)(qp + 32 + quad * 8 + 4);
    float4 k0a = *(const float4*)(kgp + quad * 8);
    float4 k0b = *(const float4*)(kgp + quad * 8 + 4);
    float4 k1a = *(const float4*)(kgp + 32 + quad * 8);
    float4 k1b = *(const float4*)(kgp + 32 + quad * 8 + 4);
    float4 p0a = *(const float4*)(per + quad * 8);
    float4 p0b = *(const float4*)(per + quad * 8 + 4);
    float4 p1a = *(const float4*)(per + 32 + quad * 8);
    float4 p1b = *(const float4*)(per + 32 + quad * 8 + 4);
    bf16x8 tA0, tA1;
    tA0[0] = (short)f2bf(q0a.x - k0a.x + p0a.x);
    tA0[1] = (short)f2bf(q0a.y - k0a.y + p0a.y);
    tA0[2] = (short)f2bf(q0a.z - k0a.z + p0a.z);
    tA0[3] = (short)f2bf(q0a.w - k0a.w + p0a.w);
    tA0[4] = (short)f2bf(q0b.x - k0b.x + p0b.x);
    tA0[5] = (short)f2bf(q0b.y - k0b.y + p0b.y);
    tA0[6] = (short)f2bf(q0b.z - k0b.z + p0b.z);
    tA0[7] = (short)f2bf(q0b.w - k0b.w + p0b.w);
    tA1[0] = (short)f2bf(q1a.x - k1a.x + p1a.x);
    tA1[1] = (short)f2bf(q1a.y - k1a.y + p1a.y);
    tA1[2] = (short)f2bf(q1a.z - k1a.z + p1a.z);
    tA1[3] = (short)f2bf(q1a.w - k1a.w + p1a.w);
    tA1[4] = (short)f2bf(q1b.x - k1b.x + p1b.x);
    tA1[5] = (short)f2bf(q1b.y - k1b.y + p1b.y);
    tA1[6] = (short)f2bf(q1b.z - k1b.z + p1b.z);
    tA1[7] = (short)f2bf(q1b.w - k1b.w + p1b.w);

    // a1 = relu(tin @ W1t + ba1)   (16x256, K=64)
    f32x4 acc1[16];
#pragma unroll
    for (int nt = 0; nt < 16; ++nt) {
      bf16x8 bfr = *(const bf16x8*)(w1f + nt * 512 + l * 8);
      acc1[nt] = MFMA16(tA0, bfr, zero);
    }
#pragma unroll
    for (int nt = 0; nt < 16; ++nt) {
      bf16x8 bfr = *(const bf16x8*)(w1f + (16 + nt) * 512 + l * 8);
      acc1[nt] = MFMA16(tA1, bfr, acc1[nt]);
    }
#pragma unroll
    for (int nt = 0; nt < 16; ++nt) {
      float bb = ba1s[nt * 16 + x];
#pragma unroll
      for (int r = 0; r < 4; ++r) {
        a1w[(quad * 4 + r) * 264 + nt * 16 + x] = f2bf(fmaxf(acc1[nt][r] + bb, 0.0f));
      }
    }
    LDS_FENCE();

    // logits = a1 @ W2t + ba2   (16x64, K=256)
    f32x4 acc2[4] = {zero, zero, zero, zero};
#pragma unroll
    for (int kt = 0; kt < 8; ++kt) {
      bf16x8 aF = *(const bf16x8*)(a1w + x * 264 + kt * 32 + quad * 8);
#pragma unroll
      for (int nt = 0; nt < 4; ++nt) {
        bf16x8 bfr = *(const bf16x8*)(w2f + (kt * 4 + nt) * 512 + l * 8);
        acc2[nt] = MFMA16(aF, bfr, acc2[nt]);
      }
    }
    LDS_FENCE();  // a1buf reads done before next iteration's writes

    // softmax over samples (distributed across quads) + aggregation
    float aggv[4];
#pragma unroll
    for (int nt = 0; nt < 4; ++nt) {
      float bb = ba2s[nt * 16 + x];
      float vc = v_pm[(size_t)pt * 64 + nt * 16 + x];
      float lg[4];
#pragma unroll
      for (int r = 0; r < 4; ++r) lg[r] = acc2[nt][r] + bb;
      float m = fmaxf(fmaxf(lg[0], lg[1]), fmaxf(lg[2], lg[3]));
      m = fmaxf(m, __shfl_xor(m, 16));
      m = fmaxf(m, __shfl_xor(m, 32));
      float den = 0.f, num = 0.f;
#pragma unroll
      for (int r = 0; r < 4; ++r) {
        float e = __expf(lg[r] - m);
        den += e;
        num += e * (vc + pev[nt][r]);
      }
      den += __shfl_xor(den, 16); den += __shfl_xor(den, 32);
      num += __shfl_xor(num, 16); num += __shfl_xor(num, 32);
      aggv[nt] = num / den;
    }
    float outv = aggv[0];
    if (quad == 1) outv = aggv[1];
    else if (quad == 2) outv = aggv[2];
    else if (quad == 3) outv = aggv[3];
    agg_pm[(size_t)pt * 64 + l] = outv;  // c = quad*16+x = l, coalesced
  }
}

// ---------------------------------------------------------------------------
// kf_final = t_end(agg) + identity; also writes output2 (B,128,512).
// ---------------------------------------------------------------------------
__global__ __launch_bounds__(128) void kfend_kernel(const float* __restrict__ agg_pm,
                                                    const float* __restrict__ kf_pm,
                                                    const float* __restrict__ wend,
                                                    const float* __restrict__ bend,
                                                    float* __restrict__ kff,
                                                    float* __restrict__ out2) {
  int pt = blockIdx.x;
  int tid = threadIdx.x;
  __shared__ __align__(16) float aggs[64];
  if (tid < 64) aggs[tid] = agg_pm[(size_t)pt * 64 + tid];
  __syncthreads();
  float a0 = bend[tid], a1 = 0.f;
  const float4* ag4 = (const float4*)aggs;
#pragma unroll
  for (int i = 0; i < 16; ++i) {
    float4 w4 = *(const float4*)(wend + (size_t)tid * 64 + i * 4);
    float4 av = ag4[i];
    a0 += w4.x * av.x + w4.y * av.y;
    a1 += w4.z * av.z + w4.w * av.w;
  }
  float val = a0 + a1 + kf_pm[(size_t)pt * 128 + tid];
  kff[(size_t)pt * 128 + tid] = val;
  int b = pt >> 9, n = pt & 511;
  out2[(size_t)b * 65536 + (size_t)tid * 512 + n] = val;
}

// ---------------------------------------------------------------------------
// Generic fp32 GEMM: C[M,N] = act(A[M,K] * Bt[K,N] + bias[N]).
// ---------------------------------------------------------------------------
template <int ACT, bool CONCAT>
__global__ __launch_bounds__(256) void gemm_kernel(const float* __restrict__ A,
                                                   const float* __restrict__ Bt,
                                                   const float* __restrict__ bias,
                                                   float* __restrict__ C,
                                                   int M, int N, int K,
                                                   const float* __restrict__ gf) {
  __shared__ __align__(16) float As[16][128];
  __shared__ __align__(16) float Bs[16][128];
  int t = threadIdx.x;
  int m0 = blockIdx.x * 128, n0 = blockIdx.y * 128;
  int tm = t >> 4, tn = t & 15;
  float acc[8][8];
#pragma unroll
  for (int i = 0; i < 8; ++i) {
#pragma unroll
    for (int j = 0; j < 8; ++j) acc[i][j] = 0.0f;
  }
  for (int k0 = 0; k0 < K; k0 += 16) {
#pragma unroll
    for (int i = 0; i < 2; ++i) {
      int lin = t * 2 + i;
      int mm = lin >> 2, kq = lin & 3;
      int kg = k0 + kq * 4;
      int m = m0 + mm;
      float4 av;
      if (CONCAT) {
        if (kg < 512) av = *(const float4*)(A + (size_t)m * 512 + kg);
        else av = *(const float4*)(gf + (size_t)(m >> 9) * 512 + (kg - 512));
      } else {
        av = *(const float4*)(A + (size_t)m * K + kg);
      }
      As[kq * 4 + 0][mm] = av.x;
      As[kq * 4 + 1][mm] = av.y;
      As[kq * 4 + 2][mm] = av.z;
      As[kq * 4 + 3][mm] = av.w;
      int kk = lin >> 5, nq = lin & 31;
      float4 bv = *(const float4*)(Bt + (size_t)(k0 + kk) * N + n0 + nq * 4);
      *(float4*)&Bs[kk][nq * 4] = bv;
    }
    __syncthreads();
#pragma unroll
    for (int kk = 0; kk < 16; ++kk) {
      float4 A0 = *(const float4*)&As[kk][tm * 8];
      float4 A1 = *(const float4*)&As[kk][tm * 8 + 4];
      float4 B0 = *(const float4*)&Bs[kk][tn * 8];
      float4 B1 = *(const float4*)&Bs[kk][tn * 8 + 4];
      float aa[8] = {A0.x, A0.y, A0.z, A0.w, A1.x, A1.y, A1.z, A1.w};
      float bb[8] = {B0.x, B0.y, B0.z, B0.w, B1.x, B1.y, B1.z, B1.w};
#pragma unroll
      for (int ii = 0; ii < 8; ++ii) {
#pragma unroll
        for (int jj = 0; jj < 8; ++jj) acc[ii][jj] += aa[ii] * bb[jj];
      }
    }
    __syncthreads();
  }
#pragma unroll
  for (int ii = 0; ii < 8; ++ii) {
    int m = m0 + tm * 8 + ii;
#pragma unroll
    for (int jj = 0; jj < 8; ++jj) {
      int n = n0 + tn * 8 + jj;
      float v = acc[ii][jj] + bias[n];
      if (ACT == 1) v = fmaxf(v, 0.0f);
      if (ACT == 2) v = (v >= 0.0f) ? v : 0.2f * v;
      C[(size_t)m * N + n] = v;
    }
  }
}

__global__ __launch_bounds__(256) void gf_kernel(const float* __restrict__ feat,
                                                 float* __restrict__ gf) {
  int gid = blockIdx.x * 256 + threadIdx.x;
  int b = gid >> 9, cc = gid & 511;
  const float* fb = feat + (size_t)b * 512 * 512 + cc;
  float m = -3.0e38f;
  for (int n = 0; n < 512; ++n) m = fmaxf(m, fb[(size_t)n * 512]);
  gf[gid] = m;
}

// ---------------------------------------------------------------------------
// mlp4 (128->12) + sym + output assembly.
// ---------------------------------------------------------------------------
__global__ __launch_bounds__(256) void final_kernel(const float* __restrict__ m3,
                                                    const float* __restrict__ w4,
                                                    const float* __restrict__ b4,
                                                    const float* __restrict__ new_xyz,
                                                    float* __restrict__ out0,
                                                    float* __restrict__ out1) {
  int gid = blockIdx.x * 256 + threadIdx.x;
  __shared__ float w4s[1536];
  __shared__ float b4s[12];
  for (int i = threadIdx.x; i < 1536; i += 256) w4s[i] = w4[i];
  if (threadIdx.x < 12) b4s[threadIdx.x] = b4[threadIdx.x];
  __syncthreads();
  float acc[12];
#pragma unroll
  for (int o = 0; o < 12; ++o) acc[o] = b4s[o];
  const float4* row = (const float4*)(m3 + (size_t)gid * 128);
#pragma unroll 8
  for (int iq = 0; iq < 32; ++iq) {
    float4 xv = row[iq];
#pragma unroll
    for (int o = 0; o < 12; ++o) {
      acc[o] += xv.x * w4s[o * 128 + iq * 4 + 0] + xv.y * w4s[o * 128 + iq * 4 + 1] +
                xv.z * w4s[o * 128 + iq * 4 + 2] + xv.w * w4s[o * 128 + iq * 4 + 3];
    }
  }
  float kx = new_xyz[(size_t)gid * 3 + 0];
  float ky = new_xyz[(size_t)gid * 3 + 1];
  float kz = new_xyz[(size_t)gid * 3 + 2];
  int b = gid >> 9, n = gid & 511;
#pragma unroll
  for (int d = 0; d < 3; ++d) {
    float s = kx * acc[d] + ky * acc[3 + d] + kz * acc[6 + d] + acc[9 + d];
    float kp = (d == 0) ? kx : ((d == 1) ? ky : kz);
    out0[(size_t)b * 3072 + (size_t)d * 1024 + n] = s;
    out0[(size_t)b * 3072 + (size_t)d * 1024 + 512 + n] = kp;
    out1[(size_t)b * 1536 + (size_t)d * 512 + n] = s;
  }
}

// ---------------------------------------------------------------------------
extern "C" void kernel_launch(void* const* d_in, const int* in_sizes, int n_in,
                              void* d_out, int out_size, void* d_ws, size_t ws_size,
                              hipStream_t stream) {
  (void)in_sizes; (void)n_in; (void)out_size; (void)ws_size;
  const float* pc        = (const float*)d_in[0];
  const float* sa_w1     = (const float*)d_in[1];
  const float* sa_b1     = (const float*)d_in[2];
  const float* sa_w2     = (const float*)d_in[3];
  const float* sa_b2     = (const float*)d_in[4];
  const float* t_start_w = (const float*)d_in[5];
  const float* t_start_b = (const float*)d_in[6];
  const float* t_q_w     = (const float*)d_in[7];
  const float* t_q_b     = (const float*)d_in[8];
  const float* t_k_w     = (const float*)d_in[9];
  const float* t_k_b     = (const float*)d_in[10];
  const float* t_v_w     = (const float*)d_in[11];
  const float* t_v_b     = (const float*)d_in[12];
  const float* t_pos_w1  = (const float*)d_in[13];
  const float* t_pos_b1  = (const float*)d_in[14];
  const float* t_pos_w2  = (const float*)d_in[15];
  const float* t_pos_b2  = (const float*)d_in[16];
  const float* t_attn_w1 = (const float*)d_in[17];
  const float* t_attn_b1 = (const float*)d_in[18];
  const float* t_attn_w2 = (const float*)d_in[19];
  const float* t_attn_b2 = (const float*)d_in[20];
  const float* t_end_w   = (const float*)d_in[21];
  const float* t_end_b   = (const float*)d_in[22];
  const float* exp_w1    = (const float*)d_in[23];
  const float* exp_b1    = (const float*)d_in[24];
  const float* exp_w2    = (const float*)d_in[25];
  const float* exp_b2    = (const float*)d_in[26];
  const float* mlp_w1    = (const float*)d_in[27];
  const float* mlp_b1    = (const float*)d_in[28];
  const float* mlp_w2    = (const float*)d_in[29];
  const float* mlp_b2    = (const float*)d_in[30];
  const float* mlp_w3    = (const float*)d_in[31];
  const float* mlp_b3    = (const float*)d_in[32];
  const float* mlp_w4    = (const float*)d_in[33];
  const float* mlp_b4    = (const float*)d_in[34];

  float* ws = (float*)d_ws;
  float* out = (float*)d_out;
  float* out0 = out;            // coarse (32,3,1024)
  float* out1 = out + 98304;    // sym    (32,3,512)
  float* out2 = out + 147456;   // keyfeatures (32,128,512)

  prep_kernel<<<3664, 256, 0, stream>>>(pc, t_start_w, t_q_w, t_k_w, t_v_w,
                                        exp_w1, exp_w2, mlp_w1, mlp_w2, mlp_w3, ws);
  wfrag_kernel<<<18, 256, 0, stream>>>(t_attn_w1, t_attn_w2, t_pos_w2,
                                       (unsigned short*)(ws + WS_WFRAG));
  fps_kernel<<<32, 256, 0, stream>>>(ws + WS_XYZT, ws + WS_NEWXYZ);
  knn1_kernel<<<64, 256, 0, stream>>>(ws + WS_XYZT, ws + WS_RR, ws + WS_NEWXYZ,
                                      (int*)(ws + WS_IDX1));
  sa_kernel<<<16384, 128, 0, stream>>>(ws + WS_XYZT, ws + WS_NEWXYZ,
                                       (const int*)(ws + WS_IDX1),
                                       sa_w1, sa_b1, sa_w2, sa_b2, ws + WS_KF);
  knn2_kernel<<<64, 256, 0, stream>>>(ws + WS_NEWXYZ, (int*)(ws + WS_IDXK));
  qkv_kernel<<<1024, 256, 0, stream>>>(ws + WS_KF, ws + WS_WT_START, ws + WS_WT_Q,
                                       ws + WS_WT_K, ws + WS_WT_V,
                                       t_start_b, t_q_b, t_k_b, t_v_b,
                                       ws + WS_Q, ws + WS_K, ws + WS_V);
  attn_mfma_kernel<<<1024, 256, 0, stream>>>(ws + WS_Q, ws + WS_K, ws + WS_V,
                                             (const int*)(ws + WS_IDXK), ws + WS_NEWXYZ,
                                             (const unsigned short*)(ws + WS_WFRAG),
                                             t_attn_b1, t_attn_b2,
                                             t_pos_w1, t_pos_b1, t_pos_b2,
                                             ws + WS_AGG);
  kfend_kernel<<<16384, 128, 0, stream>>>(ws + WS_AGG, ws + WS_KF, t_end_w, t_end_b,
                                          ws + WS_KFF, out2);
  gemm_kernel<1, false><<<dim3(128, 2), 256, 0, stream>>>(ws + WS_KFF, ws + WS_WT_E1,
                                                          exp_b1, ws + WS_E1,
                                                          NPTS, 256, 128, nullptr);
  gemm_kernel<0, false><<<dim3(128, 4), 256, 0, stream>>>(ws + WS_E1, ws + WS_WT_E2,
                                                          exp_b2, ws + WS_FEAT,
                                                          NPTS, 512, 256, nullptr);
  gf_kernel<<<64, 256, 0, stream>>>(ws + WS_FEAT, ws + WS_GF);
  gemm_kernel<2, true><<<dim3(128, 4), 256, 0, stream>>>(ws + WS_FEAT, ws + WS_WT_M1,
                                                         mlp_b1, ws + WS_M1,
                                                         NPTS, 512, 1024, ws + WS_GF);
  gemm_kernel<2, false><<<dim3(128, 2), 256, 0, stream>>>(ws + WS_M1, ws + WS_WT_M2,
                                                          mlp_b2, ws + WS_M2,
                                                          NPTS, 256, 512, nullptr);
  gemm_kernel<2, false><<<dim3(128, 1), 256, 0, stream>>>(ws + WS_M2, ws + WS_WT_M3,
                                                          mlp_b3, ws + WS_M3,
                                                          NPTS, 128, 256, nullptr);
  final_kernel<<<64, 256, 0, stream>>>(ws + WS_M3, mlp_w4, mlp_b4, ws + WS_NEWXYZ,
                                       out0, out1);
}

// Round 3
// 1817.134 us; speedup vs baseline: 1.5486x; 1.3051x over previous
//
#include <hip/hip_runtime.h>
#include <math.h>

// ---------------------------------------------------------------------------
// LSTNet on MI355X — round 2: chunked KNN (occupancy fix) + packed float4
// point loads. Attention stays MFMA (round 1). Workspace: 90.8 MB.
// ---------------------------------------------------------------------------

#define B_ 32
#define N_ 2048
#define NPOINT 512
#define NSAMPLE 16
#define NKNN 16
#define NPTS (B_ * NPOINT)   // 16384

// ---- workspace layout (float offsets) ----
#define WS_WT_START 0         // 128x64   (8192)
#define WS_WT_Q     8192      // 64x64    (4096)
#define WS_WT_K     12288
#define WS_WT_V     16384
#define WS_WT_E1    20480     // 128x256  (32768)
#define WS_WT_E2    53248     // 256x512  (131072)
#define WS_WT_M1    184320    // 1024x512 (524288)
#define WS_WT_M2    708608    // 512x256  (131072)
#define WS_WT_M3    839680    // 256x128  (32768)
#define WS_XYZW     872448    // (B,2048) float4 = 262144 floats (old XYZT+RR)
#define WS_NEWXYZ   1134592   // (B,512,3)  49152
#define WS_IDX1     1183744   // int (B,512,16) 262144
#define WS_IDXK     1445888   // int (B,512,16) 262144
#define WS_KF       1708032   // (NPTS,128) 2097152
#define WS_Q        3805184   // (NPTS,64)  1048576
#define WS_K        4853760
#define WS_V        5902336
#define WS_AGG      6950912
#define WS_KFF      7999488   // (NPTS,128) 2097152
#define WS_E1       10096640  // (NPTS,256) 4194304
#define WS_FEAT     14290944  // (NPTS,512) 8388608
#define WS_GF       22679552  // (B,512)    16384
#define WS_TOTAL    22695936
// reuse (dead by the time they're written):
#define WS_M1       WS_KFF    // (NPTS,512)? no — m1 overlays KF..KFF region
#undef  WS_M1
#define WS_M1       WS_KF     // (NPTS,512) overlays kf..kff exactly
#define WS_M2       WS_E1
#define WS_M3       WS_FEAT
// KFF region tenants (all dead before kfend writes KFF):
//   wfrag:  bf16 attention weight fragments, 36864 ushort = 18432 float-slots
//   nxyzw:  packed keypoints (NPTS float4) at +32768, 65536 floats
#define WS_WFRAG    WS_KFF
#define WS_NXYZW    (WS_KFF + 32768)
// knn partials (dead regions at knn time):
#define WS_PD1      WS_FEAT             // 16384*8*16 = 2097152 floats
#define WS_PI1      (WS_FEAT + 2097152) // 2097152 ints
#define WS_PD2      WS_E1               // 16384*4*16 = 1048576 floats
#define WS_PI2      (WS_E1 + 1048576)   // 1048576 ints

typedef __attribute__((ext_vector_type(8))) short bf16x8;
typedef __attribute__((ext_vector_type(4))) float f32x4;

__device__ __forceinline__ unsigned short f2bf(float f) {
  unsigned u = __float_as_uint(f);
  u += 0x7fff + ((u >> 16) & 1);  // RNE
  return (unsigned short)(u >> 16);
}

#define MFMA16(a, b, c) __builtin_amdgcn_mfma_f32_16x16x32_bf16((a), (b), (c), 0, 0, 0)
#define LDS_FENCE() __asm__ volatile("" ::: "memory")

// ---------------------------------------------------------------------------
// prep: packed xyzw (x,y,z,|r|^2) + 9 weight transposes.
// ---------------------------------------------------------------------------
__global__ __launch_bounds__(256) void prep_kernel(
    const float* __restrict__ pc,
    const float* __restrict__ w_start, const float* __restrict__ w_q,
    const float* __restrict__ w_k, const float* __restrict__ w_v,
    const float* __restrict__ w_e1, const float* __restrict__ w_e2,
    const float* __restrict__ w_m1, const float* __restrict__ w_m2,
    const float* __restrict__ w_m3, float* __restrict__ ws) {
  int f = blockIdx.x * 256 + threadIdx.x;
  if (f < 65536) {  // xyzw
    int b = f >> 11, j = f & 2047;
    const float* base = pc + (size_t)b * 3 * 2048;
    float x = base[j], y = base[2048 + j], z = base[4096 + j];
    *(float4*)(ws + WS_XYZW + (size_t)f * 4) = make_float4(x, y, z, x * x + y * y + z * z);
    return;
  }
  int u = f - 65536;
  if (u < 8192)  { int k = u >> 6, n = u & 63;  ws[WS_WT_START + u] = w_start[n * 128 + k]; return; }
  u -= 8192;
  if (u < 4096)  { int k = u >> 6, n = u & 63;  ws[WS_WT_Q + u] = w_q[n * 64 + k]; return; }
  u -= 4096;
  if (u < 4096)  { int k = u >> 6, n = u & 63;  ws[WS_WT_K + u] = w_k[n * 64 + k]; return; }
  u -= 4096;
  if (u < 4096)  { int k = u >> 6, n = u & 63;  ws[WS_WT_V + u] = w_v[n * 64 + k]; return; }
  u -= 4096;
  if (u < 32768) { int k = u >> 8, n = u & 255; ws[WS_WT_E1 + u] = w_e1[n * 128 + k]; return; }
  u -= 32768;
  if (u < 131072){ int k = u >> 9, n = u & 511; ws[WS_WT_E2 + u] = w_e2[n * 256 + k]; return; }
  u -= 131072;
  if (u < 524288){ int k = u >> 9, n = u & 511; ws[WS_WT_M1 + u] = w_m1[n * 1024 + k]; return; }
  u -= 524288;
  if (u < 131072){ int k = u >> 8, n = u & 255; ws[WS_WT_M2 + u] = w_m2[n * 512 + k]; return; }
  u -= 131072;
  if (u < 32768) { int k = u >> 7, n = u & 127; ws[WS_WT_M3 + u] = w_m3[n * 256 + k]; return; }
}

// ---------------------------------------------------------------------------
// wfrag: pack attention weights into MFMA B-fragment order (bf16).
// ---------------------------------------------------------------------------
__global__ __launch_bounds__(256) void wfrag_kernel(const float* __restrict__ w1,
                                                    const float* __restrict__ w2,
                                                    const float* __restrict__ wp2,
                                                    unsigned short* __restrict__ wf) {
  int t = blockIdx.x * 256 + threadIdx.x;
  const float* src;
  unsigned short* dst;
  if (t < 2048) {            // w1f
    int l = t & 63, nt = (t >> 6) & 15, kt = t >> 10;
    int n = nt * 16 + (l & 15);
    int kb = kt * 32 + ((l >> 4) & 3) * 8;
    src = w1 + n * 64 + kb;
    dst = wf + t * 8;
  } else if (t < 4096) {     // w2f
    int u = t - 2048;
    int l = u & 63, nt = (u >> 6) & 3, kt = u >> 8;
    int n = nt * 16 + (l & 15);
    int kb = kt * 32 + ((l >> 4) & 3) * 8;
    src = w2 + n * 256 + kb;
    dst = wf + 16384 + u * 8;
  } else if (t < 4608) {     // wpf
    int u = t - 4096;
    int l = u & 63, nt = (u >> 6) & 3, kt = u >> 8;
    int n = nt * 16 + (l & 15);
    int kb = kt * 32 + ((l >> 4) & 3) * 8;
    src = wp2 + n * 64 + kb;
    dst = wf + 32768 + u * 8;
  } else {
    return;
  }
#pragma unroll
  for (int j = 0; j < 8; ++j) dst[j] = f2bf(src[j]);
}

// ---------------------------------------------------------------------------
// FPS: 1 block per batch; packed float4 loads; writes new_xyz + new_xyzw.
// ---------------------------------------------------------------------------
__global__ __launch_bounds__(256) void fps_kernel(const float4* __restrict__ xyzw,
                                                  float* __restrict__ new_xyz,
                                                  float4* __restrict__ new_xyzw) {
  int b = blockIdx.x;
  int tid = threadIdx.x;
  const float4* xb = xyzw + (size_t)b * 2048;
  float px[8], py[8], pz[8], md[8];
#pragma unroll
  for (int r = 0; r < 8; ++r) {
    float4 p = xb[tid + r * 256];
    px[r] = p.x; py[r] = p.y; pz[r] = p.z;
    md[r] = 1e10f;
  }
  __shared__ float wv_[4];
  __shared__ int wi_[4];
  __shared__ int sfar;
  int far = 0;
  for (int i = 0; i < 512; ++i) {
    float4 cpt = xb[far];
    float cx = cpt.x, cy = cpt.y, cz = cpt.z;
    if (tid == 0) {
      float* o = new_xyz + (size_t)(b * 512 + i) * 3;
      o[0] = cx; o[1] = cy; o[2] = cz;
      new_xyzw[(size_t)b * 512 + i] = cpt;
    }
    float bv = -1.0f; int bj = 0;
#pragma unroll
    for (int r = 0; r < 8; ++r) {
      float dx = px[r] - cx, dy = py[r] - cy, dz = pz[r] - cz;
      float d = dx * dx + dy * dy + dz * dz;
      md[r] = fminf(md[r], d);
      if (md[r] > bv) { bv = md[r]; bj = tid + r * 256; }
    }
#pragma unroll
    for (int off = 32; off > 0; off >>= 1) {
      float ov = __shfl_down(bv, off);
      int oj = __shfl_down(bj, off);
      if (ov > bv || (ov == bv && oj < bj)) { bv = ov; bj = oj; }
    }
    int w = tid >> 6;
    if ((tid & 63) == 0) { wv_[w] = bv; wi_[w] = bj; }
    __syncthreads();
    if (tid == 0) {
      float fv = wv_[0]; int fj = wi_[0];
      for (int ww = 1; ww < 4; ++ww)
        if (wv_[ww] > fv || (wv_[ww] == fv && wi_[ww] < fj)) { fv = wv_[ww]; fj = wi_[ww]; }
      sfar = fj;
    }
    __syncthreads();
    far = sfar;
  }
}

// ---------------------------------------------------------------------------
// Chunked KNN: each thread scans CHSZ refs for one query, keeps sorted top-16.
// Partials (sorted ascending) per (query, chunk). Wave lanes share the query
// block -> ref loads are broadcast. Tie-break: strict <, ascending index scan.
// ---------------------------------------------------------------------------
template <int CHSZ, int NCH>
__global__ __launch_bounds__(256) void knn_chunk_kernel(const float4* __restrict__ refs_all,
                                                        int refs_per_batch,
                                                        const float4* __restrict__ query,
                                                        float* __restrict__ pd,
                                                        int* __restrict__ pi) {
  int qb = blockIdx.x & 63, ch = blockIdx.x >> 6;
  int q = qb * 256 + threadIdx.x;
  int b = q >> 9;
  const float4* refs = refs_all + (size_t)b * refs_per_batch + ch * CHSZ;
  float4 qp = query[q];
  float qq = qp.w;
  float bd[16]; int bi[16];
#pragma unroll
  for (int s = 0; s < 16; ++s) { bd[s] = 3.0e38f; bi[s] = 0; }
  for (int j = 0; j < CHSZ; ++j) {
    float4 r = refs[j];
    float d = (qq - 2.0f * (qp.x * r.x + qp.y * r.y + qp.z * r.z)) + r.w;
    if (d < bd[15]) {
      float nd = d; int ni = ch * CHSZ + j;
#pragma unroll
      for (int s = 0; s < 16; ++s) {
        bool sw = nd < bd[s];
        float ob = bd[s]; int oi = bi[s];
        bd[s] = sw ? nd : ob; bi[s] = sw ? ni : oi;
        nd = sw ? ob : nd; ni = sw ? oi : ni;
      }
    }
  }
  float* pdq = pd + ((size_t)q * NCH + ch) * 16;
  int* piq = pi + ((size_t)q * NCH + ch) * 16;
#pragma unroll
  for (int s = 0; s < 16; ++s) { pdq[s] = bd[s]; piq[s] = bi[s]; }
}

// Merge NCH sorted 16-lists -> top-16. Early-out per list (sorted ascending).
template <int NCH>
__global__ __launch_bounds__(256) void knn_merge_kernel(const float* __restrict__ pd,
                                                        const int* __restrict__ pi,
                                                        int* __restrict__ idx) {
  int q = blockIdx.x * 256 + threadIdx.x;
  const float* d0 = pd + (size_t)q * NCH * 16;
  const int* i0 = pi + (size_t)q * NCH * 16;
  float bd[16]; int bi[16];
#pragma unroll
  for (int s = 0; s < 16; ++s) { bd[s] = d0[s]; bi[s] = i0[s]; }
  for (int c = 1; c < NCH; ++c) {
    const float* dc = d0 + c * 16;
    const int* ic = i0 + c * 16;
    for (int s = 0; s < 16; ++s) {
      float d = dc[s];
      if (d >= bd[15]) break;
      float nd = d; int ni = ic[s];
#pragma unroll
      for (int k = 0; k < 16; ++k) {
        bool sw = nd < bd[k];
        float ob = bd[k]; int oi = bi[k];
        bd[k] = sw ? nd : ob; bi[k] = sw ? ni : oi;
        nd = sw ? ob : nd; ni = sw ? oi : ni;
      }
    }
  }
#pragma unroll
  for (int s = 0; s < 16; ++s) idx[(size_t)q * 16 + s] = bi[s];
}

// ---------------------------------------------------------------------------
// SA: group + conv2d(6->64,relu) + conv2d(64->128) + max over 16 samples.
// ---------------------------------------------------------------------------
__global__ __launch_bounds__(128) void sa_kernel(const float4* __restrict__ xyzw,
                                                 const float* __restrict__ new_xyz,
                                                 const int* __restrict__ idx1,
                                                 const float* __restrict__ w1g,
                                                 const float* __restrict__ b1g,
                                                 const float* __restrict__ w2g,
                                                 const float* __restrict__ b2g,
                                                 float* __restrict__ kf_pm) {
  int pt = blockIdx.x;
  int tid = threadIdx.x;
  int b = pt >> 9;
  __shared__ float x6[16][6];
  __shared__ __align__(16) float h1[16][64];
  __shared__ float w1s[384], b1s[64], cs[3];
  for (int i = tid; i < 384; i += 128) w1s[i] = w1g[i];
  if (tid < 64) b1s[tid] = b1g[tid];
  if (tid < 3) cs[tid] = new_xyz[(size_t)pt * 3 + tid];
  __syncthreads();
  if (tid < 16) {
    int j = idx1[(size_t)pt * 16 + tid];
    float4 n4 = xyzw[(size_t)b * 2048 + j];
    x6[tid][0] = n4.x - cs[0]; x6[tid][1] = n4.y - cs[1]; x6[tid][2] = n4.z - cs[2];
    x6[tid][3] = n4.x; x6[tid][4] = n4.y; x6[tid][5] = n4.z;
  }
  __syncthreads();
  for (int e = tid; e < 1024; e += 128) {
    int s = e >> 6, cc = e & 63;
    float v = b1s[cc];
#pragma unroll
    for (int i = 0; i < 6; ++i) v += w1s[cc * 6 + i] * x6[s][i];
    h1[s][cc] = fmaxf(v, 0.0f);
  }
  __syncthreads();
  float wrow[64];
#pragma unroll
  for (int i = 0; i < 16; ++i) {
    float4 w4 = *(const float4*)(w2g + (size_t)tid * 64 + i * 4);
    wrow[i * 4 + 0] = w4.x; wrow[i * 4 + 1] = w4.y;
    wrow[i * 4 + 2] = w4.z; wrow[i * 4 + 3] = w4.w;
  }
  float bb = b2g[tid];
  float mx = -3.0e38f;
  for (int s = 0; s < 16; s += 2) {
    float a0 = 0.f, a1 = 0.f, c0 = 0.f, c1 = 0.f;
    const float4* hA = (const float4*)&h1[s][0];
    const float4* hB = (const float4*)&h1[s + 1][0];
#pragma unroll
    for (int i = 0; i < 16; ++i) {
      float4 ha = hA[i], hb = hB[i];
      a0 += wrow[i * 4 + 0] * ha.x + wrow[i * 4 + 1] * ha.y;
      a1 += wrow[i * 4 + 2] * ha.z + wrow[i * 4 + 3] * ha.w;
      c0 += wrow[i * 4 + 0] * hb.x + wrow[i * 4 + 1] * hb.y;
      c1 += wrow[i * 4 + 2] * hb.z + wrow[i * 4 + 3] * hb.w;
    }
    mx = fmaxf(mx, fmaxf(bb + (a0 + a1), bb + (c0 + c1)));
  }
  kf_pm[(size_t)pt * 128 + tid] = mx;
}

// ---------------------------------------------------------------------------
// qkv
// ---------------------------------------------------------------------------
__global__ __launch_bounds__(256) void qkv_kernel(const float* __restrict__ kf_pm,
                                                  const float* __restrict__ wstT,
                                                  const float* __restrict__ wqT,
                                                  const float* __restrict__ wkT,
                                                  const float* __restrict__ wvT,
                                                  const float* __restrict__ bst,
                                                  const float* __restrict__ bq,
                                                  const float* __restrict__ bk,
                                                  const float* __restrict__ bv,
                                                  float* __restrict__ q_pm,
                                                  float* __restrict__ k_pm,
                                                  float* __restrict__ v_pm) {
  int t = threadIdx.x;
  int c = t & 63, g = t >> 6;
  __shared__ float wst[8192];
  __shared__ float wq[4096], wk[4096], wv[4096];
  __shared__ float bsts[64], bqs[64], bks[64], bvs[64];
  __shared__ __align__(16) float kfsh[4][128];
  __shared__ __align__(16) float xsh[4][64];
  for (int i = t; i < 8192; i += 256) wst[i] = wstT[i];
  for (int i = t; i < 4096; i += 256) { wq[i] = wqT[i]; wk[i] = wkT[i]; wv[i] = wvT[i]; }
  if (t < 64) { bsts[t] = bst[t]; bqs[t] = bq[t]; bks[t] = bk[t]; bvs[t] = bv[t]; }
  __syncthreads();
  for (int pi = g; pi < 16; pi += 4) {
    int pt = blockIdx.x * 16 + pi;
    kfsh[g][c] = kf_pm[(size_t)pt * 128 + c];
    kfsh[g][64 + c] = kf_pm[(size_t)pt * 128 + 64 + c];
    float a0 = bsts[c], a1 = 0.f, a2 = 0.f, a3 = 0.f;
    const float4* kf4 = (const float4*)&kfsh[g][0];
#pragma unroll
    for (int i = 0; i < 32; ++i) {
      float4 kv = kf4[i];
      a0 += kv.x * wst[(i * 4 + 0) * 64 + c];
      a1 += kv.y * wst[(i * 4 + 1) * 64 + c];
      a2 += kv.z * wst[(i * 4 + 2) * 64 + c];
      a3 += kv.w * wst[(i * 4 + 3) * 64 + c];
    }
    xsh[g][c] = (a0 + a1) + (a2 + a3);
    float q0 = bqs[c], q1 = 0.f, k0 = bks[c], k1 = 0.f, v0 = bvs[c], v1 = 0.f;
    const float4* x4 = (const float4*)&xsh[g][0];
#pragma unroll
    for (int i = 0; i < 16; ++i) {
      float4 xv = x4[i];
      q0 += xv.x * wq[(i * 4 + 0) * 64 + c] + xv.y * wq[(i * 4 + 1) * 64 + c];
      q1 += xv.z * wq[(i * 4 + 2) * 64 + c] + xv.w * wq[(i * 4 + 3) * 64 + c];
      k0 += xv.x * wk[(i * 4 + 0) * 64 + c] + xv.y * wk[(i * 4 + 1) * 64 + c];
      k1 += xv.z * wk[(i * 4 + 2) * 64 + c] + xv.w * wk[(i * 4 + 3) * 64 + c];
      v0 += xv.x * wv[(i * 4 + 0) * 64 + c] + xv.y * wv[(i * 4 + 1) * 64 + c];
      v1 += xv.z * wv[(i * 4 + 2) * 64 + c] + xv.w * wv[(i * 4 + 3) * 64 + c];
    }
    q_pm[(size_t)pt * 64 + c] = q0 + q1;
    k_pm[(size_t)pt * 64 + c] = k0 + k1;
    v_pm[(size_t)pt * 64 + c] = v0 + v1;
  }
}

// ---------------------------------------------------------------------------
// MFMA attention (round 1, unchanged): one wave per point.
// ---------------------------------------------------------------------------
__global__ __launch_bounds__(256) void attn_mfma_kernel(
    const float* __restrict__ q_pm, const float* __restrict__ k_pm,
    const float* __restrict__ v_pm, const int* __restrict__ idx_knn,
    const float* __restrict__ new_xyz,
    const unsigned short* __restrict__ wfrag,
    const float* __restrict__ ba1, const float* __restrict__ ba2,
    const float* __restrict__ wp1, const float* __restrict__ bp1,
    const float* __restrict__ bp2,
    float* __restrict__ agg_pm) {
  const int t = threadIdx.x;
  const int w = t >> 6, l = t & 63;
  const int x = l & 15, quad = l >> 4;
  const unsigned short* w1f = wfrag;
  const unsigned short* w2f = wfrag + 16384;
  const unsigned short* wpf = wfrag + 32768;

  __shared__ float4 wp14[64];
  __shared__ float bp2s[64], ba2s[64], ba1s[256];
  __shared__ __align__(16) float pebuf[4][16 * 68];
  __shared__ __align__(16) unsigned short a1buf[4][16 * 264];

  if (t < 64) wp14[t] = make_float4(wp1[t * 3], wp1[t * 3 + 1], wp1[t * 3 + 2], bp1[t]);
  else if (t < 128) bp2s[t - 64] = bp2[t - 64];
  else if (t < 192) ba2s[t - 128] = ba2[t - 128];
  if (t < 256) ba1s[t] = ba1[t];
  __syncthreads();

  float* pew = pebuf[w];
  unsigned short* a1w = a1buf[w];
  const f32x4 zero = {0.f, 0.f, 0.f, 0.f};

  for (int pi = 0; pi < 4; ++pi) {
    int pt = blockIdx.x * 16 + w * 4 + pi;
    int b = pt >> 9;
    int jn = idx_knn[(size_t)pt * 16 + x];
    const float* nb = new_xyz + (size_t)(b * 512 + jn) * 3;
    const float* p0 = new_xyz + (size_t)pt * 3;
    float prx = p0[0] - nb[0], pry = p0[1] - nb[1], prz = p0[2] - nb[2];

    bf16x8 hA0, hA1;
#pragma unroll
    for (int j = 0; j < 8; ++j) {
      float4 cf = wp14[quad * 8 + j];
      hA0[j] = (short)f2bf(fmaxf(cf.w + cf.x * prx + cf.y * pry + cf.z * prz, 0.0f));
      float4 cg = wp14[32 + quad * 8 + j];
      hA1[j] = (short)f2bf(fmaxf(cg.w + cg.x * prx + cg.y * pry + cg.z * prz, 0.0f));
    }
    f32x4 pacc[4];
#pragma unroll
    for (int nt = 0; nt < 4; ++nt) {
      bf16x8 b0 = *(const bf16x8*)(wpf + nt * 512 + l * 8);
      bf16x8 b1 = *(const bf16x8*)(wpf + (4 + nt) * 512 + l * 8);
      f32x4 z = MFMA16(hA0, b0, zero);
      pacc[nt] = MFMA16(hA1, b1, z);
    }
    float pev[4][4];
#pragma unroll
    for (int nt = 0; nt < 4; ++nt) {
      float bb = bp2s[nt * 16 + x];
#pragma unroll
      for (int r = 0; r < 4; ++r) {
        float pe = pacc[nt][r] + bb;
        pev[nt][r] = pe;
        pew[(quad * 4 + r) * 68 + nt * 16 + x] = pe;
      }
    }
    LDS_FENCE();

    const float* qp = q_pm + (size_t)pt * 64;
    const float* kgp = k_pm + (size_t)(b * 512 + jn) * 64;
    const float* per = pew + x * 68;
    float4 q0a = *(const float4*)(qp + quad * 8);
    float4 q0b = *(const float4*)(qp + quad * 8 + 4);
    float4 q1a = *(const float4*)(qp + 32 + quad * 8);
    float4 q1b = *(const float4*)(qp + 32 + quad * 8 + 4);
    float4 k0a = *(const float4*)(kgp + quad * 8);
    float4 k0b = *(const float4*)(kgp + quad * 8 + 4);
    float4 k1a = *(const float4*)(kgp + 32 + quad * 8);
    float4 k1b = *(const float4*)(kgp + 32 + quad * 8 + 4);
    float4 p0a = *(const float4*)(per + quad * 8);
    float4 p0b = *(const float4*)(per + quad * 8 + 4);
    float4 p1a = *(const float4*)(per + 32 + quad * 8);
    float4 p1b = *(const float4*)(per + 32 + quad * 8 + 4);
    bf16x8 tA0, tA1;
    tA0[0] = (short)f2bf(q0a.x - k0a.x + p0a.x);
    tA0[1] = (short)f2bf(q0a.y - k0a.y + p0a.y);
    tA0[2] = (short)f2bf(q0a.z - k0a.z + p0a.z);
    tA0[3] = (short)f2bf(q0a.w - k0a.w + p0a.w);
    tA0[4] = (short)f2bf(q0b.x - k0b.x + p0b.x);
    tA0[5] = (short)f2bf(q0b.y - k0b.y + p0b.y);
    tA0[6] = (short)f2bf(q0b.z - k0b.z + p0b.z);
    tA0[7] = (short)f2bf(q0b.w - k0b.w + p0b.w);
    tA1[0] = (short)f2bf(q1a.x - k1a.x + p1a.x);
    tA1[1] = (short)f2bf(q1a.y - k1a.y + p1a.y);
    tA1[2] = (short)f2bf(q1a.z - k1a.z + p1a.z);
    tA1[3] = (short)f2bf(q1a.w - k1a.w + p1a.w);
    tA1[4] = (short)f2bf(q1b.x - k1b.x + p1b.x);
    tA1[5] = (short)f2bf(q1b.y - k1b.y + p1b.y);
    tA1[6] = (short)f2bf(q1b.z - k1b.z + p1b.z);
    tA1[7] = (short)f2bf(q1b.w - k1b.w + p1b.w);

    f32x4 acc1[16];
#pragma unroll
    for (int nt = 0; nt < 16; ++nt) {
      bf16x8 bfr = *(const bf16x8*)(w1f + nt * 512 + l * 8);
      acc1[nt] = MFMA16(tA0, bfr, zero);
    }
#pragma unroll
    for (int nt = 0; nt < 16; ++nt) {
      bf16x8 bfr = *(const bf16x8*)(w1f + (16 + nt) * 512 + l * 8);
      acc1[nt] = MFMA16(tA1, bfr, acc1[nt]);
    }
#pragma unroll
    for (int nt = 0; nt < 16; ++nt) {
      float bb = ba1s[nt * 16 + x];
#pragma unroll
      for (int r = 0; r < 4; ++r) {
        a1w[(quad * 4 + r) * 264 + nt * 16 + x] = f2bf(fmaxf(acc1[nt][r] + bb, 0.0f));
      }
    }
    LDS_FENCE();

    f32x4 acc2[4] = {zero, zero, zero, zero};
#pragma unroll
    for (int kt = 0; kt < 8; ++kt) {
      bf16x8 aF = *(const bf16x8*)(a1w + x * 264 + kt * 32 + quad * 8);
#pragma unroll
      for (int nt = 0; nt < 4; ++nt) {
        bf16x8 bfr = *(const bf16x8*)(w2f + (kt * 4 + nt) * 512 + l * 8);
        acc2[nt] = MFMA16(aF, bfr, acc2[nt]);
      }
    }
    LDS_FENCE();

    float aggv[4];
#pragma unroll
    for (int nt = 0; nt < 4; ++nt) {
      float bb = ba2s[nt * 16 + x];
      float vc = v_pm[(size_t)pt * 64 + nt * 16 + x];
      float lg[4];
#pragma unroll
      for (int r = 0; r < 4; ++r) lg[r] = acc2[nt][r] + bb;
      float m = fmaxf(fmaxf(lg[0], lg[1]), fmaxf(lg[2], lg[3]));
      m = fmaxf(m, __shfl_xor(m, 16));
      m = fmaxf(m, __shfl_xor(m, 32));
      float den = 0.f, num = 0.f;
#pragma unroll
      for (int r = 0; r < 4; ++r) {
        float e = __expf(lg[r] - m);
        den += e;
        num += e * (vc + pev[nt][r]);
      }
      den += __shfl_xor(den, 16); den += __shfl_xor(den, 32);
      num += __shfl_xor(num, 16); num += __shfl_xor(num, 32);
      aggv[nt] = num / den;
    }
    float outv = aggv[0];
    if (quad == 1) outv = aggv[1];
    else if (quad == 2) outv = aggv[2];
    else if (quad == 3) outv = aggv[3];
    agg_pm[(size_t)pt * 64 + l] = outv;
  }
}

// ---------------------------------------------------------------------------
// kf_final = t_end(agg) + identity; also writes output2 (B,128,512).
// ---------------------------------------------------------------------------
__global__ __launch_bounds__(128) void kfend_kernel(const float* __restrict__ agg_pm,
                                                    const float* __restrict__ kf_pm,
                                                    const float* __restrict__ wend,
                                                    const float* __restrict__ bend,
                                                    float* __restrict__ kff,
                                                    float* __restrict__ out2) {
  int pt = blockIdx.x;
  int tid = threadIdx.x;
  __shared__ __align__(16) float aggs[64];
  if (tid < 64) aggs[tid] = agg_pm[(size_t)pt * 64 + tid];
  __syncthreads();
  float a0 = bend[tid], a1 = 0.f;
  const float4* ag4 = (const float4*)aggs;
#pragma unroll
  for (int i = 0; i < 16; ++i) {
    float4 w4 = *(const float4*)(wend + (size_t)tid * 64 + i * 4);
    float4 av = ag4[i];
    a0 += w4.x * av.x + w4.y * av.y;
    a1 += w4.z * av.z + w4.w * av.w;
  }
  float val = a0 + a1 + kf_pm[(size_t)pt * 128 + tid];
  kff[(size_t)pt * 128 + tid] = val;
  int b = pt >> 9, n = pt & 511;
  out2[(size_t)b * 65536 + (size_t)tid * 512 + n] = val;
}

// ---------------------------------------------------------------------------
// Generic fp32 GEMM: C[M,N] = act(A[M,K] * Bt[K,N] + bias[N]).
// ---------------------------------------------------------------------------
template <int ACT, bool CONCAT>
__global__ __launch_bounds__(256) void gemm_kernel(const float* __restrict__ A,
                                                   const float* __restrict__ Bt,
                                                   const float* __restrict__ bias,
                                                   float* __restrict__ C,
                                                   int M, int N, int K,
                                                   const float* __restrict__ gf) {
  __shared__ __align__(16) float As[16][128];
  __shared__ __align__(16) float Bs[16][128];
  int t = threadIdx.x;
  int m0 = blockIdx.x * 128, n0 = blockIdx.y * 128;
  int tm = t >> 4, tn = t & 15;
  float acc[8][8];
#pragma unroll
  for (int i = 0; i < 8; ++i) {
#pragma unroll
    for (int j = 0; j < 8; ++j) acc[i][j] = 0.0f;
  }
  for (int k0 = 0; k0 < K; k0 += 16) {
#pragma unroll
    for (int i = 0; i < 2; ++i) {
      int lin = t * 2 + i;
      int mm = lin >> 2, kq = lin & 3;
      int kg = k0 + kq * 4;
      int m = m0 + mm;
      float4 av;
      if (CONCAT) {
        if (kg < 512) av = *(const float4*)(A + (size_t)m * 512 + kg);
        else av = *(const float4*)(gf + (size_t)(m >> 9) * 512 + (kg - 512));
      } else {
        av = *(const float4*)(A + (size_t)m * K + kg);
      }
      As[kq * 4 + 0][mm] = av.x;
      As[kq * 4 + 1][mm] = av.y;
      As[kq * 4 + 2][mm] = av.z;
      As[kq * 4 + 3][mm] = av.w;
      int kk = lin >> 5, nq = lin & 31;
      float4 bv = *(const float4*)(Bt + (size_t)(k0 + kk) * N + n0 + nq * 4);
      *(float4*)&Bs[kk][nq * 4] = bv;
    }
    __syncthreads();
#pragma unroll
    for (int kk = 0; kk < 16; ++kk) {
      float4 A0 = *(const float4*)&As[kk][tm * 8];
      float4 A1 = *(const float4*)&As[kk][tm * 8 + 4];
      float4 B0 = *(const float4*)&Bs[kk][tn * 8];
      float4 B1 = *(const float4*)&Bs[kk][tn * 8 + 4];
      float aa[8] = {A0.x, A0.y, A0.z, A0.w, A1.x, A1.y, A1.z, A1.w};
      float bb[8] = {B0.x, B0.y, B0.z, B0.w, B1.x, B1.y, B1.z, B1.w};
#pragma unroll
      for (int ii = 0; ii < 8; ++ii) {
#pragma unroll
        for (int jj = 0; jj < 8; ++jj) acc[ii][jj] += aa[ii] * bb[jj];
      }
    }
    __syncthreads();
  }
#pragma unroll
  for (int ii = 0; ii < 8; ++ii) {
    int m = m0 + tm * 8 + ii;
#pragma unroll
    for (int jj = 0; jj < 8; ++jj) {
      int n = n0 + tn * 8 + jj;
      float v = acc[ii][jj] + bias[n];
      if (ACT == 1) v = fmaxf(v, 0.0f);
      if (ACT == 2) v = (v >= 0.0f) ? v : 0.2f * v;
      C[(size_t)m * N + n] = v;
    }
  }
}

__global__ __launch_bounds__(256) void gf_kernel(const float* __restrict__ feat,
                                                 float* __restrict__ gf) {
  int gid = blockIdx.x * 256 + threadIdx.x;
  int b = gid >> 9, cc = gid & 511;
  const float* fb = feat + (size_t)b * 512 * 512 + cc;
  float m = -3.0e38f;
  for (int n = 0; n < 512; ++n) m = fmaxf(m, fb[(size_t)n * 512]);
  gf[gid] = m;
}

// ---------------------------------------------------------------------------
// mlp4 (128->12) + sym + output assembly.
// ---------------------------------------------------------------------------
__global__ __launch_bounds__(256) void final_kernel(const float* __restrict__ m3,
                                                    const float* __restrict__ w4,
                                                    const float* __restrict__ b4,
                                                    const float* __restrict__ new_xyz,
                                                    float* __restrict__ out0,
                                                    float* __restrict__ out1) {
  int gid = blockIdx.x * 256 + threadIdx.x;
  __shared__ float w4s[1536];
  __shared__ float b4s[12];
  for (int i = threadIdx.x; i < 1536; i += 256) w4s[i] = w4[i];
  if (threadIdx.x < 12) b4s[threadIdx.x] = b4[threadIdx.x];
  __syncthreads();
  float acc[12];
#pragma unroll
  for (int o = 0; o < 12; ++o) acc[o] = b4s[o];
  const float4* row = (const float4*)(m3 + (size_t)gid * 128);
#pragma unroll 8
  for (int iq = 0; iq < 32; ++iq) {
    float4 xv = row[iq];
#pragma unroll
    for (int o = 0; o < 12; ++o) {
      acc[o] += xv.x * w4s[o * 128 + iq * 4 + 0] + xv.y * w4s[o * 128 + iq * 4 + 1] +
                xv.z * w4s[o * 128 + iq * 4 + 2] + xv.w * w4s[o * 128 + iq * 4 + 3];
    }
  }
  float kx = new_xyz[(size_t)gid * 3 + 0];
  float ky = new_xyz[(size_t)gid * 3 + 1];
  float kz = new_xyz[(size_t)gid * 3 + 2];
  int b = gid >> 9, n = gid & 511;
#pragma unroll
  for (int d = 0; d < 3; ++d) {
    float s = kx * acc[d] + ky * acc[3 + d] + kz * acc[6 + d] + acc[9 + d];
    float kp = (d == 0) ? kx : ((d == 1) ? ky : kz);
    out0[(size_t)b * 3072 + (size_t)d * 1024 + n] = s;
    out0[(size_t)b * 3072 + (size_t)d * 1024 + 512 + n] = kp;
    out1[(size_t)b * 1536 + (size_t)d * 512 + n] = s;
  }
}

// ---------------------------------------------------------------------------
extern "C" void kernel_launch(void* const* d_in, const int* in_sizes, int n_in,
                              void* d_out, int out_size, void* d_ws, size_t ws_size,
                              hipStream_t stream) {
  (void)in_sizes; (void)n_in; (void)out_size; (void)ws_size;
  const float* pc        = (const float*)d_in[0];
  const float* sa_w1     = (const float*)d_in[1];
  const float* sa_b1     = (const float*)d_in[2];
  const float* sa_w2     = (const float*)d_in[3];
  const float* sa_b2     = (const float*)d_in[4];
  const float* t_start_w = (const float*)d_in[5];
  const float* t_start_b = (const float*)d_in[6];
  const float* t_q_w     = (const float*)d_in[7];
  const float* t_q_b     = (const float*)d_in[8];
  const float* t_k_w     = (const float*)d_in[9];
  const float* t_k_b     = (const float*)d_in[10];
  const float* t_v_w     = (const float*)d_in[11];
  const float* t_v_b     = (const float*)d_in[12];
  const float* t_pos_w1  = (const float*)d_in[13];
  const float* t_pos_b1  = (const float*)d_in[14];
  const float* t_pos_w2  = (const float*)d_in[15];
  const float* t_pos_b2  = (const float*)d_in[16];
  const float* t_attn_w1 = (const float*)d_in[17];
  const float* t_attn_b1 = (const float*)d_in[18];
  const float* t_attn_w2 = (const float*)d_in[19];
  const float* t_attn_b2 = (const float*)d_in[20];
  const float* t_end_w   = (const float*)d_in[21];
  const float* t_end_b   = (const float*)d_in[22];
  const float* exp_w1    = (const float*)d_in[23];
  const float* exp_b1    = (const float*)d_in[24];
  const float* exp_w2    = (const float*)d_in[25];
  const float* exp_b2    = (const float*)d_in[26];
  const float* mlp_w1    = (const float*)d_in[27];
  const float* mlp_b1    = (const float*)d_in[28];
  const float* mlp_w2    = (const float*)d_in[29];
  const float* mlp_b2    = (const float*)d_in[30];
  const float* mlp_w3    = (const float*)d_in[31];
  const float* mlp_b3    = (const float*)d_in[32];
  const float* mlp_w4    = (const float*)d_in[33];
  const float* mlp_b4    = (const float*)d_in[34];

  float* ws = (float*)d_ws;
  float* out = (float*)d_out;
  float* out0 = out;            // coarse (32,3,1024)
  float* out1 = out + 98304;    // sym    (32,3,512)
  float* out2 = out + 147456;   // keyfeatures (32,128,512)

  prep_kernel<<<3664, 256, 0, stream>>>(pc, t_start_w, t_q_w, t_k_w, t_v_w,
                                        exp_w1, exp_w2, mlp_w1, mlp_w2, mlp_w3, ws);
  wfrag_kernel<<<18, 256, 0, stream>>>(t_attn_w1, t_attn_w2, t_pos_w2,
                                       (unsigned short*)(ws + WS_WFRAG));
  fps_kernel<<<32, 256, 0, stream>>>((const float4*)(ws + WS_XYZW), ws + WS_NEWXYZ,
                                     (float4*)(ws + WS_NXYZW));
  knn_chunk_kernel<256, 8><<<512, 256, 0, stream>>>((const float4*)(ws + WS_XYZW), 2048,
                                                    (const float4*)(ws + WS_NXYZW),
                                                    ws + WS_PD1, (int*)(ws + WS_PI1));
  knn_merge_kernel<8><<<64, 256, 0, stream>>>(ws + WS_PD1, (const int*)(ws + WS_PI1),
                                              (int*)(ws + WS_IDX1));
  knn_chunk_kernel<128, 4><<<256, 256, 0, stream>>>((const float4*)(ws + WS_NXYZW), 512,
                                                    (const float4*)(ws + WS_NXYZW),
                                                    ws + WS_PD2, (int*)(ws + WS_PI2));
  knn_merge_kernel<4><<<64, 256, 0, stream>>>(ws + WS_PD2, (const int*)(ws + WS_PI2),
                                              (int*)(ws + WS_IDXK));
  sa_kernel<<<16384, 128, 0, stream>>>((const float4*)(ws + WS_XYZW), ws + WS_NEWXYZ,
                                       (const int*)(ws + WS_IDX1),
                                       sa_w1, sa_b1, sa_w2, sa_b2, ws + WS_KF);
  qkv_kernel<<<1024, 256, 0, stream>>>(ws + WS_KF, ws + WS_WT_START, ws + WS_WT_Q,
                                       ws + WS_WT_K, ws + WS_WT_V,
                                       t_start_b, t_q_b, t_k_b, t_v_b,
                                       ws + WS_Q, ws + WS_K, ws + WS_V);
  attn_mfma_kernel<<<1024, 256, 0, stream>>>(ws + WS_Q, ws + WS_K, ws + WS_V,
                                             (const int*)(ws + WS_IDXK), ws + WS_NEWXYZ,
                                             (const unsigned short*)(ws + WS_WFRAG),
                                             t_attn_b1, t_attn_b2,
                                             t_pos_w1, t_pos_b1, t_pos_b2,
                                             ws + WS_AGG);
  kfend_kernel<<<16384, 128, 0, stream>>>(ws + WS_AGG, ws + WS_KF, t_end_w, t_end_b,
                                          ws + WS_KFF, out2);
  gemm_kernel<1, false><<<dim3(128, 2), 256, 0, stream>>>(ws + WS_KFF, ws + WS_WT_E1,
                                                          exp_b1, ws + WS_E1,
                                                          NPTS, 256, 128, nullptr);
  gemm_kernel<0, false><<<dim3(128, 4), 256, 0, stream>>>(ws + WS_E1, ws + WS_WT_E2,
                                                          exp_b2, ws + WS_FEAT,
                                                          NPTS, 512, 256, nullptr);
  gf_kernel<<<64, 256, 0, stream>>>(ws + WS_FEAT, ws + WS_GF);
  gemm_kernel<2, true><<<dim3(128, 4), 256, 0, stream>>>(ws + WS_FEAT, ws + WS_WT_M1,
                                                         mlp_b1, ws + WS_M1,
                                                         NPTS, 512, 1024, ws + WS_GF);
  gemm_kernel<2, false><<<dim3(128, 2), 256, 0, stream>>>(ws + WS_M1, ws + WS_WT_M2,
                                                          mlp_b2, ws + WS_M2,
                                                          NPTS, 256, 512, nullptr);
  gemm_kernel<2, false><<<dim3(128, 1), 256, 0, stream>>>(ws + WS_M2, ws + WS_WT_M3,
                                                          mlp_b3, ws + WS_M3,
                                                          NPTS, 128, 256, nullptr);
  final_kernel<<<64, 256, 0, stream>>>(ws + WS_M3, mlp_w4, mlp_b4, ws + WS_NEWXYZ,
                                       out0, out1);
}

// Round 4
// 1221.181 us; speedup vs baseline: 2.3043x; 1.4880x over previous
//
#include <hip/hip_runtime.h>
#include <math.h>

// ---------------------------------------------------------------------------
// LSTNet on MI355X — round 3:
//   (a) FPS rewrite: LDS-staged points, uint64-packed argmax, 1 barrier/iter.
//   (b) bf16 MFMA GEMM chain (exp1/exp2/mlp1/mlp2/mlp3) with frag-packed
//       weights, direct-from-L2 fragment loads, bf16 activation chaining.
// Workspace: 90.8 MB (same footprint, heavy region reuse).
// ---------------------------------------------------------------------------

#define B_ 32
#define N_ 2048
#define NPOINT 512
#define NSAMPLE 16
#define NKNN 16
#define NPTS (B_ * NPOINT)   // 16384

// ---- workspace layout (float offsets) ----
#define WS_WT_START 0         // 128x64   (8192)
#define WS_WT_Q     8192      // 64x64    (4096)
#define WS_WT_K     12288
#define WS_WT_V     16384
// [20480 .. 872448) : formerly f32 weight transposes; now bf16 GEMM frags.
#define WS_XYZW     872448    // (B,2048) float4 = 262144 floats
#define WS_NEWXYZ   1134592   // (B,512,3)  49152
#define WS_IDX1     1183744   // int (B,512,16) 262144
#define WS_IDXK     1445888   // int (B,512,16) 262144
#define WS_KF       1708032   // (NPTS,128) 2097152
#define WS_Q        3805184   // (NPTS,64)  1048576
#define WS_K        4853760
#define WS_V        5902336
#define WS_AGG      6950912
#define WS_KFF      7999488   // region (2097152 floats)
#define WS_E1       10096640  // region (4194304 floats)
#define WS_FEAT     14290944  // region (8388608 floats)
#define WS_GF       22679552  // (B,512)    16384
#define WS_TOTAL    22695936
// KFF-region tenants (dead before kfend):
#define WS_WFRAG    WS_KFF               // attn bf16 frags (36864 us)
#define WS_NXYZW    (WS_KFF + 32768)     // packed keypoints (65536 f)
// knn partials (dead before GEMM chain):
#define WS_PD1      WS_FEAT              // 2097152 f
#define WS_PI1      (WS_FEAT + 2097152)  // 2097152 i
#define WS_PD2      WS_E1                // 1048576 f
#define WS_PI2      (WS_E1 + 1048576)    // 1048576 i

// ---- ushort offsets (into (unsigned short*)ws) ----
// GEMM weight fragments (in old f32 weight-transpose region, float 20480+):
#define UF_E1  40960     // 32768 us   (K=128,N=256)
#define UF_E2  73728     // 131072 us  (K=256,N=512)
#define UF_M1  204800    // 524288 us  (K=1024,N=512)
#define UF_M2  729088    // 131072 us  (K=512,N=256)
#define UF_M3  860160    // 32768 us   (K=256,N=128)
// bf16 activations:
#define UB_KFF 16261120  // (WS_KFF+131072)*2  : (NPTS,128)
#define UB_E1  20193280  // WS_E1*2            : (NPTS,256)
#define UB_M2  24387584  // (WS_E1+2097152)*2  : (NPTS,256)
#define UB_FEAT 28581888 // WS_FEAT*2          : (NPTS,512)
#define UB_M1  36970496  // (WS_FEAT+4194304)*2: (NPTS,512)
#define UB_M3  3416064   // WS_KF*2            : (NPTS,128)
#define UB_GF  45359104  // WS_GF*2            : (B,512)

typedef __attribute__((ext_vector_type(8))) short bf16x8;
typedef __attribute__((ext_vector_type(8))) unsigned short u16x8;
typedef __attribute__((ext_vector_type(4))) float f32x4;

__device__ __forceinline__ unsigned short f2bf(float f) {
  unsigned u = __float_as_uint(f);
  u += 0x7fff + ((u >> 16) & 1);  // RNE
  return (unsigned short)(u >> 16);
}
__device__ __forceinline__ float bf2f(unsigned short u) {
  return __uint_as_float((unsigned)u << 16);
}

#define MFMA16(a, b, c) __builtin_amdgcn_mfma_f32_16x16x32_bf16((a), (b), (c), 0, 0, 0)
#define LDS_FENCE() __asm__ volatile("" ::: "memory")

// ---------------------------------------------------------------------------
// prep: packed xyzw (x,y,z,|r|^2) + qkv weight transposes. 86016 threads.
// ---------------------------------------------------------------------------
__global__ __launch_bounds__(256) void prep_kernel(
    const float* __restrict__ pc,
    const float* __restrict__ w_start, const float* __restrict__ w_q,
    const float* __restrict__ w_k, const float* __restrict__ w_v,
    float* __restrict__ ws) {
  int f = blockIdx.x * 256 + threadIdx.x;
  if (f < 65536) {  // xyzw
    int b = f >> 11, j = f & 2047;
    const float* base = pc + (size_t)b * 3 * 2048;
    float x = base[j], y = base[2048 + j], z = base[4096 + j];
    *(float4*)(ws + WS_XYZW + (size_t)f * 4) = make_float4(x, y, z, x * x + y * y + z * z);
    return;
  }
  int u = f - 65536;
  if (u < 8192)  { int k = u >> 6, n = u & 63;  ws[WS_WT_START + u] = w_start[n * 128 + k]; return; }
  u -= 8192;
  if (u < 4096)  { int k = u >> 6, n = u & 63;  ws[WS_WT_Q + u] = w_q[n * 64 + k]; return; }
  u -= 4096;
  if (u < 4096)  { int k = u >> 6, n = u & 63;  ws[WS_WT_K + u] = w_k[n * 64 + k]; return; }
  u -= 4096;
  if (u < 4096)  { int k = u >> 6, n = u & 63;  ws[WS_WT_V + u] = w_v[n * 64 + k]; return; }
}

// ---------------------------------------------------------------------------
// wfrag: pack attention + GEMM weights into MFMA B-fragment order (bf16).
// B-frag (16x16x32): lane l holds B[k=kt*32+(l>>4)*8+j][n=nt*16+(l&15)],
// linear u = (kt*(N/16)+nt)*64 + l, 8 contiguous source elems per thread.
// 111104 threads.
// ---------------------------------------------------------------------------
__device__ __forceinline__ void packw(int u, const float* __restrict__ W, int K,
                                      int N16, unsigned short* __restrict__ dst) {
  int l = u & 63;
  int ntk = u >> 6;
  int nt = ntk & (N16 - 1);
  int kt = ntk / N16;
  int n = nt * 16 + (l & 15);
  int kb = kt * 32 + (l >> 4) * 8;
  const float* s = W + (size_t)n * K + kb;
  unsigned short* d = dst + (size_t)u * 8;
#pragma unroll
  for (int j = 0; j < 8; ++j) d[j] = f2bf(s[j]);
}

__global__ __launch_bounds__(256) void wfrag_kernel(
    const float* __restrict__ w1, const float* __restrict__ w2,
    const float* __restrict__ wp2,
    const float* __restrict__ we1, const float* __restrict__ we2,
    const float* __restrict__ wm1, const float* __restrict__ wm2,
    const float* __restrict__ wm3,
    unsigned short* __restrict__ wf, unsigned short* __restrict__ ws_us) {
  int t = blockIdx.x * 256 + threadIdx.x;
  if (t < 2048) { packw(t, w1, 64, 16, wf); return; }            // attn W1t 64x256
  if (t < 4096) { packw(t - 2048, w2, 256, 4, wf + 16384); return; }  // attn W2t 256x64
  if (t < 4608) { packw(t - 4096, wp2, 64, 4, wf + 32768); return; }  // attn Wp2t 64x64
  int u = t - 4608;
  if (u < 4096)  { packw(u, we1, 128, 16, ws_us + UF_E1); return; }
  u -= 4096;
  if (u < 16384) { packw(u, we2, 256, 32, ws_us + UF_E2); return; }
  u -= 16384;
  if (u < 65536) { packw(u, wm1, 1024, 32, ws_us + UF_M1); return; }
  u -= 65536;
  if (u < 16384) { packw(u, wm2, 512, 16, ws_us + UF_M2); return; }
  u -= 16384;
  if (u < 4096)  { packw(u, wm3, 256, 8, ws_us + UF_M3); return; }
}

// ---------------------------------------------------------------------------
// FPS: 1 block/batch, points staged in LDS, uint64-packed (dist, 2047-j)
// argmax, wave butterfly + 1 barrier/iter (double-buffered combine slots).
// ---------------------------------------------------------------------------
__global__ __launch_bounds__(256) void fps_kernel(const float4* __restrict__ xyzw,
                                                  float* __restrict__ new_xyz,
                                                  float4* __restrict__ new_xyzw) {
  int b = blockIdx.x;
  int tid = threadIdx.x;
  int w = tid >> 6;
  __shared__ float4 pts[2048];
  __shared__ unsigned long long kbuf[2][4];
  const float4* xb = xyzw + (size_t)b * 2048;
  float px[8], py[8], pz[8], md[8];
#pragma unroll
  for (int r = 0; r < 8; ++r) {
    float4 p = xb[tid + r * 256];
    pts[tid + r * 256] = p;
    px[r] = p.x; py[r] = p.y; pz[r] = p.z;
    md[r] = 1e10f;
  }
  __syncthreads();
  int far = 0;
  for (int i = 0; i < 512; ++i) {
    float4 cpt = pts[far];
    if (tid == 0) {
      float* o = new_xyz + (size_t)(b * 512 + i) * 3;
      o[0] = cpt.x; o[1] = cpt.y; o[2] = cpt.z;
      new_xyzw[(size_t)b * 512 + i] = cpt;
    }
    float bv = -1.0f; int bj = 0;
#pragma unroll
    for (int r = 0; r < 8; ++r) {
      float dx = px[r] - cpt.x, dy = py[r] - cpt.y, dz = pz[r] - cpt.z;
      float d = dx * dx + dy * dy + dz * dz;
      md[r] = fminf(md[r], d);
      if (md[r] > bv) { bv = md[r]; bj = tid + r * 256; }
    }
    // dist >= 0 so float bits are order-preserving; (2047-j) => smaller j wins ties
    unsigned long long key =
        ((unsigned long long)__float_as_uint(bv) << 32) | (unsigned)(2047 - bj);
#pragma unroll
    for (int off = 1; off < 64; off <<= 1) {
      unsigned long long ok = __shfl_xor(key, off);
      key = ok > key ? ok : key;
    }
    if ((tid & 63) == 0) kbuf[i & 1][w] = key;
    __syncthreads();
    unsigned long long k0 = kbuf[i & 1][0], k1 = kbuf[i & 1][1];
    unsigned long long k2 = kbuf[i & 1][2], k3 = kbuf[i & 1][3];
    k0 = k1 > k0 ? k1 : k0;
    k2 = k3 > k2 ? k3 : k2;
    k0 = k2 > k0 ? k2 : k0;
    far = 2047 - (int)(unsigned)(k0 & 0xffffffffull);
  }
}

// ---------------------------------------------------------------------------
// Chunked KNN (round 2, unchanged).
// ---------------------------------------------------------------------------
template <int CHSZ, int NCH>
__global__ __launch_bounds__(256) void knn_chunk_kernel(const float4* __restrict__ refs_all,
                                                        int refs_per_batch,
                                                        const float4* __restrict__ query,
                                                        float* __restrict__ pd,
                                                        int* __restrict__ pi) {
  int qb = blockIdx.x & 63, ch = blockIdx.x >> 6;
  int q = qb * 256 + threadIdx.x;
  int b = q >> 9;
  const float4* refs = refs_all + (size_t)b * refs_per_batch + ch * CHSZ;
  float4 qp = query[q];
  float qq = qp.w;
  float bd[16]; int bi[16];
#pragma unroll
  for (int s = 0; s < 16; ++s) { bd[s] = 3.0e38f; bi[s] = 0; }
  for (int j = 0; j < CHSZ; ++j) {
    float4 r = refs[j];
    float d = (qq - 2.0f * (qp.x * r.x + qp.y * r.y + qp.z * r.z)) + r.w;
    if (d < bd[15]) {
      float nd = d; int ni = ch * CHSZ + j;
#pragma unroll
      for (int s = 0; s < 16; ++s) {
        bool sw = nd < bd[s];
        float ob = bd[s]; int oi = bi[s];
        bd[s] = sw ? nd : ob; bi[s] = sw ? ni : oi;
        nd = sw ? ob : nd; ni = sw ? oi : ni;
      }
    }
  }
  float* pdq = pd + ((size_t)q * NCH + ch) * 16;
  int* piq = pi + ((size_t)q * NCH + ch) * 16;
#pragma unroll
  for (int s = 0; s < 16; ++s) { pdq[s] = bd[s]; piq[s] = bi[s]; }
}

template <int NCH>
__global__ __launch_bounds__(256) void knn_merge_kernel(const float* __restrict__ pd,
                                                        const int* __restrict__ pi,
                                                        int* __restrict__ idx) {
  int q = blockIdx.x * 256 + threadIdx.x;
  const float* d0 = pd + (size_t)q * NCH * 16;
  const int* i0 = pi + (size_t)q * NCH * 16;
  float bd[16]; int bi[16];
#pragma unroll
  for (int s = 0; s < 16; ++s) { bd[s] = d0[s]; bi[s] = i0[s]; }
  for (int c = 1; c < NCH; ++c) {
    const float* dc = d0 + c * 16;
    const int* ic = i0 + c * 16;
    for (int s = 0; s < 16; ++s) {
      float d = dc[s];
      if (d >= bd[15]) break;
      float nd = d; int ni = ic[s];
#pragma unroll
      for (int k = 0; k < 16; ++k) {
        bool sw = nd < bd[k];
        float ob = bd[k]; int oi = bi[k];
        bd[k] = sw ? nd : ob; bi[k] = sw ? ni : oi;
        nd = sw ? ob : nd; ni = sw ? oi : ni;
      }
    }
  }
#pragma unroll
  for (int s = 0; s < 16; ++s) idx[(size_t)q * 16 + s] = bi[s];
}

// ---------------------------------------------------------------------------
// SA (round 2, unchanged).
// ---------------------------------------------------------------------------
__global__ __launch_bounds__(128) void sa_kernel(const float4* __restrict__ xyzw,
                                                 const float* __restrict__ new_xyz,
                                                 const int* __restrict__ idx1,
                                                 const float* __restrict__ w1g,
                                                 const float* __restrict__ b1g,
                                                 const float* __restrict__ w2g,
                                                 const float* __restrict__ b2g,
                                                 float* __restrict__ kf_pm) {
  int pt = blockIdx.x;
  int tid = threadIdx.x;
  int b = pt >> 9;
  __shared__ float x6[16][6];
  __shared__ __align__(16) float h1[16][64];
  __shared__ float w1s[384], b1s[64], cs[3];
  for (int i = tid; i < 384; i += 128) w1s[i] = w1g[i];
  if (tid < 64) b1s[tid] = b1g[tid];
  if (tid < 3) cs[tid] = new_xyz[(size_t)pt * 3 + tid];
  __syncthreads();
  if (tid < 16) {
    int j = idx1[(size_t)pt * 16 + tid];
    float4 n4 = xyzw[(size_t)b * 2048 + j];
    x6[tid][0] = n4.x - cs[0]; x6[tid][1] = n4.y - cs[1]; x6[tid][2] = n4.z - cs[2];
    x6[tid][3] = n4.x; x6[tid][4] = n4.y; x6[tid][5] = n4.z;
  }
  __syncthreads();
  for (int e = tid; e < 1024; e += 128) {
    int s = e >> 6, cc = e & 63;
    float v = b1s[cc];
#pragma unroll
    for (int i = 0; i < 6; ++i) v += w1s[cc * 6 + i] * x6[s][i];
    h1[s][cc] = fmaxf(v, 0.0f);
  }
  __syncthreads();
  float wrow[64];
#pragma unroll
  for (int i = 0; i < 16; ++i) {
    float4 w4 = *(const float4*)(w2g + (size_t)tid * 64 + i * 4);
    wrow[i * 4 + 0] = w4.x; wrow[i * 4 + 1] = w4.y;
    wrow[i * 4 + 2] = w4.z; wrow[i * 4 + 3] = w4.w;
  }
  float bb = b2g[tid];
  float mx = -3.0e38f;
  for (int s = 0; s < 16; s += 2) {
    float a0 = 0.f, a1 = 0.f, c0 = 0.f, c1 = 0.f;
    const float4* hA = (const float4*)&h1[s][0];
    const float4* hB = (const float4*)&h1[s + 1][0];
#pragma unroll
    for (int i = 0; i < 16; ++i) {
      float4 ha = hA[i], hb = hB[i];
      a0 += wrow[i * 4 + 0] * ha.x + wrow[i * 4 + 1] * ha.y;
      a1 += wrow[i * 4 + 2] * ha.z + wrow[i * 4 + 3] * ha.w;
      c0 += wrow[i * 4 + 0] * hb.x + wrow[i * 4 + 1] * hb.y;
      c1 += wrow[i * 4 + 2] * hb.z + wrow[i * 4 + 3] * hb.w;
    }
    mx = fmaxf(mx, fmaxf(bb + (a0 + a1), bb + (c0 + c1)));
  }
  kf_pm[(size_t)pt * 128 + tid] = mx;
}

// ---------------------------------------------------------------------------
// qkv (round 2, unchanged).
// ---------------------------------------------------------------------------
__global__ __launch_bounds__(256) void qkv_kernel(const float* __restrict__ kf_pm,
                                                  const float* __restrict__ wstT,
                                                  const float* __restrict__ wqT,
                                                  const float* __restrict__ wkT,
                                                  const float* __restrict__ wvT,
                                                  const float* __restrict__ bst,
                                                  const float* __restrict__ bq,
                                                  const float* __restrict__ bk,
                                                  const float* __restrict__ bv,
                                                  float* __restrict__ q_pm,
                                                  float* __restrict__ k_pm,
                                                  float* __restrict__ v_pm) {
  int t = threadIdx.x;
  int c = t & 63, g = t >> 6;
  __shared__ float wst[8192];
  __shared__ float wq[4096], wk[4096], wv[4096];
  __shared__ float bsts[64], bqs[64], bks[64], bvs[64];
  __shared__ __align__(16) float kfsh[4][128];
  __shared__ __align__(16) float xsh[4][64];
  for (int i = t; i < 8192; i += 256) wst[i] = wstT[i];
  for (int i = t; i < 4096; i += 256) { wq[i] = wqT[i]; wk[i] = wkT[i]; wv[i] = wvT[i]; }
  if (t < 64) { bsts[t] = bst[t]; bqs[t] = bq[t]; bks[t] = bk[t]; bvs[t] = bv[t]; }
  __syncthreads();
  for (int pi = g; pi < 16; pi += 4) {
    int pt = blockIdx.x * 16 + pi;
    kfsh[g][c] = kf_pm[(size_t)pt * 128 + c];
    kfsh[g][64 + c] = kf_pm[(size_t)pt * 128 + 64 + c];
    float a0 = bsts[c], a1 = 0.f, a2 = 0.f, a3 = 0.f;
    const float4* kf4 = (const float4*)&kfsh[g][0];
#pragma unroll
    for (int i = 0; i < 32; ++i) {
      float4 kv = kf4[i];
      a0 += kv.x * wst[(i * 4 + 0) * 64 + c];
      a1 += kv.y * wst[(i * 4 + 1) * 64 + c];
      a2 += kv.z * wst[(i * 4 + 2) * 64 + c];
      a3 += kv.w * wst[(i * 4 + 3) * 64 + c];
    }
    xsh[g][c] = (a0 + a1) + (a2 + a3);
    float q0 = bqs[c], q1 = 0.f, k0 = bks[c], k1 = 0.f, v0 = bvs[c], v1 = 0.f;
    const float4* x4 = (const float4*)&xsh[g][0];
#pragma unroll
    for (int i = 0; i < 16; ++i) {
      float4 xv = x4[i];
      q0 += xv.x * wq[(i * 4 + 0) * 64 + c] + xv.y * wq[(i * 4 + 1) * 64 + c];
      q1 += xv.z * wq[(i * 4 + 2) * 64 + c] + xv.w * wq[(i * 4 + 3) * 64 + c];
      k0 += xv.x * wk[(i * 4 + 0) * 64 + c] + xv.y * wk[(i * 4 + 1) * 64 + c];
      k1 += xv.z * wk[(i * 4 + 2) * 64 + c] + xv.w * wk[(i * 4 + 3) * 64 + c];
      v0 += xv.x * wv[(i * 4 + 0) * 64 + c] + xv.y * wv[(i * 4 + 1) * 64 + c];
      v1 += xv.z * wv[(i * 4 + 2) * 64 + c] + xv.w * wv[(i * 4 + 3) * 64 + c];
    }
    q_pm[(size_t)pt * 64 + c] = q0 + q1;
    k_pm[(size_t)pt * 64 + c] = k0 + k1;
    v_pm[(size_t)pt * 64 + c] = v0 + v1;
  }
}

// ---------------------------------------------------------------------------
// MFMA attention (round 1, unchanged).
// ---------------------------------------------------------------------------
__global__ __launch_bounds__(256) void attn_mfma_kernel(
    const float* __restrict__ q_pm, const float* __restrict__ k_pm,
    const float* __restrict__ v_pm, const int* __restrict__ idx_knn,
    const float* __restrict__ new_xyz,
    const unsigned short* __restrict__ wfrag,
    const float* __restrict__ ba1, const float* __restrict__ ba2,
    const float* __restrict__ wp1, const float* __restrict__ bp1,
    const float* __restrict__ bp2,
    float* __restrict__ agg_pm) {
  const int t = threadIdx.x;
  const int w = t >> 6, l = t & 63;
  const int x = l & 15, quad = l >> 4;
  const unsigned short* w1f = wfrag;
  const unsigned short* w2f = wfrag + 16384;
  const unsigned short* wpf = wfrag + 32768;

  __shared__ float4 wp14[64];
  __shared__ float bp2s[64], ba2s[64], ba1s[256];
  __shared__ __align__(16) float pebuf[4][16 * 68];
  __shared__ __align__(16) unsigned short a1buf[4][16 * 264];

  if (t < 64) wp14[t] = make_float4(wp1[t * 3], wp1[t * 3 + 1], wp1[t * 3 + 2], bp1[t]);
  else if (t < 128) bp2s[t - 64] = bp2[t - 64];
  else if (t < 192) ba2s[t - 128] = ba2[t - 128];
  if (t < 256) ba1s[t] = ba1[t];
  __syncthreads();

  float* pew = pebuf[w];
  unsigned short* a1w = a1buf[w];
  const f32x4 zero = {0.f, 0.f, 0.f, 0.f};

  for (int pi = 0; pi < 4; ++pi) {
    int pt = blockIdx.x * 16 + w * 4 + pi;
    int b = pt >> 9;
    int jn = idx_knn[(size_t)pt * 16 + x];
    const float* nb = new_xyz + (size_t)(b * 512 + jn) * 3;
    const float* p0 = new_xyz + (size_t)pt * 3;
    float prx = p0[0] - nb[0], pry = p0[1] - nb[1], prz = p0[2] - nb[2];

    bf16x8 hA0, hA1;
#pragma unroll
    for (int j = 0; j < 8; ++j) {
      float4 cf = wp14[quad * 8 + j];
      hA0[j] = (short)f2bf(fmaxf(cf.w + cf.x * prx + cf.y * pry + cf.z * prz, 0.0f));
      float4 cg = wp14[32 + quad * 8 + j];
      hA1[j] = (short)f2bf(fmaxf(cg.w + cg.x * prx + cg.y * pry + cg.z * prz, 0.0f));
    }
    f32x4 pacc[4];
#pragma unroll
    for (int nt = 0; nt < 4; ++nt) {
      bf16x8 b0 = *(const bf16x8*)(wpf + nt * 512 + l * 8);
      bf16x8 b1 = *(const bf16x8*)(wpf + (4 + nt) * 512 + l * 8);
      f32x4 z = MFMA16(hA0, b0, zero);
      pacc[nt] = MFMA16(hA1, b1, z);
    }
    float pev[4][4];
#pragma unroll
    for (int nt = 0; nt < 4; ++nt) {
      float bb = bp2s[nt * 16 + x];
#pragma unroll
      for (int r = 0; r < 4; ++r) {
        float pe = pacc[nt][r] + bb;
        pev[nt][r] = pe;
        pew[(quad * 4 + r) * 68 + nt * 16 + x] = pe;
      }
    }
    LDS_FENCE();

    const float* qp = q_pm + (size_t)pt * 64;
    const float* kgp = k_pm + (size_t)(b * 512 + jn) * 64;
    const float* per = pew + x * 68;
    float4 q0a = *(const float4*)(qp + quad * 8);
    float4 q0b = *(const float4*)(qp + quad * 8 + 4);
    float4 q1a = *(const float4*)(qp + 32 + quad * 8);
    float4 q1b = *(const float4*)(qp + 32 + quad * 8 + 4);
    float4 k0a = *(const float4*)(kgp + quad * 8);
    float4 k0b = *(const float4*)(kgp + quad * 8 + 4);
    float4 k1a = *(const float4*)(kgp + 32 + quad * 8);
    float4 k1b = *(const float4*)(kgp + 32 + quad * 8 + 4);
    float4 p0a = *(const float4*)(per + quad * 8);
    float4 p0b = *(const float4*)(per + quad * 8 + 4);
    float4 p1a = *(const float4*)(per + 32 + quad * 8);
    float4 p1b = *(const float4*)(per + 32 + quad * 8 + 4);
    bf16x8 tA0, tA1;
    tA0[0] = (short)f2bf(q0a.x - k0a.x + p0a.x);
    tA0[1] = (short)f2bf(q0a.y - k0a.y + p0a.y);
    tA0[2] = (short)f2bf(q0a.z - k0a.z + p0a.z);
    tA0[3] = (short)f2bf(q0a.w - k0a.w + p0a.w);
    tA0[4] = (short)f2bf(q0b.x - k0b.x + p0b.x);
    tA0[5] = (short)f2bf(q0b.y - k0b.y + p0b.y);
    tA0[6] = (short)f2bf(q0b.z - k0b.z + p0b.z);
    tA0[7] = (short)f2bf(q0b.w - k0b.w + p0b.w);
    tA1[0] = (short)f2bf(q1a.x - k1a.x + p1a.x);
    tA1[1] = (short)f2bf(q1a.y - k1a.y + p1a.y);
    tA1[2] = (short)f2bf(q1a.z - k1a.z + p1a.z);
    tA1[3] = (short)f2bf(q1a.w - k1a.w + p1a.w);
    tA1[4] = (short)f2bf(q1b.x - k1b.x + p1b.x);
    tA1[5] = (short)f2bf(q1b.y - k1b.y + p1b.y);
    tA1[6] = (short)f2bf(q1b.z - k1b.z + p1b.z);
    tA1[7] = (short)f2bf(q1b.w - k1b.w + p1b.w);

    f32x4 acc1[16];
#pragma unroll
    for (int nt = 0; nt < 16; ++nt) {
      bf16x8 bfr = *(const bf16x8*)(w1f + nt * 512 + l * 8);
      acc1[nt] = MFMA16(tA0, bfr, zero);
    }
#pragma unroll
    for (int nt = 0; nt < 16; ++nt) {
      bf16x8 bfr = *(const bf16x8*)(w1f + (16 + nt) * 512 + l * 8);
      acc1[nt] = MFMA16(tA1, bfr, acc1[nt]);
    }
#pragma unroll
    for (int nt = 0; nt < 16; ++nt) {
      float bb = ba1s[nt * 16 + x];
#pragma unroll
      for (int r = 0; r < 4; ++r) {
        a1w[(quad * 4 + r) * 264 + nt * 16 + x] = f2bf(fmaxf(acc1[nt][r] + bb, 0.0f));
      }
    }
    LDS_FENCE();

    f32x4 acc2[4] = {zero, zero, zero, zero};
#pragma unroll
    for (int kt = 0; kt < 8; ++kt) {
      bf16x8 aF = *(const bf16x8*)(a1w + x * 264 + kt * 32 + quad * 8);
#pragma unroll
      for (int nt = 0; nt < 4; ++nt) {
        bf16x8 bfr = *(const bf16x8*)(w2f + (kt * 4 + nt) * 512 + l * 8);
        acc2[nt] = MFMA16(aF, bfr, acc2[nt]);
      }
    }
    LDS_FENCE();

    float aggv[4];
#pragma unroll
    for (int nt = 0; nt < 4; ++nt) {
      float bb = ba2s[nt * 16 + x];
      float vc = v_pm[(size_t)pt * 64 + nt * 16 + x];
      float lg[4];
#pragma unroll
      for (int r = 0; r < 4; ++r) lg[r] = acc2[nt][r] + bb;
      float m = fmaxf(fmaxf(lg[0], lg[1]), fmaxf(lg[2], lg[3]));
      m = fmaxf(m, __shfl_xor(m, 16));
      m = fmaxf(m, __shfl_xor(m, 32));
      float den = 0.f, num = 0.f;
#pragma unroll
      for (int r = 0; r < 4; ++r) {
        float e = __expf(lg[r] - m);
        den += e;
        num += e * (vc + pev[nt][r]);
      }
      den += __shfl_xor(den, 16); den += __shfl_xor(den, 32);
      num += __shfl_xor(num, 16); num += __shfl_xor(num, 32);
      aggv[nt] = num / den;
    }
    float outv = aggv[0];
    if (quad == 1) outv = aggv[1];
    else if (quad == 2) outv = aggv[2];
    else if (quad == 3) outv = aggv[3];
    agg_pm[(size_t)pt * 64 + l] = outv;
  }
}

// ---------------------------------------------------------------------------
// kf_final = t_end(agg) + identity; writes bf16 kffb + f32 output2.
// ---------------------------------------------------------------------------
__global__ __launch_bounds__(128) void kfend_kernel(const float* __restrict__ agg_pm,
                                                    const float* __restrict__ kf_pm,
                                                    const float* __restrict__ wend,
                                                    const float* __restrict__ bend,
                                                    unsigned short* __restrict__ kffb,
                                                    float* __restrict__ out2) {
  int pt = blockIdx.x;
  int tid = threadIdx.x;
  __shared__ __align__(16) float aggs[64];
  if (tid < 64) aggs[tid] = agg_pm[(size_t)pt * 64 + tid];
  __syncthreads();
  float a0 = bend[tid], a1 = 0.f;
  const float4* ag4 = (const float4*)aggs;
#pragma unroll
  for (int i = 0; i < 16; ++i) {
    float4 w4 = *(const float4*)(wend + (size_t)tid * 64 + i * 4);
    float4 av = ag4[i];
    a0 += w4.x * av.x + w4.y * av.y;
    a1 += w4.z * av.z + w4.w * av.w;
  }
  float val = a0 + a1 + kf_pm[(size_t)pt * 128 + tid];
  kffb[(size_t)pt * 128 + tid] = f2bf(val);
  int b = pt >> 9, n = pt & 511;
  out2[(size_t)b * 65536 + (size_t)tid * 512 + n] = val;
}

// ---------------------------------------------------------------------------
// bf16 MFMA GEMM: C[M,N](bf16) = act(A[M,K](bf16) @ Bfrag + bias).
// 128x128 block tile, 4 waves in 2x2, 64x64 wave tile, no LDS/barriers —
// A-frags and frag-packed B straight from L1/L2.
// CONCAT: k<512 from A (width 512), k>=512 from gfb[row>>9].
// ---------------------------------------------------------------------------
template <int ACT, bool CONCAT>
__global__ __launch_bounds__(256) void gemm_bf16_kernel(
    const unsigned short* __restrict__ A, const unsigned short* __restrict__ Bf,
    const float* __restrict__ bias, unsigned short* __restrict__ C,
    int M, int N, int K, const unsigned short* __restrict__ gfb) {
  int t = threadIdx.x;
  int l = t & 63, w = t >> 6;
  int x = l & 15, quad = l >> 4;
  int m0 = blockIdx.x * 128 + (w >> 1) * 64;
  int n0 = blockIdx.y * 128 + (w & 1) * 64;
  int N16 = N >> 4;
  const f32x4 zero = {0.f, 0.f, 0.f, 0.f};
  f32x4 acc[4][4];
#pragma unroll
  for (int i = 0; i < 4; ++i)
#pragma unroll
    for (int j = 0; j < 4; ++j) acc[i][j] = zero;

  for (int k0 = 0; k0 < K; k0 += 32) {
    bf16x8 af[4], bfr[4];
#pragma unroll
    for (int mi = 0; mi < 4; ++mi) {
      int arow = m0 + mi * 16 + x;
      const unsigned short* ap;
      if (CONCAT) {
        if (k0 < 512) ap = A + (size_t)arow * 512 + k0 + quad * 8;
        else ap = gfb + (size_t)(arow >> 9) * 512 + (k0 - 512) + quad * 8;
      } else {
        ap = A + (size_t)arow * K + k0 + quad * 8;
      }
      af[mi] = *(const bf16x8*)ap;
    }
    int bbase = (k0 >> 5) * N16 + (n0 >> 4);
#pragma unroll
    for (int ni = 0; ni < 4; ++ni)
      bfr[ni] = *(const bf16x8*)(Bf + (size_t)(bbase + ni) * 512 + l * 8);
#pragma unroll
    for (int mi = 0; mi < 4; ++mi)
#pragma unroll
      for (int ni = 0; ni < 4; ++ni) acc[mi][ni] = MFMA16(af[mi], bfr[ni], acc[mi][ni]);
  }
#pragma unroll
  for (int ni = 0; ni < 4; ++ni) {
    int col = n0 + ni * 16 + x;
    float bb = bias[col];
#pragma unroll
    for (int mi = 0; mi < 4; ++mi) {
      int row = m0 + mi * 16 + quad * 4;
#pragma unroll
      for (int r = 0; r < 4; ++r) {
        float v = acc[mi][ni][r] + bb;
        if (ACT == 1) v = fmaxf(v, 0.0f);
        if (ACT == 2) v = (v >= 0.0f) ? v : 0.2f * v;
        C[(size_t)(row + r) * N + col] = f2bf(v);
      }
    }
  }
}

// global max over points per (batch, channel), bf16 in/out
__global__ __launch_bounds__(256) void gf_kernel(const unsigned short* __restrict__ featb,
                                                 unsigned short* __restrict__ gfb) {
  int gid = blockIdx.x * 256 + threadIdx.x;
  int b = gid >> 9, cc = gid & 511;
  const unsigned short* fb = featb + (size_t)b * 512 * 512 + cc;
  float m = -3.0e38f;
  for (int n = 0; n < 512; ++n) m = fmaxf(m, bf2f(fb[(size_t)n * 512]));
  gfb[gid] = f2bf(m);
}

// ---------------------------------------------------------------------------
// mlp4 (128->12, bf16 A) + sym + output assembly.
// ---------------------------------------------------------------------------
__global__ __launch_bounds__(256) void final_kernel(const unsigned short* __restrict__ m3b,
                                                    const float* __restrict__ w4,
                                                    const float* __restrict__ b4,
                                                    const float* __restrict__ new_xyz,
                                                    float* __restrict__ out0,
                                                    float* __restrict__ out1) {
  int gid = blockIdx.x * 256 + threadIdx.x;
  __shared__ float w4s[1536];
  __shared__ float b4s[12];
  for (int i = threadIdx.x; i < 1536; i += 256) w4s[i] = w4[i];
  if (threadIdx.x < 12) b4s[threadIdx.x] = b4[threadIdx.x];
  __syncthreads();
  float acc[12];
#pragma unroll
  for (int o = 0; o < 12; ++o) acc[o] = b4s[o];
  const unsigned short* row = m3b + (size_t)gid * 128;
#pragma unroll 4
  for (int iq = 0; iq < 16; ++iq) {
    u16x8 xv = *(const u16x8*)(row + iq * 8);
#pragma unroll
    for (int j = 0; j < 8; ++j) {
      float xf = bf2f(xv[j]);
#pragma unroll
      for (int o = 0; o < 12; ++o) acc[o] += xf * w4s[o * 128 + iq * 8 + j];
    }
  }
  float kx = new_xyz[(size_t)gid * 3 + 0];
  float ky = new_xyz[(size_t)gid * 3 + 1];
  float kz = new_xyz[(size_t)gid * 3 + 2];
  int b = gid >> 9, n = gid & 511;
#pragma unroll
  for (int d = 0; d < 3; ++d) {
    float s = kx * acc[d] + ky * acc[3 + d] + kz * acc[6 + d] + acc[9 + d];
    float kp = (d == 0) ? kx : ((d == 1) ? ky : kz);
    out0[(size_t)b * 3072 + (size_t)d * 1024 + n] = s;
    out0[(size_t)b * 3072 + (size_t)d * 1024 + 512 + n] = kp;
    out1[(size_t)b * 1536 + (size_t)d * 512 + n] = s;
  }
}

// ---------------------------------------------------------------------------
extern "C" void kernel_launch(void* const* d_in, const int* in_sizes, int n_in,
                              void* d_out, int out_size, void* d_ws, size_t ws_size,
                              hipStream_t stream) {
  (void)in_sizes; (void)n_in; (void)out_size; (void)ws_size;
  const float* pc        = (const float*)d_in[0];
  const float* sa_w1     = (const float*)d_in[1];
  const float* sa_b1     = (const float*)d_in[2];
  const float* sa_w2     = (const float*)d_in[3];
  const float* sa_b2     = (const float*)d_in[4];
  const float* t_start_w = (const float*)d_in[5];
  const float* t_start_b = (const float*)d_in[6];
  const float* t_q_w     = (const float*)d_in[7];
  const float* t_q_b     = (const float*)d_in[8];
  const float* t_k_w     = (const float*)d_in[9];
  const float* t_k_b     = (const float*)d_in[10];
  const float* t_v_w     = (const float*)d_in[11];
  const float* t_v_b     = (const float*)d_in[12];
  const float* t_pos_w1  = (const float*)d_in[13];
  const float* t_pos_b1  = (const float*)d_in[14];
  const float* t_pos_w2  = (const float*)d_in[15];
  const float* t_pos_b2  = (const float*)d_in[16];
  const float* t_attn_w1 = (const float*)d_in[17];
  const float* t_attn_b1 = (const float*)d_in[18];
  const float* t_attn_w2 = (const float*)d_in[19];
  const float* t_attn_b2 = (const float*)d_in[20];
  const float* t_end_w   = (const float*)d_in[21];
  const float* t_end_b   = (const float*)d_in[22];
  const float* exp_w1    = (const float*)d_in[23];
  const float* exp_b1    = (const float*)d_in[24];
  const float* exp_w2    = (const float*)d_in[25];
  const float* exp_b2    = (const float*)d_in[26];
  const float* mlp_w1    = (const float*)d_in[27];
  const float* mlp_b1    = (const float*)d_in[28];
  const float* mlp_w2    = (const float*)d_in[29];
  const float* mlp_b2    = (const float*)d_in[30];
  const float* mlp_w3    = (const float*)d_in[31];
  const float* mlp_b3    = (const float*)d_in[32];
  const float* mlp_w4    = (const float*)d_in[33];
  const float* mlp_b4    = (const float*)d_in[34];

  float* ws = (float*)d_ws;
  unsigned short* ws_us = (unsigned short*)d_ws;
  float* out = (float*)d_out;
  float* out0 = out;            // coarse (32,3,1024)
  float* out1 = out + 98304;    // sym    (32,3,512)
  float* out2 = out + 147456;   // keyfeatures (32,128,512)

  prep_kernel<<<336, 256, 0, stream>>>(pc, t_start_w, t_q_w, t_k_w, t_v_w, ws);
  wfrag_kernel<<<434, 256, 0, stream>>>(t_attn_w1, t_attn_w2, t_pos_w2,
                                        exp_w1, exp_w2, mlp_w1, mlp_w2, mlp_w3,
                                        (unsigned short*)(ws + WS_WFRAG), ws_us);
  fps_kernel<<<32, 256, 0, stream>>>((const float4*)(ws + WS_XYZW), ws + WS_NEWXYZ,
                                     (float4*)(ws + WS_NXYZW));
  knn_chunk_kernel<256, 8><<<512, 256, 0, stream>>>((const float4*)(ws + WS_XYZW), 2048,
                                                    (const float4*)(ws + WS_NXYZW),
                                                    ws + WS_PD1, (int*)(ws + WS_PI1));
  knn_merge_kernel<8><<<64, 256, 0, stream>>>(ws + WS_PD1, (const int*)(ws + WS_PI1),
                                              (int*)(ws + WS_IDX1));
  knn_chunk_kernel<128, 4><<<256, 256, 0, stream>>>((const float4*)(ws + WS_NXYZW), 512,
                                                    (const float4*)(ws + WS_NXYZW),
                                                    ws + WS_PD2, (int*)(ws + WS_PI2));
  knn_merge_kernel<4><<<64, 256, 0, stream>>>(ws + WS_PD2, (const int*)(ws + WS_PI2),
                                              (int*)(ws + WS_IDXK));
  sa_kernel<<<16384, 128, 0, stream>>>((const float4*)(ws + WS_XYZW), ws + WS_NEWXYZ,
                                       (const int*)(ws + WS_IDX1),
                                       sa_w1, sa_b1, sa_w2, sa_b2, ws + WS_KF);
  qkv_kernel<<<1024, 256, 0, stream>>>(ws + WS_KF, ws + WS_WT_START, ws + WS_WT_Q,
                                       ws + WS_WT_K, ws + WS_WT_V,
                                       t_start_b, t_q_b, t_k_b, t_v_b,
                                       ws + WS_Q, ws + WS_K, ws + WS_V);
  attn_mfma_kernel<<<1024, 256, 0, stream>>>(ws + WS_Q, ws + WS_K, ws + WS_V,
                                             (const int*)(ws + WS_IDXK), ws + WS_NEWXYZ,
                                             (const unsigned short*)(ws + WS_WFRAG),
                                             t_attn_b1, t_attn_b2,
                                             t_pos_w1, t_pos_b1, t_pos_b2,
                                             ws + WS_AGG);
  kfend_kernel<<<16384, 128, 0, stream>>>(ws + WS_AGG, ws + WS_KF, t_end_w, t_end_b,
                                          ws_us + UB_KFF, out2);
  gemm_bf16_kernel<1, false><<<dim3(128, 2), 256, 0, stream>>>(
      ws_us + UB_KFF, ws_us + UF_E1, exp_b1, ws_us + UB_E1, NPTS, 256, 128, nullptr);
  gemm_bf16_kernel<0, false><<<dim3(128, 4), 256, 0, stream>>>(
      ws_us + UB_E1, ws_us + UF_E2, exp_b2, ws_us + UB_FEAT, NPTS, 512, 256, nullptr);
  gf_kernel<<<64, 256, 0, stream>>>(ws_us + UB_FEAT, ws_us + UB_GF);
  gemm_bf16_kernel<2, true><<<dim3(128, 4), 256, 0, stream>>>(
      ws_us + UB_FEAT, ws_us + UF_M1, mlp_b1, ws_us + UB_M1, NPTS, 512, 1024, ws_us + UB_GF);
  gemm_bf16_kernel<2, false><<<dim3(128, 2), 256, 0, stream>>>(
      ws_us + UB_M1, ws_us + UF_M2, mlp_b2, ws_us + UB_M2, NPTS, 256, 512, nullptr);
  gemm_bf16_kernel<2, false><<<dim3(128, 1), 256, 0, stream>>>(
      ws_us + UB_M2, ws_us + UF_M3, mlp_b3, ws_us + UB_M3, NPTS, 128, 256, nullptr);
  final_kernel<<<64, 256, 0, stream>>>(ws_us + UB_M3, mlp_w4, mlp_b4, ws + WS_NEWXYZ,
                                       out0, out1);
}

// Round 5
// 1126.950 us; speedup vs baseline: 2.4970x; 1.0836x over previous
//
#include <hip/hip_runtime.h>
#include <math.h>

// ---------------------------------------------------------------------------
// LSTNet on MI355X — round 4:
//   (a) FPS v3: single wave per batch, packed-fp32 distance update, no barrier.
//   (b) SA rewritten as wave-per-point MFMA (conv1 K=6 zero-padded + conv2).
//   (c) Launch fusion: setup(prep+wfrag), combo1(knn2chunk+merge1),
//       combo2(sa+merge2). 14 launches total.
// ---------------------------------------------------------------------------

#define B_ 32
#define N_ 2048
#define NPOINT 512
#define NSAMPLE 16
#define NKNN 16
#define NPTS (B_ * NPOINT)   // 16384

// ---- workspace layout (float offsets) ----
#define WS_WT_START 0         // 128x64   (8192)
#define WS_WT_Q     8192      // 64x64    (4096)
#define WS_WT_K     12288
#define WS_WT_V     16384
// [20480 .. 872448) : bf16 GEMM/SA weight fragments (ushort offsets below).
#define WS_XYZW     872448    // (B,2048) float4 = 262144 floats
#define WS_NEWXYZ   1134592   // (B,512,3)  49152
#define WS_IDX1     1183744   // int (B,512,16) 262144
#define WS_IDXK     1445888   // int (B,512,16) 262144
#define WS_KF       1708032   // (NPTS,128) f32 2097152
#define WS_Q        3805184   // (NPTS,64)  1048576
#define WS_K        4853760
#define WS_V        5902336
#define WS_AGG      6950912
#define WS_KFF      7999488   // region (2097152 floats)
#define WS_E1       10096640  // region (4194304 floats)
#define WS_FEAT     14290944  // region (8388608 floats)
#define WS_GF       22679552  // (B,512)    16384
#define WS_TOTAL    22695936
// KFF-region tenants (dead before kfend):
#define WS_WFRAG    WS_KFF               // attn bf16 frags (36864 us)
#define WS_NXYZW    (WS_KFF + 32768)     // packed keypoints (65536 f)
// knn partials (dead before GEMM chain):
#define WS_PD1      WS_FEAT              // 2097152 f
#define WS_PI1      (WS_FEAT + 2097152)  // 2097152 i
#define WS_PD2      WS_E1                // 1048576 f
#define WS_PI2      (WS_E1 + 1048576)    // 1048576 i

// ---- ushort offsets (into (unsigned short*)ws) ----
#define UF_E1  40960     // 32768 us   (K=128,N=256)
#define UF_E2  73728     // 131072 us  (K=256,N=512)
#define UF_M1  204800    // 524288 us  (K=1024,N=512)
#define UF_M2  729088    // 131072 us  (K=512,N=256)
#define UF_M3  860160    // 32768 us   (K=256,N=128)
#define UF_SA1 892928    // 2048 us    (K=32 zero-padded from 6, N=64)
#define UF_SA2 894976    // 8192 us    (K=64,N=128)
// bf16 activations:
#define UB_KFF 16261120  // (WS_KFF+131072)*2  : (NPTS,128)
#define UB_E1  20193280  // WS_E1*2            : (NPTS,256)
#define UB_M2  24387584  // (WS_E1+2097152)*2  : (NPTS,256)
#define UB_FEAT 28581888 // WS_FEAT*2          : (NPTS,512)
#define UB_M1  36970496  // (WS_FEAT+4194304)*2: (NPTS,512)
#define UB_M3  3416064   // WS_KF*2            : (NPTS,128)
#define UB_GF  45359104  // WS_GF*2            : (B,512)

typedef __attribute__((ext_vector_type(8))) short bf16x8;
typedef __attribute__((ext_vector_type(8))) unsigned short u16x8;
typedef __attribute__((ext_vector_type(4))) float f32x4;
typedef __attribute__((ext_vector_type(2))) float f32x2;

__device__ __forceinline__ unsigned short f2bf(float f) {
  unsigned u = __float_as_uint(f);
  u += 0x7fff + ((u >> 16) & 1);  // RNE
  return (unsigned short)(u >> 16);
}
__device__ __forceinline__ float bf2f(unsigned short u) {
  return __uint_as_float((unsigned)u << 16);
}

#define MFMA16(a, b, c) __builtin_amdgcn_mfma_f32_16x16x32_bf16((a), (b), (c), 0, 0, 0)
#define LDS_FENCE() __asm__ volatile("" ::: "memory")

// ---------------------------------------------------------------------------
// B-frag pack helper: lane l of tile (kt,nt) holds B[k=kt*32+(l>>4)*8+j][n=nt*16+(l&15)]
// for row-major W[n][K] (B = W^T). u = (kt*N16+nt)*64 + l.
// ---------------------------------------------------------------------------
__device__ __forceinline__ void packw(int u, const float* __restrict__ W, int K,
                                      int N16, unsigned short* __restrict__ dst) {
  int l = u & 63;
  int ntk = u >> 6;
  int nt = ntk & (N16 - 1);
  int kt = ntk / N16;
  int n = nt * 16 + (l & 15);
  int kb = kt * 32 + (l >> 4) * 8;
  const float* s = W + (size_t)n * K + kb;
  unsigned short* d = dst + (size_t)u * 8;
#pragma unroll
  for (int j = 0; j < 8; ++j) d[j] = f2bf(s[j]);
}

// ---------------------------------------------------------------------------
// setup: xyzw packing + qkv f32 weight transposes + all bf16 frag packs.
// 198400 threads = 775 blocks.
// ---------------------------------------------------------------------------
__global__ __launch_bounds__(256) void setup_kernel(
    const float* __restrict__ pc,
    const float* __restrict__ w_start, const float* __restrict__ w_q,
    const float* __restrict__ w_k, const float* __restrict__ w_v,
    const float* __restrict__ w1a, const float* __restrict__ w2a,
    const float* __restrict__ wp2,
    const float* __restrict__ we1, const float* __restrict__ we2,
    const float* __restrict__ wm1, const float* __restrict__ wm2,
    const float* __restrict__ wm3,
    const float* __restrict__ sw1, const float* __restrict__ sw2,
    float* __restrict__ ws) {
  int f = blockIdx.x * 256 + threadIdx.x;
  if (f < 65536) {  // xyzw
    int b = f >> 11, j = f & 2047;
    const float* base = pc + (size_t)b * 3 * 2048;
    float x = base[j], y = base[2048 + j], z = base[4096 + j];
    *(float4*)(ws + WS_XYZW + (size_t)f * 4) = make_float4(x, y, z, x * x + y * y + z * z);
    return;
  }
  int u = f - 65536;
  if (u < 8192)  { int k = u >> 6, n = u & 63;  ws[WS_WT_START + u] = w_start[n * 128 + k]; return; }
  u -= 8192;
  if (u < 4096)  { int k = u >> 6, n = u & 63;  ws[WS_WT_Q + u] = w_q[n * 64 + k]; return; }
  u -= 4096;
  if (u < 4096)  { int k = u >> 6, n = u & 63;  ws[WS_WT_K + u] = w_k[n * 64 + k]; return; }
  u -= 4096;
  if (u < 4096)  { int k = u >> 6, n = u & 63;  ws[WS_WT_V + u] = w_v[n * 64 + k]; return; }
  u -= 4096;
  unsigned short* ws_us = (unsigned short*)ws;
  unsigned short* wf = (unsigned short*)(ws + WS_WFRAG);
  if (u < 2048)  { packw(u, w1a, 64, 16, wf); return; }
  u -= 2048;
  if (u < 2048)  { packw(u, w2a, 256, 4, wf + 16384); return; }
  u -= 2048;
  if (u < 512)   { packw(u, wp2, 64, 4, wf + 32768); return; }
  u -= 512;
  if (u < 4096)  { packw(u, we1, 128, 16, ws_us + UF_E1); return; }
  u -= 4096;
  if (u < 16384) { packw(u, we2, 256, 32, ws_us + UF_E2); return; }
  u -= 16384;
  if (u < 65536) { packw(u, wm1, 1024, 32, ws_us + UF_M1); return; }
  u -= 65536;
  if (u < 16384) { packw(u, wm2, 512, 16, ws_us + UF_M2); return; }
  u -= 16384;
  if (u < 4096)  { packw(u, wm3, 256, 8, ws_us + UF_M3); return; }
  u -= 4096;
  if (u < 256) {  // sa conv1: K=6 zero-padded to 32, N=64. W1 is (64,6).
    int l = u & 63, nt = (u >> 6) & 3;
    int n = nt * 16 + (l & 15);
    int kb = (l >> 4) * 8;
    unsigned short* d = ws_us + UF_SA1 + (size_t)u * 8;
#pragma unroll
    for (int j = 0; j < 8; ++j) {
      int k = kb + j;
      d[j] = (k < 6) ? f2bf(sw1[n * 6 + k]) : 0;
    }
    return;
  }
  u -= 256;
  if (u < 1024)  { packw(u, sw2, 64, 8, ws_us + UF_SA2); return; }
}

// ---------------------------------------------------------------------------
// FPS v3: 1 wave per batch, 32 pts/lane, packed-f32 update, u64 butterfly,
// zero barriers in the iteration loop (single wave).
// ---------------------------------------------------------------------------
__global__ __launch_bounds__(64) void fps_kernel(const float4* __restrict__ xyzw,
                                                 float* __restrict__ new_xyz,
                                                 float4* __restrict__ new_xyzw) {
  int b = blockIdx.x, l = threadIdx.x;
  __shared__ __align__(16) float4 pts[2048];
  const float4* xb = xyzw + (size_t)b * 2048;
  f32x2 px[16], py[16], pz[16], md[16];
#pragma unroll
  for (int p = 0; p < 16; ++p) {
    float4 a = xb[p * 128 + l];
    float4 c = xb[p * 128 + 64 + l];
    pts[p * 128 + l] = a;
    pts[p * 128 + 64 + l] = c;
    px[p] = f32x2{a.x, c.x};
    py[p] = f32x2{a.y, c.y};
    pz[p] = f32x2{a.z, c.z};
    md[p] = f32x2{1e10f, 1e10f};
  }
  __syncthreads();  // single wave: just a waitcnt
  int far = 0;
  for (int i = 0; i < 512; ++i) {
    float4 cpt = pts[far];
    if (l == 0) {
      float* o = new_xyz + (size_t)(b * 512 + i) * 3;
      o[0] = cpt.x; o[1] = cpt.y; o[2] = cpt.z;
      new_xyzw[(size_t)b * 512 + i] = cpt;
    }
    f32x2 cx2 = {cpt.x, cpt.x}, cy2 = {cpt.y, cpt.y}, cz2 = {cpt.z, cpt.z};
    float bv = -1.0f; int bj = 0;
#pragma unroll
    for (int p = 0; p < 16; ++p) {
      f32x2 dx = px[p] - cx2, dy = py[p] - cy2, dz = pz[p] - cz2;
      f32x2 d2 = dx * dx + dy * dy + dz * dz;
      f32x2 m = md[p];
      m.x = fminf(m.x, d2.x);
      m.y = fminf(m.y, d2.y);
      md[p] = m;
      if (m.x > bv) { bv = m.x; bj = p * 128 + l; }
      if (m.y > bv) { bv = m.y; bj = p * 128 + 64 + l; }
    }
    unsigned long long key =
        ((unsigned long long)__float_as_uint(bv) << 32) | (unsigned)(2047 - bj);
#pragma unroll
    for (int off = 1; off < 64; off <<= 1) {
      unsigned long long ok = __shfl_xor(key, off);
      key = ok > key ? ok : key;
    }
    far = 2047 - (int)(unsigned)(key & 0xffffffffull);
  }
}

// ---------------------------------------------------------------------------
// Chunked KNN bodies.
// ---------------------------------------------------------------------------
template <int CHSZ, int NCH>
__device__ __forceinline__ void knn_chunk_body(int bid, int tid,
                                               const float4* __restrict__ refs_all,
                                               int refs_per_batch,
                                               const float4* __restrict__ query,
                                               float* __restrict__ pd,
                                               int* __restrict__ pi) {
  int qb = bid & 63, ch = bid >> 6;
  int q = qb * 256 + tid;
  int b = q >> 9;
  const float4* refs = refs_all + (size_t)b * refs_per_batch + ch * CHSZ;
  float4 qp = query[q];
  float qq = qp.w;
  float bd[16]; int bi[16];
#pragma unroll
  for (int s = 0; s < 16; ++s) { bd[s] = 3.0e38f; bi[s] = 0; }
  for (int j = 0; j < CHSZ; ++j) {
    float4 r = refs[j];
    float d = (qq - 2.0f * (qp.x * r.x + qp.y * r.y + qp.z * r.z)) + r.w;
    if (d < bd[15]) {
      float nd = d; int ni = ch * CHSZ + j;
#pragma unroll
      for (int s = 0; s < 16; ++s) {
        bool sw = nd < bd[s];
        float ob = bd[s]; int oi = bi[s];
        bd[s] = sw ? nd : ob; bi[s] = sw ? ni : oi;
        nd = sw ? ob : nd; ni = sw ? oi : ni;
      }
    }
  }
  float* pdq = pd + ((size_t)q * NCH + ch) * 16;
  int* piq = pi + ((size_t)q * NCH + ch) * 16;
#pragma unroll
  for (int s = 0; s < 16; ++s) { pdq[s] = bd[s]; piq[s] = bi[s]; }
}

template <int NCH>
__device__ __forceinline__ void knn_merge_body(int bid, int tid,
                                               const float* __restrict__ pd,
                                               const int* __restrict__ pi,
                                               int* __restrict__ idx) {
  int q = bid * 256 + tid;
  const float* d0 = pd + (size_t)q * NCH * 16;
  const int* i0 = pi + (size_t)q * NCH * 16;
  float bd[16]; int bi[16];
#pragma unroll
  for (int s = 0; s < 16; ++s) { bd[s] = d0[s]; bi[s] = i0[s]; }
  for (int c = 1; c < NCH; ++c) {
    const float* dc = d0 + c * 16;
    const int* ic = i0 + c * 16;
    for (int s = 0; s < 16; ++s) {
      float d = dc[s];
      if (d >= bd[15]) break;
      float nd = d; int ni = ic[s];
#pragma unroll
      for (int k = 0; k < 16; ++k) {
        bool sw = nd < bd[k];
        float ob = bd[k]; int oi = bi[k];
        bd[k] = sw ? nd : ob; bi[k] = sw ? ni : oi;
        nd = sw ? ob : nd; ni = sw ? oi : ni;
      }
    }
  }
#pragma unroll
  for (int s = 0; s < 16; ++s) idx[(size_t)q * 16 + s] = bi[s];
}

// knn1 chunk pass (512 blocks)
__global__ __launch_bounds__(256) void knn1_chunk_kernel(const float4* __restrict__ xyzw,
                                                         const float4* __restrict__ nxyzw,
                                                         float* __restrict__ pd,
                                                         int* __restrict__ pi) {
  knn_chunk_body<256, 8>(blockIdx.x, threadIdx.x, xyzw, 2048, nxyzw, pd, pi);
}

// combo1: blocks [0,256) = knn2 chunk pass; [256,320) = knn1 merge.
__global__ __launch_bounds__(256) void combo1_kernel(const float4* __restrict__ nxyzw,
                                                     const float* __restrict__ pd1,
                                                     const int* __restrict__ pi1,
                                                     int* __restrict__ idx1,
                                                     float* __restrict__ pd2,
                                                     int* __restrict__ pi2) {
  if (blockIdx.x < 256)
    knn_chunk_body<128, 4>(blockIdx.x, threadIdx.x, nxyzw, 512, nxyzw, pd2, pi2);
  else
    knn_merge_body<8>(blockIdx.x - 256, threadIdx.x, pd1, pi1, idx1);
}

// ---------------------------------------------------------------------------
// SA as wave-per-point MFMA. Block = 4 waves = 4 points.
// conv1: zero-padded K=32 MFMA (A = x6 features, only quad0 lanes nonzero);
// h1 (relu, bf16) round-trips per-wave LDS into A-layout; conv2 = 16 MFMA;
// max over 16 samples via shfl_xor(16,32) on C rows.
// ---------------------------------------------------------------------------
__device__ __forceinline__ void sa_body(int bid, int t,
                                        const float4* __restrict__ xyzw,
                                        const float* __restrict__ new_xyz,
                                        const int* __restrict__ idx1,
                                        const unsigned short* __restrict__ sa1f,
                                        const unsigned short* __restrict__ sa2f,
                                        const float* __restrict__ b1g,
                                        const float* __restrict__ b2g,
                                        float* __restrict__ kf_pm,
                                        unsigned short* __restrict__ h1buf) {
  int w = t >> 6, l = t & 63, x = l & 15, quad = l >> 4;
  int pt = bid * 4 + w;
  int b = pt >> 9;
  int jn = idx1[(size_t)pt * 16 + x];
  float4 n4 = xyzw[(size_t)b * 2048 + jn];
  float c0 = new_xyz[(size_t)pt * 3 + 0];
  float c1 = new_xyz[(size_t)pt * 3 + 1];
  float c2 = new_xyz[(size_t)pt * 3 + 2];
  const f32x4 zero = {0.f, 0.f, 0.f, 0.f};
  bf16x8 xf;
#pragma unroll
  for (int j = 0; j < 8; ++j) xf[j] = 0;
  if (quad == 0) {
    xf[0] = (short)f2bf(n4.x - c0);
    xf[1] = (short)f2bf(n4.y - c1);
    xf[2] = (short)f2bf(n4.z - c2);
    xf[3] = (short)f2bf(n4.x);
    xf[4] = (short)f2bf(n4.y);
    xf[5] = (short)f2bf(n4.z);
  }
  unsigned short* hb = h1buf + w * 16 * 72;
#pragma unroll
  for (int nt = 0; nt < 4; ++nt) {
    f32x4 h = MFMA16(xf, *(const bf16x8*)(sa1f + (nt * 64 + l) * 8), zero);
    float bb = b1g[nt * 16 + x];
#pragma unroll
    for (int r = 0; r < 4; ++r)
      hb[(quad * 4 + r) * 72 + nt * 16 + x] = f2bf(fmaxf(h[r] + bb, 0.0f));
  }
  LDS_FENCE();
  bf16x8 hA0 = *(const bf16x8*)(hb + x * 72 + quad * 8);
  bf16x8 hA1 = *(const bf16x8*)(hb + x * 72 + 32 + quad * 8);
  f32x4 acc[8];
#pragma unroll
  for (int nt = 0; nt < 8; ++nt)
    acc[nt] = MFMA16(hA0, *(const bf16x8*)(sa2f + (nt * 64 + l) * 8), zero);
#pragma unroll
  for (int nt = 0; nt < 8; ++nt)
    acc[nt] = MFMA16(hA1, *(const bf16x8*)(sa2f + ((8 + nt) * 64 + l) * 8), acc[nt]);
#pragma unroll
  for (int nt = 0; nt < 8; ++nt) {
    float bb = b2g[nt * 16 + x];
    float m = fmaxf(fmaxf(acc[nt][0], acc[nt][1]), fmaxf(acc[nt][2], acc[nt][3])) + bb;
    m = fmaxf(m, __shfl_xor(m, 16));
    m = fmaxf(m, __shfl_xor(m, 32));
    if (quad == 0) kf_pm[(size_t)pt * 128 + nt * 16 + x] = m;
  }
}

// combo2: blocks [0,4096) = sa (4 pts/block); [4096,4160) = knn2 merge.
__global__ __launch_bounds__(256) void combo2_kernel(const float4* __restrict__ xyzw,
                                                     const float* __restrict__ new_xyz,
                                                     const int* __restrict__ idx1,
                                                     const unsigned short* __restrict__ sa1f,
                                                     const unsigned short* __restrict__ sa2f,
                                                     const float* __restrict__ b1g,
                                                     const float* __restrict__ b2g,
                                                     float* __restrict__ kf_pm,
                                                     const float* __restrict__ pd2,
                                                     const int* __restrict__ pi2,
                                                     int* __restrict__ idxk) {
  __shared__ __align__(16) unsigned short h1buf[4 * 16 * 72];
  if (blockIdx.x < 4096)
    sa_body(blockIdx.x, threadIdx.x, xyzw, new_xyz, idx1, sa1f, sa2f, b1g, b2g,
            kf_pm, h1buf);
  else
    knn_merge_body<4>(blockIdx.x - 4096, threadIdx.x, pd2, pi2, idxk);
}

// ---------------------------------------------------------------------------
// qkv (unchanged).
// ---------------------------------------------------------------------------
__global__ __launch_bounds__(256) void qkv_kernel(const float* __restrict__ kf_pm,
                                                  const float* __restrict__ wstT,
                                                  const float* __restrict__ wqT,
                                                  const float* __restrict__ wkT,
                                                  const float* __restrict__ wvT,
                                                  const float* __restrict__ bst,
                                                  const float* __restrict__ bq,
                                                  const float* __restrict__ bk,
                                                  const float* __restrict__ bv,
                                                  float* __restrict__ q_pm,
                                                  float* __restrict__ k_pm,
                                                  float* __restrict__ v_pm) {
  int t = threadIdx.x;
  int c = t & 63, g = t >> 6;
  __shared__ float wst[8192];
  __shared__ float wq[4096], wk[4096], wv[4096];
  __shared__ float bsts[64], bqs[64], bks[64], bvs[64];
  __shared__ __align__(16) float kfsh[4][128];
  __shared__ __align__(16) float xsh[4][64];
  for (int i = t; i < 8192; i += 256) wst[i] = wstT[i];
  for (int i = t; i < 4096; i += 256) { wq[i] = wqT[i]; wk[i] = wkT[i]; wv[i] = wvT[i]; }
  if (t < 64) { bsts[t] = bst[t]; bqs[t] = bq[t]; bks[t] = bk[t]; bvs[t] = bv[t]; }
  __syncthreads();
  for (int pi = g; pi < 16; pi += 4) {
    int pt = blockIdx.x * 16 + pi;
    kfsh[g][c] = kf_pm[(size_t)pt * 128 + c];
    kfsh[g][64 + c] = kf_pm[(size_t)pt * 128 + 64 + c];
    float a0 = bsts[c], a1 = 0.f, a2 = 0.f, a3 = 0.f;
    const float4* kf4 = (const float4*)&kfsh[g][0];
#pragma unroll
    for (int i = 0; i < 32; ++i) {
      float4 kv = kf4[i];
      a0 += kv.x * wst[(i * 4 + 0) * 64 + c];
      a1 += kv.y * wst[(i * 4 + 1) * 64 + c];
      a2 += kv.z * wst[(i * 4 + 2) * 64 + c];
      a3 += kv.w * wst[(i * 4 + 3) * 64 + c];
    }
    xsh[g][c] = (a0 + a1) + (a2 + a3);
    float q0 = bqs[c], q1 = 0.f, k0 = bks[c], k1 = 0.f, v0 = bvs[c], v1 = 0.f;
    const float4* x4 = (const float4*)&xsh[g][0];
#pragma unroll
    for (int i = 0; i < 16; ++i) {
      float4 xv = x4[i];
      q0 += xv.x * wq[(i * 4 + 0) * 64 + c] + xv.y * wq[(i * 4 + 1) * 64 + c];
      q1 += xv.z * wq[(i * 4 + 2) * 64 + c] + xv.w * wq[(i * 4 + 3) * 64 + c];
      k0 += xv.x * wk[(i * 4 + 0) * 64 + c] + xv.y * wk[(i * 4 + 1) * 64 + c];
      k1 += xv.z * wk[(i * 4 + 2) * 64 + c] + xv.w * wk[(i * 4 + 3) * 64 + c];
      v0 += xv.x * wv[(i * 4 + 0) * 64 + c] + xv.y * wv[(i * 4 + 1) * 64 + c];
      v1 += xv.z * wv[(i * 4 + 2) * 64 + c] + xv.w * wv[(i * 4 + 3) * 64 + c];
    }
    q_pm[(size_t)pt * 64 + c] = q0 + q1;
    k_pm[(size_t)pt * 64 + c] = k0 + k1;
    v_pm[(size_t)pt * 64 + c] = v0 + v1;
  }
}

// ---------------------------------------------------------------------------
// MFMA attention (unchanged from round 1).
// ---------------------------------------------------------------------------
__global__ __launch_bounds__(256) void attn_mfma_kernel(
    const float* __restrict__ q_pm, const float* __restrict__ k_pm,
    const float* __restrict__ v_pm, const int* __restrict__ idx_knn,
    const float* __restrict__ new_xyz,
    const unsigned short* __restrict__ wfrag,
    const float* __restrict__ ba1, const float* __restrict__ ba2,
    const float* __restrict__ wp1, const float* __restrict__ bp1,
    const float* __restrict__ bp2,
    float* __restrict__ agg_pm) {
  const int t = threadIdx.x;
  const int w = t >> 6, l = t & 63;
  const int x = l & 15, quad = l >> 4;
  const unsigned short* w1f = wfrag;
  const unsigned short* w2f = wfrag + 16384;
  const unsigned short* wpf = wfrag + 32768;

  __shared__ float4 wp14[64];
  __shared__ float bp2s[64], ba2s[64], ba1s[256];
  __shared__ __align__(16) float pebuf[4][16 * 68];
  __shared__ __align__(16) unsigned short a1buf[4][16 * 264];

  if (t < 64) wp14[t] = make_float4(wp1[t * 3], wp1[t * 3 + 1], wp1[t * 3 + 2], bp1[t]);
  else if (t < 128) bp2s[t - 64] = bp2[t - 64];
  else if (t < 192) ba2s[t - 128] = ba2[t - 128];
  if (t < 256) ba1s[t] = ba1[t];
  __syncthreads();

  float* pew = pebuf[w];
  unsigned short* a1w = a1buf[w];
  const f32x4 zero = {0.f, 0.f, 0.f, 0.f};

  for (int pi = 0; pi < 4; ++pi) {
    int pt = blockIdx.x * 16 + w * 4 + pi;
    int b = pt >> 9;
    int jn = idx_knn[(size_t)pt * 16 + x];
    const float* nb = new_xyz + (size_t)(b * 512 + jn) * 3;
    const float* p0 = new_xyz + (size_t)pt * 3;
    float prx = p0[0] - nb[0], pry = p0[1] - nb[1], prz = p0[2] - nb[2];

    bf16x8 hA0, hA1;
#pragma unroll
    for (int j = 0; j < 8; ++j) {
      float4 cf = wp14[quad * 8 + j];
      hA0[j] = (short)f2bf(fmaxf(cf.w + cf.x * prx + cf.y * pry + cf.z * prz, 0.0f));
      float4 cg = wp14[32 + quad * 8 + j];
      hA1[j] = (short)f2bf(fmaxf(cg.w + cg.x * prx + cg.y * pry + cg.z * prz, 0.0f));
    }
    f32x4 pacc[4];
#pragma unroll
    for (int nt = 0; nt < 4; ++nt) {
      bf16x8 b0 = *(const bf16x8*)(wpf + nt * 512 + l * 8);
      bf16x8 b1 = *(const bf16x8*)(wpf + (4 + nt) * 512 + l * 8);
      f32x4 z = MFMA16(hA0, b0, zero);
      pacc[nt] = MFMA16(hA1, b1, z);
    }
    float pev[4][4];
#pragma unroll
    for (int nt = 0; nt < 4; ++nt) {
      float bb = bp2s[nt * 16 + x];
#pragma unroll
      for (int r = 0; r < 4; ++r) {
        float pe = pacc[nt][r] + bb;
        pev[nt][r] = pe;
        pew[(quad * 4 + r) * 68 + nt * 16 + x] = pe;
      }
    }
    LDS_FENCE();

    const float* qp = q_pm + (size_t)pt * 64;
    const float* kgp = k_pm + (size_t)(b * 512 + jn) * 64;
    const float* per = pew + x * 68;
    float4 q0a = *(const float4*)(qp + quad * 8);
    float4 q0b = *(const float4*)(qp + quad * 8 + 4);
    float4 q1a = *(const float4*)(qp + 32 + quad * 8);
    float4 q1b = *(const float4*)(qp + 32 + quad * 8 + 4);
    float4 k0a = *(const float4*)(kgp + quad * 8);
    float4 k0b = *(const float4*)(kgp + quad * 8 + 4);
    float4 k1a = *(const float4*)(kgp + 32 + quad * 8);
    float4 k1b = *(const float4*)(kgp + 32 + quad * 8 + 4);
    float4 p0a = *(const float4*)(per + quad * 8);
    float4 p0b = *(const float4*)(per + quad * 8 + 4);
    float4 p1a = *(const float4*)(per + 32 + quad * 8);
    float4 p1b = *(const float4*)(per + 32 + quad * 8 + 4);
    bf16x8 tA0, tA1;
    tA0[0] = (short)f2bf(q0a.x - k0a.x + p0a.x);
    tA0[1] = (short)f2bf(q0a.y - k0a.y + p0a.y);
    tA0[2] = (short)f2bf(q0a.z - k0a.z + p0a.z);
    tA0[3] = (short)f2bf(q0a.w - k0a.w + p0a.w);
    tA0[4] = (short)f2bf(q0b.x - k0b.x + p0b.x);
    tA0[5] = (short)f2bf(q0b.y - k0b.y + p0b.y);
    tA0[6] = (short)f2bf(q0b.z - k0b.z + p0b.z);
    tA0[7] = (short)f2bf(q0b.w - k0b.w + p0b.w);
    tA1[0] = (short)f2bf(q1a.x - k1a.x + p1a.x);
    tA1[1] = (short)f2bf(q1a.y - k1a.y + p1a.y);
    tA1[2] = (short)f2bf(q1a.z - k1a.z + p1a.z);
    tA1[3] = (short)f2bf(q1a.w - k1a.w + p1a.w);
    tA1[4] = (short)f2bf(q1b.x - k1b.x + p1b.x);
    tA1[5] = (short)f2bf(q1b.y - k1b.y + p1b.y);
    tA1[6] = (short)f2bf(q1b.z - k1b.z + p1b.z);
    tA1[7] = (short)f2bf(q1b.w - k1b.w + p1b.w);

    f32x4 acc1[16];
#pragma unroll
    for (int nt = 0; nt < 16; ++nt) {
      bf16x8 bfr = *(const bf16x8*)(w1f + nt * 512 + l * 8);
      acc1[nt] = MFMA16(tA0, bfr, zero);
    }
#pragma unroll
    for (int nt = 0; nt < 16; ++nt) {
      bf16x8 bfr = *(const bf16x8*)(w1f + (16 + nt) * 512 + l * 8);
      acc1[nt] = MFMA16(tA1, bfr, acc1[nt]);
    }
#pragma unroll
    for (int nt = 0; nt < 16; ++nt) {
      float bb = ba1s[nt * 16 + x];
#pragma unroll
      for (int r = 0; r < 4; ++r) {
        a1w[(quad * 4 + r) * 264 + nt * 16 + x] = f2bf(fmaxf(acc1[nt][r] + bb, 0.0f));
      }
    }
    LDS_FENCE();

    f32x4 acc2[4] = {zero, zero, zero, zero};
#pragma unroll
    for (int kt = 0; kt < 8; ++kt) {
      bf16x8 aF = *(const bf16x8*)(a1w + x * 264 + kt * 32 + quad * 8);
#pragma unroll
      for (int nt = 0; nt < 4; ++nt) {
        bf16x8 bfr = *(const bf16x8*)(w2f + (kt * 4 + nt) * 512 + l * 8);
        acc2[nt] = MFMA16(aF, bfr, acc2[nt]);
      }
    }
    LDS_FENCE();

    float aggv[4];
#pragma unroll
    for (int nt = 0; nt < 4; ++nt) {
      float bb = ba2s[nt * 16 + x];
      float vc = v_pm[(size_t)pt * 64 + nt * 16 + x];
      float lg[4];
#pragma unroll
      for (int r = 0; r < 4; ++r) lg[r] = acc2[nt][r] + bb;
      float m = fmaxf(fmaxf(lg[0], lg[1]), fmaxf(lg[2], lg[3]));
      m = fmaxf(m, __shfl_xor(m, 16));
      m = fmaxf(m, __shfl_xor(m, 32));
      float den = 0.f, num = 0.f;
#pragma unroll
      for (int r = 0; r < 4; ++r) {
        float e = __expf(lg[r] - m);
        den += e;
        num += e * (vc + pev[nt][r]);
      }
      den += __shfl_xor(den, 16); den += __shfl_xor(den, 32);
      num += __shfl_xor(num, 16); num += __shfl_xor(num, 32);
      aggv[nt] = num / den;
    }
    float outv = aggv[0];
    if (quad == 1) outv = aggv[1];
    else if (quad == 2) outv = aggv[2];
    else if (quad == 3) outv = aggv[3];
    agg_pm[(size_t)pt * 64 + l] = outv;
  }
}

// ---------------------------------------------------------------------------
// kf_final = t_end(agg) + identity; writes bf16 kffb + f32 output2.
// ---------------------------------------------------------------------------
__global__ __launch_bounds__(128) void kfend_kernel(const float* __restrict__ agg_pm,
                                                    const float* __restrict__ kf_pm,
                                                    const float* __restrict__ wend,
                                                    const float* __restrict__ bend,
                                                    unsigned short* __restrict__ kffb,
                                                    float* __restrict__ out2) {
  int pt = blockIdx.x;
  int tid = threadIdx.x;
  __shared__ __align__(16) float aggs[64];
  if (tid < 64) aggs[tid] = agg_pm[(size_t)pt * 64 + tid];
  __syncthreads();
  float a0 = bend[tid], a1 = 0.f;
  const float4* ag4 = (const float4*)aggs;
#pragma unroll
  for (int i = 0; i < 16; ++i) {
    float4 w4 = *(const float4*)(wend + (size_t)tid * 64 + i * 4);
    float4 av = ag4[i];
    a0 += w4.x * av.x + w4.y * av.y;
    a1 += w4.z * av.z + w4.w * av.w;
  }
  float val = a0 + a1 + kf_pm[(size_t)pt * 128 + tid];
  kffb[(size_t)pt * 128 + tid] = f2bf(val);
  int b = pt >> 9, n = pt & 511;
  out2[(size_t)b * 65536 + (size_t)tid * 512 + n] = val;
}

// ---------------------------------------------------------------------------
// bf16 MFMA GEMM (unchanged from round 3).
// ---------------------------------------------------------------------------
template <int ACT, bool CONCAT>
__global__ __launch_bounds__(256) void gemm_bf16_kernel(
    const unsigned short* __restrict__ A, const unsigned short* __restrict__ Bf,
    const float* __restrict__ bias, unsigned short* __restrict__ C,
    int M, int N, int K, const unsigned short* __restrict__ gfb) {
  int t = threadIdx.x;
  int l = t & 63, w = t >> 6;
  int x = l & 15, quad = l >> 4;
  int m0 = blockIdx.x * 128 + (w >> 1) * 64;
  int n0 = blockIdx.y * 128 + (w & 1) * 64;
  int N16 = N >> 4;
  const f32x4 zero = {0.f, 0.f, 0.f, 0.f};
  f32x4 acc[4][4];
#pragma unroll
  for (int i = 0; i < 4; ++i)
#pragma unroll
    for (int j = 0; j < 4; ++j) acc[i][j] = zero;

  for (int k0 = 0; k0 < K; k0 += 32) {
    bf16x8 af[4], bfr[4];
#pragma unroll
    for (int mi = 0; mi < 4; ++mi) {
      int arow = m0 + mi * 16 + x;
      const unsigned short* ap;
      if (CONCAT) {
        if (k0 < 512) ap = A + (size_t)arow * 512 + k0 + quad * 8;
        else ap = gfb + (size_t)(arow >> 9) * 512 + (k0 - 512) + quad * 8;
      } else {
        ap = A + (size_t)arow * K + k0 + quad * 8;
      }
      af[mi] = *(const bf16x8*)ap;
    }
    int bbase = (k0 >> 5) * N16 + (n0 >> 4);
#pragma unroll
    for (int ni = 0; ni < 4; ++ni)
      bfr[ni] = *(const bf16x8*)(Bf + (size_t)(bbase + ni) * 512 + l * 8);
#pragma unroll
    for (int mi = 0; mi < 4; ++mi)
#pragma unroll
      for (int ni = 0; ni < 4; ++ni) acc[mi][ni] = MFMA16(af[mi], bfr[ni], acc[mi][ni]);
  }
#pragma unroll
  for (int ni = 0; ni < 4; ++ni) {
    int col = n0 + ni * 16 + x;
    float bb = bias[col];
#pragma unroll
    for (int mi = 0; mi < 4; ++mi) {
      int row = m0 + mi * 16 + quad * 4;
#pragma unroll
      for (int r = 0; r < 4; ++r) {
        float v = acc[mi][ni][r] + bb;
        if (ACT == 1) v = fmaxf(v, 0.0f);
        if (ACT == 2) v = (v >= 0.0f) ? v : 0.2f * v;
        C[(size_t)(row + r) * N + col] = f2bf(v);
      }
    }
  }
}

// global max over points per (batch, channel), bf16 in/out
__global__ __launch_bounds__(256) void gf_kernel(const unsigned short* __restrict__ featb,
                                                 unsigned short* __restrict__ gfb) {
  int gid = blockIdx.x * 256 + threadIdx.x;
  int b = gid >> 9, cc = gid & 511;
  const unsigned short* fb = featb + (size_t)b * 512 * 512 + cc;
  float m = -3.0e38f;
  for (int n = 0; n < 512; ++n) m = fmaxf(m, bf2f(fb[(size_t)n * 512]));
  gfb[gid] = f2bf(m);
}

// ---------------------------------------------------------------------------
// mlp4 (128->12, bf16 A) + sym + output assembly.
// ---------------------------------------------------------------------------
__global__ __launch_bounds__(256) void final_kernel(const unsigned short* __restrict__ m3b,
                                                    const float* __restrict__ w4,
                                                    const float* __restrict__ b4,
                                                    const float* __restrict__ new_xyz,
                                                    float* __restrict__ out0,
                                                    float* __restrict__ out1) {
  int gid = blockIdx.x * 256 + threadIdx.x;
  __shared__ float w4s[1536];
  __shared__ float b4s[12];
  for (int i = threadIdx.x; i < 1536; i += 256) w4s[i] = w4[i];
  if (threadIdx.x < 12) b4s[threadIdx.x] = b4[threadIdx.x];
  __syncthreads();
  float acc[12];
#pragma unroll
  for (int o = 0; o < 12; ++o) acc[o] = b4s[o];
  const unsigned short* row = m3b + (size_t)gid * 128;
#pragma unroll 4
  for (int iq = 0; iq < 16; ++iq) {
    u16x8 xv = *(const u16x8*)(row + iq * 8);
#pragma unroll
    for (int j = 0; j < 8; ++j) {
      float xf = bf2f(xv[j]);
#pragma unroll
      for (int o = 0; o < 12; ++o) acc[o] += xf * w4s[o * 128 + iq * 8 + j];
    }
  }
  float kx = new_xyz[(size_t)gid * 3 + 0];
  float ky = new_xyz[(size_t)gid * 3 + 1];
  float kz = new_xyz[(size_t)gid * 3 + 2];
  int b = gid >> 9, n = gid & 511;
#pragma unroll
  for (int d = 0; d < 3; ++d) {
    float s = kx * acc[d] + ky * acc[3 + d] + kz * acc[6 + d] + acc[9 + d];
    float kp = (d == 0) ? kx : ((d == 1) ? ky : kz);
    out0[(size_t)b * 3072 + (size_t)d * 1024 + n] = s;
    out0[(size_t)b * 3072 + (size_t)d * 1024 + 512 + n] = kp;
    out1[(size_t)b * 1536 + (size_t)d * 512 + n] = s;
  }
}

// ---------------------------------------------------------------------------
extern "C" void kernel_launch(void* const* d_in, const int* in_sizes, int n_in,
                              void* d_out, int out_size, void* d_ws, size_t ws_size,
                              hipStream_t stream) {
  (void)in_sizes; (void)n_in; (void)out_size; (void)ws_size;
  const float* pc        = (const float*)d_in[0];
  const float* sa_w1     = (const float*)d_in[1];
  const float* sa_b1     = (const float*)d_in[2];
  const float* sa_w2     = (const float*)d_in[3];
  const float* sa_b2     = (const float*)d_in[4];
  const float* t_start_w = (const float*)d_in[5];
  const float* t_start_b = (const float*)d_in[6];
  const float* t_q_w     = (const float*)d_in[7];
  const float* t_q_b     = (const float*)d_in[8];
  const float* t_k_w     = (const float*)d_in[9];
  const float* t_k_b     = (const float*)d_in[10];
  const float* t_v_w     = (const float*)d_in[11];
  const float* t_v_b     = (const float*)d_in[12];
  const float* t_pos_w1  = (const float*)d_in[13];
  const float* t_pos_b1  = (const float*)d_in[14];
  const float* t_pos_w2  = (const float*)d_in[15];
  const float* t_pos_b2  = (const float*)d_in[16];
  const float* t_attn_w1 = (const float*)d_in[17];
  const float* t_attn_b1 = (const float*)d_in[18];
  const float* t_attn_w2 = (const float*)d_in[19];
  const float* t_attn_b2 = (const float*)d_in[20];
  const float* t_end_w   = (const float*)d_in[21];
  const float* t_end_b   = (const float*)d_in[22];
  const float* exp_w1    = (const float*)d_in[23];
  const float* exp_b1    = (const float*)d_in[24];
  const float* exp_w2    = (const float*)d_in[25];
  const float* exp_b2    = (const float*)d_in[26];
  const float* mlp_w1    = (const float*)d_in[27];
  const float* mlp_b1    = (const float*)d_in[28];
  const float* mlp_w2    = (const float*)d_in[29];
  const float* mlp_b2    = (const float*)d_in[30];
  const float* mlp_w3    = (const float*)d_in[31];
  const float* mlp_b3    = (const float*)d_in[32];
  const float* mlp_w4    = (const float*)d_in[33];
  const float* mlp_b4    = (const float*)d_in[34];

  float* ws = (float*)d_ws;
  unsigned short* ws_us = (unsigned short*)d_ws;
  float* out = (float*)d_out;
  float* out0 = out;            // coarse (32,3,1024)
  float* out1 = out + 98304;    // sym    (32,3,512)
  float* out2 = out + 147456;   // keyfeatures (32,128,512)

  setup_kernel<<<775, 256, 0, stream>>>(pc, t_start_w, t_q_w, t_k_w, t_v_w,
                                        t_attn_w1, t_attn_w2, t_pos_w2,
                                        exp_w1, exp_w2, mlp_w1, mlp_w2, mlp_w3,
                                        sa_w1, sa_w2, ws);
  fps_kernel<<<32, 64, 0, stream>>>((const float4*)(ws + WS_XYZW), ws + WS_NEWXYZ,
                                    (float4*)(ws + WS_NXYZW));
  knn1_chunk_kernel<<<512, 256, 0, stream>>>((const float4*)(ws + WS_XYZW),
                                             (const float4*)(ws + WS_NXYZW),
                                             ws + WS_PD1, (int*)(ws + WS_PI1));
  combo1_kernel<<<320, 256, 0, stream>>>((const float4*)(ws + WS_NXYZW),
                                         ws + WS_PD1, (const int*)(ws + WS_PI1),
                                         (int*)(ws + WS_IDX1),
                                         ws + WS_PD2, (int*)(ws + WS_PI2));
  combo2_kernel<<<4160, 256, 0, stream>>>((const float4*)(ws + WS_XYZW), ws + WS_NEWXYZ,
                                          (const int*)(ws + WS_IDX1),
                                          ws_us + UF_SA1, ws_us + UF_SA2,
                                          sa_b1, sa_b2, ws + WS_KF,
                                          ws + WS_PD2, (const int*)(ws + WS_PI2),
                                          (int*)(ws + WS_IDXK));
  qkv_kernel<<<1024, 256, 0, stream>>>(ws + WS_KF, ws + WS_WT_START, ws + WS_WT_Q,
                                       ws + WS_WT_K, ws + WS_WT_V,
                                       t_start_b, t_q_b, t_k_b, t_v_b,
                                       ws + WS_Q, ws + WS_K, ws + WS_V);
  attn_mfma_kernel<<<1024, 256, 0, stream>>>(ws + WS_Q, ws + WS_K, ws + WS_V,
                                             (const int*)(ws + WS_IDXK), ws + WS_NEWXYZ,
                                             (const unsigned short*)(ws + WS_WFRAG),
                                             t_attn_b1, t_attn_b2,
                                             t_pos_w1, t_pos_b1, t_pos_b2,
                                             ws + WS_AGG);
  kfend_kernel<<<16384, 128, 0, stream>>>(ws + WS_AGG, ws + WS_KF, t_end_w, t_end_b,
                                          ws_us + UB_KFF, out2);
  gemm_bf16_kernel<1, false><<<dim3(128, 2), 256, 0, stream>>>(
      ws_us + UB_KFF, ws_us + UF_E1, exp_b1, ws_us + UB_E1, NPTS, 256, 128, nullptr);
  gemm_bf16_kernel<0, false><<<dim3(128, 4), 256, 0, stream>>>(
      ws_us + UB_E1, ws_us + UF_E2, exp_b2, ws_us + UB_FEAT, NPTS, 512, 256, nullptr);
  gf_kernel<<<64, 256, 0, stream>>>(ws_us + UB_FEAT, ws_us + UB_GF);
  gemm_bf16_kernel<2, true><<<dim3(128, 4), 256, 0, stream>>>(
      ws_us + UB_FEAT, ws_us + UF_M1, mlp_b1, ws_us + UB_M1, NPTS, 512, 1024, ws_us + UB_GF);
  gemm_bf16_kernel<2, false><<<dim3(128, 2), 256, 0, stream>>>(
      ws_us + UB_M1, ws_us + UF_M2, mlp_b2, ws_us + UB_M2, NPTS, 256, 512, nullptr);
  gemm_bf16_kernel<2, false><<<dim3(128, 1), 256, 0, stream>>>(
      ws_us + UB_M2, ws_us + UF_M3, mlp_b3, ws_us + UB_M3, NPTS, 128, 256, nullptr);
  final_kernel<<<64, 256, 0, stream>>>(ws_us + UB_M3, mlp_w4, mlp_b4, ws + WS_NEWXYZ,
                                       out0, out1);
}